// Round 6
// baseline (475.461 us; speedup 1.0000x reference)
//
#include <hip/hip_runtime.h>
#include <math.h>

#define NN   50000
#define NE   800000
#define FEATD 128
#define SED  16
#define HD   64
#define NCLS 10
#define NLAY 3
#define NG   500

// two-level counting sort params
#define CHUNK 4096
#define NCH   ((NE + CHUNK - 1) / CHUNK)  // 196
#define CBSH  9
#define CB    ((NN + (1 << CBSH) - 1) >> CBSH)  // 98

// pre_emb block split across launches
#define GL    ((NN + 63) / 64)   // 782
#define PRE1  582                // pre blocks riding with bin
#define PRE2  (GL - PRE1)        // 200 pre blocks riding with scatter

typedef short  v8s __attribute__((ext_vector_type(8)));
typedef float  v4f __attribute__((ext_vector_type(4)));

// ---- bf16 helpers ---------------------------------------------------------
__device__ inline unsigned short f2bf(float f){
    unsigned int u = __float_as_uint(f);
    u += 0x7fffu + ((u >> 16) & 1u);
    return (unsigned short)(u >> 16);
}
__device__ inline unsigned int pack2bf(float a, float b){
    return (unsigned int)f2bf(a) | ((unsigned int)f2bf(b) << 16);
}
__device__ inline float bf_lo(unsigned int p){ return __uint_as_float(p << 16); }
__device__ inline float bf_hi(unsigned int p){ return __uint_as_float(p & 0xffff0000u); }

// fast tanh via v_exp (accuracy ~1e-7 rel, far below bf16 storage error)
__device__ inline float fast_tanh(float x){
    float ax = fabsf(x);
    float t  = __expf(-2.f * ax);
    float r  = (1.f - t) / (1.f + t);
    return copysignf(r, x);
}

// ---------------- pre_emb as a device function (callable from 2 kernels) ---
// Needs 38912B of dynamic LDS. pblk in [0, GL).
__device__ void pre_emb_block(
        int pblk, char* smem,
        const float* __restrict__ x, const float* __restrict__ preW,
        const float* __restrict__ preb,
        const float* __restrict__ s, const float* __restrict__ embW,
        const float* __restrict__ embb,
        unsigned short* __restrict__ xcb, int n)
{
    float* atx = (float*)smem;        // 64*132
    float* ats = atx + 64*132;        // 64*20
    int t  = threadIdx.x;
    int r0 = pblk * 64;
    for (int idx = t; idx < 64 * 32; idx += 256){
        int row = idx >> 5, kq = idx & 31;
        float4 v = make_float4(0.f, 0.f, 0.f, 0.f);
        if (r0 + row < n) v = *(const float4*)(x + (size_t)(r0 + row) * 128 + kq * 4);
        *(float4*)(&atx[row * 132 + kq * 4]) = v;
    }
    for (int idx = t; idx < 64 * 4; idx += 256){
        int row = idx >> 2, kq = idx & 3;
        float4 v = make_float4(0.f, 0.f, 0.f, 0.f);
        if (r0 + row < n) v = *(const float4*)(s + (size_t)(r0 + row) * 16 + kq * 4);
        *(float4*)(&ats[row * 20 + kq * 4]) = v;
    }
    __syncthreads();
    int lane = t & 63;
    int c0 = __builtin_amdgcn_readfirstlane((t >> 6) << 4);
    int row = r0 + lane;
    if (row >= n) return;
    float acc[16];
#pragma unroll
    for (int j = 0; j < 16; j++) acc[j] = 0.f;
    for (int k = 0; k < 128; k += 4){
        float4 av = *(const float4*)(&atx[lane * 132 + k]);
        float aa[4] = {av.x, av.y, av.z, av.w};
#pragma unroll
        for (int kk = 0; kk < 4; kk++){
            const float* wr = preW + (k + kk) * 64 + c0;
#pragma unroll
            for (int j = 0; j < 16; j++)
                acc[j] = fmaf(aa[kk], wr[j], acc[j]);
        }
    }
#pragma unroll
    for (int j = 0; j < 16; j++) acc[j] += preb[c0 + j];
    unsigned int pk[8];
#pragma unroll
    for (int j = 0; j < 8; j++) pk[j] = pack2bf(acc[2*j], acc[2*j+1]);
    {
        unsigned short* ob = xcb + (size_t)row * 128 + c0;
        uint4 u0; u0.x = pk[0]; u0.y = pk[1]; u0.z = pk[2]; u0.w = pk[3];
        uint4 u1; u1.x = pk[4]; u1.y = pk[5]; u1.z = pk[6]; u1.w = pk[7];
        *(uint4*)(ob)     = u0;
        *(uint4*)(ob + 8) = u1;
    }
#pragma unroll
    for (int j = 0; j < 16; j++) acc[j] = 0.f;
    for (int k = 0; k < 16; k += 4){
        float4 av = *(const float4*)(&ats[lane * 20 + k]);
        float aa[4] = {av.x, av.y, av.z, av.w};
#pragma unroll
        for (int kk = 0; kk < 4; kk++){
            const float* wr = embW + (k + kk) * 64 + c0;
#pragma unroll
            for (int j = 0; j < 16; j++)
                acc[j] = fmaf(aa[kk], wr[j], acc[j]);
        }
    }
#pragma unroll
    for (int j = 0; j < 16; j++) acc[j] += embb[c0 + j];
#pragma unroll
    for (int j = 0; j < 8; j++) pk[j] = pack2bf(acc[2*j], acc[2*j+1]);
    {
        unsigned short* ob = xcb + (size_t)row * 128 + 64 + c0;
        uint4 u0; u0.x = pk[0]; u0.y = pk[1]; u0.z = pk[2]; u0.w = pk[3];
        uint4 u1; u1.x = pk[4]; u1.y = pk[5]; u1.z = pk[6]; u1.w = pk[7];
        *(uint4*)(ob)     = u0;
        *(uint4*)(ob + 8) = u1;
    }
}

// ---------------- fused prep: weight transpose + coarse hist + gbuf zero ---
// blocks [0,224): wprep; [224,224+NCH): coarse_hist; rest: zero gbuf.
__global__ __launch_bounds__(256) void k_prep(
        const float* __restrict__ gcn_W, const float* __restrict__ gin_W1,
        const float* __restrict__ gin_W2, const float* __restrict__ whp_W,
        unsigned short* __restrict__ gcnWT, unsigned short* __restrict__ W1T,
        unsigned short* __restrict__ W2T,  unsigned short* __restrict__ whpWT,
        const int* __restrict__ dst, int* __restrict__ ghist,
        float* __restrict__ gbuf)
{
    __shared__ int h[CB];
    int b = blockIdx.x;
    if (b < 224){
        int i = b*256 + threadIdx.x;
        if (i < 12288){
            int li = i / 4096, r = i % 4096, nn = r / 64, kk = r % 64;
            gcnWT[li*4096 + nn*64 + kk] = f2bf(gcn_W[li*4096 + kk*64 + nn]);
        } else if (i < 36864){
            int j = i - 12288; int li = j / 8192, r = j % 8192, nn = r / 128, kk = r % 128;
            W1T[li*8192 + nn*128 + kk] = f2bf(gin_W1[li*8192 + kk*64 + nn]);
        } else if (i < 49152){
            int j = i - 36864; int li = j / 4096, r = j % 4096, nn = r / 64, kk = r % 64;
            W2T[li*4096 + nn*64 + kk] = f2bf(gin_W2[li*4096 + kk*64 + nn]);
        } else if (i < 57344){
            int j = i - 49152; int nn = j / 128, kk = j % 128;
            whpWT[nn*128 + kk] = f2bf(whp_W[kk*64 + nn]);
        }
    } else if (b < 224 + NCH){
        int c = b - 224;
        for (int i = threadIdx.x; i < CB; i += 256) h[i] = 0;
        __syncthreads();
        int base = c * CHUNK;
        int end  = base + CHUNK; if (end > NE) end = NE;
        for (int i = base + threadIdx.x; i < end; i += 256)
            atomicAdd(&h[dst[i] >> CBSH], 1);
        __syncthreads();
        for (int i = threadIdx.x; i < CB; i += 256)
            ghist[(size_t)c * CB + i] = h[i];
    } else {
        int i = (b - 224 - NCH)*256 + threadIdx.x;
        if (i < NG*64) gbuf[i] = 0.f;
    }
}

// LDS-staged scan of ghist (196*98 ints = 77KB LDS); single-block kernel.
__global__ __launch_bounds__(256) void coarse_scan(int* __restrict__ ghist){
    __shared__ int sh[NCH * CB];
    __shared__ int sc[256];
    int t = threadIdx.x;
    for (int i = t; i < NCH * CB; i += 256) sh[i] = ghist[i];
    __syncthreads();
    int run = 0;
    if (t < CB){
        for (int c = 0; c < NCH; c++){
            int v = sh[c*CB + t];
            sh[c*CB + t] = run;
            run += v;
        }
    }
    sc[t] = (t < CB) ? run : 0;
    __syncthreads();
    for (int d = 1; d < 256; d <<= 1){
        int u = (t >= d) ? sc[t-d] : 0;
        __syncthreads();
        sc[t] += u;
        __syncthreads();
    }
    int bstart = (t == 0) ? 0 : sc[t-1];
    if (t < CB){
        for (int c = 0; c < NCH; c++) sh[c*CB + t] += bstart;
    }
    __syncthreads();
    for (int i = t; i < NCH * CB; i += 256) ghist[i] = sh[i];
}

// ---------------- fused: bin (blocks [0,NCH)) + pre_emb [NCH, NCH+PRE1) ----
// Union'd dynamic LDS: bin needs 35360B, pre needs 38912B -> launch 38912.
__global__ __launch_bounds__(256) void bin_pre(
        const int* __restrict__ src, const int* __restrict__ dstp,
        const int* __restrict__ ghist, unsigned int* __restrict__ ebuf,
        const float* __restrict__ x, const float* __restrict__ preW,
        const float* __restrict__ preb,
        const float* __restrict__ s, const float* __restrict__ embW,
        const float* __restrict__ embb,
        unsigned short* __restrict__ xcb, int n)
{
    extern __shared__ char smem[];
    int t = threadIdx.x;
    if (blockIdx.x >= NCH){
        pre_emb_block(blockIdx.x - NCH, smem, x, preW, preb, s, embW, embb, xcb, n);
        return;
    }
    // ---- bin ----
    unsigned int* lbuf  = (unsigned int*)smem;
    unsigned int* lbuf2 = lbuf + CHUNK;
    int* hist   = (int*)(lbuf2 + CHUNK);
    int* lstart = hist + CB;
    int* cursor = lstart + CB;
    int* gbase  = cursor + CB;
    int* sc     = gbase + CB;
    int c = blockIdx.x;
    for (int i = t; i < CB; i += 256){
        hist[i] = 0;
        gbase[i] = ghist[(size_t)c*CB + i];
    }
    __syncthreads();
    int base = c * CHUNK;
    int nend = base + CHUNK; if (nend > NE) nend = NE;
    nend -= base;
    for (int i = t; i < nend; i += 256){
        int d = dstp[base + i];
        lbuf[i] = (unsigned int)src[base + i] | ((unsigned int)d << 16);
        atomicAdd(&hist[d >> CBSH], 1);
    }
    __syncthreads();
    sc[t] = (t < CB) ? hist[t] : 0;
    __syncthreads();
    for (int d = 1; d < 256; d <<= 1){
        int u = (t >= d) ? sc[t-d] : 0;
        __syncthreads();
        sc[t] += u;
        __syncthreads();
    }
    if (t < CB){
        lstart[t] = sc[t] - hist[t];
        cursor[t] = sc[t] - hist[t];
    }
    __syncthreads();
    for (int i = t; i < nend; i += 256){
        unsigned int u = lbuf[i];
        int b = (int)(u >> 16) >> CBSH;
        int p = atomicAdd(&cursor[b], 1);
        lbuf2[p] = u;
    }
    __syncthreads();
    for (int p = t; p < nend; p += 256){
        unsigned int u = lbuf2[p];
        int b = (int)(u >> 16) >> CBSH;
        ebuf[gbase[b] + (p - lstart[b])] = u;
    }
}

// ---------------- fused: scatter (blocks [0,CB)) + pre_emb rest ------------
__global__ __launch_bounds__(256) void scatter_pre(
        const unsigned int* __restrict__ ebuf, const int* __restrict__ ghist,
        int* __restrict__ off, float* __restrict__ dinv,
        int* __restrict__ csr, int n,
        const float* __restrict__ x, const float* __restrict__ preW,
        const float* __restrict__ preb,
        const float* __restrict__ s, const float* __restrict__ embW,
        const float* __restrict__ embb,
        unsigned short* __restrict__ xcb)
{
    extern __shared__ char smem[];
    if (blockIdx.x >= CB){
        pre_emb_block(PRE1 + (int)blockIdx.x - CB, smem,
                      x, preW, preb, s, embW, embb, xcb, n);
        return;
    }
    __shared__ int lcnt[512];
    __shared__ int lex[512];
    __shared__ int sc[256];
    int t = threadIdx.x, b = blockIdx.x;
    int n0 = b << CBSH;
    int nn = n - n0; if (nn > 512) nn = 512;
    int lo = ghist[b];
    int hi = (b + 1 < CB) ? ghist[b + 1] : NE;
    lcnt[t] = 0; lcnt[t + 256] = 0;
    __syncthreads();
    for (int j = lo + t; j < hi; j += 256)
        atomicAdd(&lcnt[(int)(ebuf[j] >> 16) - n0], 1);
    __syncthreads();
    int c0 = lcnt[2*t], c1 = lcnt[2*t+1];
    sc[t] = c0 + c1;
    __syncthreads();
    for (int d = 1; d < 256; d <<= 1){
        int u = (t >= d) ? sc[t-d] : 0;
        __syncthreads();
        sc[t] += u;
        __syncthreads();
    }
    int bse = sc[t] - (c0 + c1);
    lex[2*t]   = bse;
    lex[2*t+1] = bse + c0;
    __syncthreads();
    for (int i = t; i < nn; i += 256){
        off[n0 + i]  = lo + lex[i];
        dinv[n0 + i] = rsqrtf((float)lcnt[i] + 1.0f);
    }
    if (b == 0 && t == 0) off[n] = NE;
    __syncthreads();
    for (int j = lo + t; j < hi; j += 256){
        unsigned int u = ebuf[j];
        int d = (int)(u >> 16) - n0;
        int p = atomicAdd(&lex[d], 1);
        csr[lo + p] = (int)(u & 0xffffu);
    }
}

// ---------------- merged aggregation: ONE gather feeds GIN + GCN -----------
// 8-edge unrolled main loop: 8 gathers + 8 dinv in flight per waitcnt drain.
__global__ __launch_bounds__(256) void merged_agg(
        const unsigned int* __restrict__ xcb_cur,
        const float* __restrict__ dinv,
        const int* __restrict__ off, const int* __restrict__ csr,
        unsigned int* __restrict__ hpreb, unsigned int* __restrict__ ub, int n)
{
    int node = __builtin_amdgcn_readfirstlane(blockIdx.x * 4 + (threadIdx.x >> 6));
    int lane = threadIdx.x & 63;
    if (node >= n) return;
    int beg = off[node], end = off[node+1];
    unsigned int ps = xcb_cur[(size_t)node*64 + lane];
    float s0f = bf_lo(ps), s1f = bf_hi(ps);
    float a0 = s0f, a1 = s1f;
    float g0 = 0.f, g1 = 0.f;
    int e = beg;
    for (; e + 8 <= end; e += 8){
        int s0 = csr[e],   s1 = csr[e+1], s2 = csr[e+2], s3 = csr[e+3];
        int s4 = csr[e+4], s5 = csr[e+5], s6 = csr[e+6], s7 = csr[e+7];
        unsigned int p0 = xcb_cur[(size_t)s0*64 + lane];
        unsigned int p1 = xcb_cur[(size_t)s1*64 + lane];
        unsigned int p2 = xcb_cur[(size_t)s2*64 + lane];
        unsigned int p3 = xcb_cur[(size_t)s3*64 + lane];
        unsigned int p4 = xcb_cur[(size_t)s4*64 + lane];
        unsigned int p5 = xcb_cur[(size_t)s5*64 + lane];
        unsigned int p6 = xcb_cur[(size_t)s6*64 + lane];
        unsigned int p7 = xcb_cur[(size_t)s7*64 + lane];
        float d0 = dinv[s0], d1 = dinv[s1], d2 = dinv[s2], d3 = dinv[s3];
        float d4 = dinv[s4], d5 = dinv[s5], d6 = dinv[s6], d7 = dinv[s7];
        float v0 = bf_lo(p0), v1 = bf_lo(p1), v2 = bf_lo(p2), v3 = bf_lo(p3);
        float v4 = bf_lo(p4), v5 = bf_lo(p5), v6 = bf_lo(p6), v7 = bf_lo(p7);
        float w0 = bf_hi(p0), w1 = bf_hi(p1), w2 = bf_hi(p2), w3 = bf_hi(p3);
        float w4 = bf_hi(p4), w5 = bf_hi(p5), w6 = bf_hi(p6), w7 = bf_hi(p7);
        a0 += ((v0 + v1) + (v2 + v3)) + ((v4 + v5) + (v6 + v7));
        a1 += ((w0 + w1) + (w2 + w3)) + ((w4 + w5) + (w6 + w7));
        float ga = fmaf(d0, v0, fmaf(d1, v1, fmaf(d2, v2, d3*v3)));
        float gb = fmaf(d4, v4, fmaf(d5, v5, fmaf(d6, v6, d7*v7)));
        g0 += ga + gb;
        float gc = fmaf(d0, w0, fmaf(d1, w1, fmaf(d2, w2, d3*w3)));
        float gd = fmaf(d4, w4, fmaf(d5, w5, fmaf(d6, w6, d7*w7)));
        g1 += gc + gd;
    }
    for (; e + 4 <= end; e += 4){
        int s0 = csr[e], s1 = csr[e+1], s2 = csr[e+2], s3 = csr[e+3];
        unsigned int p0 = xcb_cur[(size_t)s0*64 + lane];
        unsigned int p1 = xcb_cur[(size_t)s1*64 + lane];
        unsigned int p2 = xcb_cur[(size_t)s2*64 + lane];
        unsigned int p3 = xcb_cur[(size_t)s3*64 + lane];
        float d0 = dinv[s0], d1 = dinv[s1], d2 = dinv[s2], d3 = dinv[s3];
        float v0 = bf_lo(p0), v1 = bf_lo(p1), v2 = bf_lo(p2), v3 = bf_lo(p3);
        float w0 = bf_hi(p0), w1 = bf_hi(p1), w2 = bf_hi(p2), w3 = bf_hi(p3);
        a0 += (v0 + v1) + (v2 + v3);
        a1 += (w0 + w1) + (w2 + w3);
        g0 = fmaf(d0, v0, fmaf(d1, v1, fmaf(d2, v2, fmaf(d3, v3, g0))));
        g1 = fmaf(d0, w0, fmaf(d1, w1, fmaf(d2, w2, fmaf(d3, w3, g1))));
    }
    for (; e < end; e++){
        int s0 = csr[e];
        unsigned int p0 = xcb_cur[(size_t)s0*64 + lane];
        float d0 = dinv[s0];
        float v0 = bf_lo(p0), w0 = bf_hi(p0);
        a0 += v0; a1 += w0;
        g0 = fmaf(d0, v0, g0);
        g1 = fmaf(d0, w0, g1);
    }
    hpreb[(size_t)node*64 + lane] = pack2bf(a0, a1);
    if (lane >= 32){   // lanes 32..63 hold s_prev cols (64..127)
        float di = dinv[node];
        float u0 = fmaf(di, g0, di*di*s0f);
        float u1 = fmaf(di, g1, di*di*s1f);
        ub[(size_t)node*32 + (lane - 32)] = pack2bf(u0, u1);
    }
}

// ---------------- fused per-layer MFMA: GIN MLP + GCN linear ---------------
__global__ __launch_bounds__(256) void ginmlp3(
        const unsigned short* __restrict__ hpreb,   // [n,128] bf16
        const unsigned short* __restrict__ ub,      // [n,64]  bf16
        const unsigned short* __restrict__ W1T,     // [64][128]
        const float* __restrict__ b1,
        const unsigned short* __restrict__ W2T,     // [64][64]
        const float* __restrict__ b2,
        const unsigned short* __restrict__ gcnWT,   // [64][64]
        const float* __restrict__ gcnb,
        unsigned short* __restrict__ xcb_nxt, int n)
{
    __shared__ unsigned short hsh[64 * 72];
    int tid = threadIdx.x;
    int w = tid >> 6, l = tid & 63;
    int m = l & 15, q = l >> 4;
    int rbase = blockIdx.x * 64 + w * 16;
    int arow  = rbase + m;
    bool valid = arow < n;
    v8s z = {0,0,0,0,0,0,0,0};
    // GEMM3: s_new = tanh(ub @ gcnW + b)
    {
        v8s a3[2];
#pragma unroll
        for (int ko = 0; ko < 2; ko++)
            a3[ko] = valid ? *(const v8s*)(ub + (size_t)arow * 64 + ko*32 + q*8) : z;
#pragma unroll
        for (int ct = 0; ct < 4; ct++){
            v4f acc = {0.f, 0.f, 0.f, 0.f};
#pragma unroll
            for (int ko = 0; ko < 2; ko++){
                v8s b = *(const v8s*)(gcnWT + (size_t)(ct*16 + m) * 64 + ko*32 + q*8);
                acc = __builtin_amdgcn_mfma_f32_16x16x32_bf16(a3[ko], b, acc, 0, 0, 0);
            }
            int col = ct*16 + m;
            float bv = gcnb[col];
#pragma unroll
            for (int r = 0; r < 4; r++){
                int orow = rbase + q*4 + r;
                if (orow < n)
                    xcb_nxt[(size_t)orow * 128 + 64 + col] = f2bf(fast_tanh(acc[r] + bv));
            }
        }
    }
    // GEMM1: h = relu(hpreb @ W1 + b1) -> LDS (bf16)
    {
        v8s a[4];
#pragma unroll
        for (int ko = 0; ko < 4; ko++)
            a[ko] = valid ? *(const v8s*)(hpreb + (size_t)arow * 128 + ko*32 + q*8) : z;
#pragma unroll
        for (int ct = 0; ct < 4; ct++){
            v4f acc = {0.f, 0.f, 0.f, 0.f};
#pragma unroll
            for (int ko = 0; ko < 4; ko++){
                v8s b = *(const v8s*)(W1T + (size_t)(ct*16 + m) * 128 + ko*32 + q*8);
                acc = __builtin_amdgcn_mfma_f32_16x16x32_bf16(a[ko], b, acc, 0, 0, 0);
            }
            int col = ct*16 + m;
            float bv = b1[col];
#pragma unroll
            for (int r = 0; r < 4; r++){
                int lrow = w*16 + q*4 + r;
                hsh[lrow*72 + col] = f2bf(fmaxf(acc[r] + bv, 0.f));
            }
        }
    }
    __syncthreads();
    // GEMM2: x_new = relu(h @ W2 + b2)
    v8s a2[2];
#pragma unroll
    for (int ko = 0; ko < 2; ko++)
        a2[ko] = *(const v8s*)(&hsh[(w*16 + m)*72 + ko*32 + q*8]);
#pragma unroll
    for (int ct = 0; ct < 4; ct++){
        v4f acc = {0.f, 0.f, 0.f, 0.f};
#pragma unroll
        for (int ko = 0; ko < 2; ko++){
            v8s b = *(const v8s*)(W2T + (size_t)(ct*16 + m) * 64 + ko*32 + q*8);
            acc = __builtin_amdgcn_mfma_f32_16x16x32_bf16(a2[ko], b, acc, 0, 0, 0);
        }
        int col = ct*16 + m;
        float bv = b2[col];
#pragma unroll
        for (int r = 0; r < 4; r++){
            int orow = rbase + q*4 + r;
            if (orow < n)
                xcb_nxt[(size_t)orow * 128 + col] = f2bf(fmaxf(acc[r] + bv, 0.f));
        }
    }
}

// ---------------- fused whp linear + global_add_pool -----------------------
__global__ __launch_bounds__(256) void whp_pool(
        const unsigned short* __restrict__ A,       // [n,128] bf16
        const unsigned short* __restrict__ WT,      // [64][128] bf16
        const float* __restrict__ bias,
        const int* __restrict__ batch,
        float* __restrict__ gbuf, int n)
{
    __shared__ float gacc[8 * 64];
    int tid = threadIdx.x;
    int w = tid >> 6, l = tid & 63;
    int m = l & 15, q = l >> 4;
    int blk0  = blockIdx.x * 64;
    int rbase = blk0 + w * 16;
    int rmax  = blk0 + 63; if (rmax > n - 1) rmax = n - 1;
    int bmin = batch[blk0];
    int span = batch[rmax] - bmin + 1;
    bool useLds = (span <= 8);
    if (useLds){
        for (int i = tid; i < span * 64; i += 256) gacc[i] = 0.f;
    }
    __syncthreads();
    int arow = rbase + m;
    bool valid = arow < n;
    v8s z = {0,0,0,0,0,0,0,0};
    v8s a[4];
#pragma unroll
    for (int ko = 0; ko < 4; ko++)
        a[ko] = valid ? *(const v8s*)(A + (size_t)arow * 128 + ko*32 + q*8) : z;
    int bb[4];
#pragma unroll
    for (int r = 0; r < 4; r++){
        int orow = rbase + q*4 + r;
        bb[r] = (orow < n) ? batch[orow] : -1;
    }
#pragma unroll
    for (int ct = 0; ct < 4; ct++){
        v4f acc = {0.f, 0.f, 0.f, 0.f};
#pragma unroll
        for (int ko = 0; ko < 4; ko++){
            v8s b = *(const v8s*)(WT + (size_t)(ct*16 + m) * 128 + ko*32 + q*8);
            acc = __builtin_amdgcn_mfma_f32_16x16x32_bf16(a[ko], b, acc, 0, 0, 0);
        }
        int col = ct*16 + m;
        float bv = bias[col];
#pragma unroll
        for (int r = 0; r < 4; r++){
            if (bb[r] >= 0){
                float val = acc[r] + bv;
                if (useLds) atomicAdd(&gacc[(bb[r] - bmin) * 64 + col], val);
                else        atomicAdd(&gbuf[(size_t)bb[r] * 64 + col], val);
            }
        }
    }
    __syncthreads();
    if (useLds){
        for (int i = tid; i < span * 64; i += 256)
            atomicAdd(&gbuf[(size_t)(bmin + (i >> 6)) * 64 + (i & 63)], gacc[i]);
    }
}

// ---------------- head ----------------------------------------------------
__global__ __launch_bounds__(256) void head_kernel(
        const float* __restrict__ g, const float* __restrict__ postW,
        const float* __restrict__ postb, const float* __restrict__ roW,
        const float* __restrict__ rob, float* __restrict__ out, int ngraph)
{
    int gr = __builtin_amdgcn_readfirstlane(blockIdx.x * 4 + (threadIdx.x >> 6));
    int lane = threadIdx.x & 63;
    if (gr >= ngraph) return;
    float gv = g[(size_t)gr*64 + lane];
    float t = postb[lane];
    for (int k = 0; k < 64; k++){
        float a = __shfl(gv, k);
        t = fmaf(a, postW[k*64 + lane], t);
    }
    t = fmaxf(t, 0.f);
    float lg = (lane < NCLS) ? rob[lane] : 0.f;
    for (int k = 0; k < 64; k++){
        float a = __shfl(t, k);
        float w = (lane < NCLS) ? roW[k*NCLS + lane] : 0.f;
        lg = fmaf(a, w, lg);
    }
    float m = (lane < NCLS) ? lg : -INFINITY;
#pragma unroll
    for (int d = 1; d < 16; d <<= 1) m = fmaxf(m, __shfl_xor(m, d, 16));
    float ex = (lane < NCLS) ? expf(lg - m) : 0.f;
    float ssum = ex;
#pragma unroll
    for (int d = 1; d < 16; d <<= 1) ssum += __shfl_xor(ssum, d, 16);
    if (lane < NCLS) out[(size_t)gr*NCLS + lane] = lg - m - logf(ssum);
}

// ---------------- launch --------------------------------------------------
extern "C" void kernel_launch(void* const* d_in, const int* in_sizes, int n_in,
                              void* d_out, int out_size, void* d_ws, size_t ws_size,
                              hipStream_t stream) {
    const float* x      = (const float*)d_in[0];
    const float* s      = (const float*)d_in[1];
    const int*   ei     = (const int*)d_in[2];    // int32
    const int*   batch  = (const int*)d_in[3];    // int32
    const float* pre_W  = (const float*)d_in[4];
    const float* pre_b  = (const float*)d_in[5];
    const float* emb_W  = (const float*)d_in[6];
    const float* emb_b  = (const float*)d_in[7];
    const float* gin_W1 = (const float*)d_in[8];
    const float* gin_b1 = (const float*)d_in[9];
    const float* gin_W2 = (const float*)d_in[10];
    const float* gin_b2 = (const float*)d_in[11];
    const float* gcn_W  = (const float*)d_in[12];
    const float* gcn_b  = (const float*)d_in[13];
    const float* whp_W  = (const float*)d_in[14];
    const float* whp_b  = (const float*)d_in[15];
    const float* post_W = (const float*)d_in[16];
    const float* post_b = (const float*)d_in[17];
    const float* ro_W   = (const float*)d_in[18];
    const float* ro_b   = (const float*)d_in[19];
    float* out = (float*)d_out;

    char* w = (char*)d_ws;
    auto alloc = [&](size_t bytes) -> void* {
        void* p = (void*)w;
        w += (bytes + 255) & ~(size_t)255;
        return p;
    };
    int*   off   = (int*)  alloc((size_t)(NN+1) * 4);
    int*   csr   = (int*)  alloc((size_t)NE * 4);
    int*   ghist = (int*)  alloc((size_t)NCH * CB * 4);
    unsigned int* ebuf = (unsigned int*)alloc((size_t)NE * 4);
    float* dinv = (float*)alloc((size_t)NN * 4);
    unsigned short* xcb0 = (unsigned short*)alloc((size_t)NN * 128 * 2);
    unsigned short* xcb1 = (unsigned short*)alloc((size_t)NN * 128 * 2);
    unsigned int*   hpreb = (unsigned int*)alloc((size_t)NN * 64 * 4);  // bf16 [n,128]
    unsigned int*   ub    = (unsigned int*)alloc((size_t)NN * 32 * 4);  // bf16 [n,64]
    float* gbuf = (float*)alloc((size_t)NG * 64 * 4);
    unsigned short* gcnWT = (unsigned short*)alloc((size_t)3 * 4096 * 2);
    unsigned short* W1T   = (unsigned short*)alloc((size_t)3 * 8192 * 2);
    unsigned short* W2T   = (unsigned short*)alloc((size_t)3 * 4096 * 2);
    unsigned short* whpWT = (unsigned short*)alloc((size_t)8192 * 2);

    const int B   = 256;
    const int GA  = (NN + 3) / 4;          // 12500
    const int GZB = (NG*64 + 255) / 256;   // 126

    // fused prep (wprep + coarse_hist + gbuf zero), then scan, then fused
    // bin+pre_emb, then fused scatter+pre_emb (38912B dynamic LDS both).
    k_prep<<<224 + NCH + GZB, B, 0, stream>>>(gcn_W, gin_W1, gin_W2, whp_W,
                                              gcnWT, W1T, W2T, whpWT,
                                              ei + NE, ghist, gbuf);
    coarse_scan<<<1, B, 0, stream>>>(ghist);
    bin_pre<<<NCH + PRE1, B, 38912, stream>>>(ei, ei + NE, ghist, ebuf,
                                              x, pre_W, pre_b, s, emb_W, emb_b,
                                              xcb0, NN);
    scatter_pre<<<CB + PRE2, B, 38912, stream>>>(ebuf, ghist, off, dinv, csr, NN,
                                                 x, pre_W, pre_b, s, emb_W, emb_b,
                                                 xcb0);

    for (int i = 0; i < NLAY; i++){
        unsigned short* cur = (i & 1) ? xcb1 : xcb0;
        unsigned short* nxt = (i & 1) ? xcb0 : xcb1;
        merged_agg<<<GA, B, 0, stream>>>((const unsigned int*)cur, dinv, off, csr,
                                         hpreb, ub, NN);
        ginmlp3<<<GL, B, 0, stream>>>((const unsigned short*)hpreb,
                                      (const unsigned short*)ub,
                                      W1T + (size_t)i*8192, gin_b1 + i*64,
                                      W2T + (size_t)i*4096, gin_b2 + i*64,
                                      gcnWT + (size_t)i*4096, gcn_b + i*64,
                                      nxt, NN);
    }

    // fused whp linear + pool (gbuf pre-zeroed in k_prep), then head
    whp_pool<<<GL, B, 0, stream>>>(xcb1, whpWT, whp_b, batch, gbuf, NN);
    head_kernel<<<(NG + 3)/4, B, 0, stream>>>(gbuf, post_W, post_b, ro_W, ro_b, out, NG);
}

// Round 7
// 367.176 us; speedup vs baseline: 1.2949x; 1.2949x over previous
//
#include <hip/hip_runtime.h>
#include <math.h>

#define NN   50000
#define NE   800000
#define FEATD 128
#define SED  16
#define HD   64
#define NCLS 10
#define NLAY 3
#define NG   500

// two-level counting sort params
#define CHUNK 4096
#define NCH   ((NE + CHUNK - 1) / CHUNK)  // 196
#define CBSH  9
#define CB    ((NN + (1 << CBSH) - 1) >> CBSH)  // 98

typedef short  v8s __attribute__((ext_vector_type(8)));
typedef float  v4f __attribute__((ext_vector_type(4)));

// ---- bf16 helpers ---------------------------------------------------------
__device__ inline unsigned short f2bf(float f){
    unsigned int u = __float_as_uint(f);
    u += 0x7fffu + ((u >> 16) & 1u);
    return (unsigned short)(u >> 16);
}
__device__ inline unsigned int pack2bf(float a, float b){
    return (unsigned int)f2bf(a) | ((unsigned int)f2bf(b) << 16);
}
__device__ inline float bf_lo(unsigned int p){ return __uint_as_float(p << 16); }
__device__ inline float bf_hi(unsigned int p){ return __uint_as_float(p & 0xffff0000u); }

// fast tanh via v_exp (accuracy ~1e-7 rel, far below bf16 storage error)
__device__ inline float fast_tanh(float x){
    float ax = fabsf(x);
    float t  = __expf(-2.f * ax);
    float r  = (1.f - t) / (1.f + t);
    return copysignf(r, x);
}

// ---------------- fused prep: weight transpose + coarse hist + gbuf zero ---
// blocks [0,224): wprep; [224,224+NCH): coarse_hist; rest: zero gbuf.
__global__ __launch_bounds__(256) void k_prep(
        const float* __restrict__ gcn_W, const float* __restrict__ gin_W1,
        const float* __restrict__ gin_W2, const float* __restrict__ whp_W,
        unsigned short* __restrict__ gcnWT, unsigned short* __restrict__ W1T,
        unsigned short* __restrict__ W2T,  unsigned short* __restrict__ whpWT,
        const int* __restrict__ dst, int* __restrict__ ghist,
        float* __restrict__ gbuf)
{
    __shared__ int h[CB];
    int b = blockIdx.x;
    if (b < 224){
        int i = b*256 + threadIdx.x;
        if (i < 12288){
            int li = i / 4096, r = i % 4096, nn = r / 64, kk = r % 64;
            gcnWT[li*4096 + nn*64 + kk] = f2bf(gcn_W[li*4096 + kk*64 + nn]);
        } else if (i < 36864){
            int j = i - 12288; int li = j / 8192, r = j % 8192, nn = r / 128, kk = r % 128;
            W1T[li*8192 + nn*128 + kk] = f2bf(gin_W1[li*8192 + kk*64 + nn]);
        } else if (i < 49152){
            int j = i - 36864; int li = j / 4096, r = j % 4096, nn = r / 64, kk = r % 64;
            W2T[li*4096 + nn*64 + kk] = f2bf(gin_W2[li*4096 + kk*64 + nn]);
        } else if (i < 57344){
            int j = i - 49152; int nn = j / 128, kk = j % 128;
            whpWT[nn*128 + kk] = f2bf(whp_W[kk*64 + nn]);
        }
    } else if (b < 224 + NCH){
        int c = b - 224;
        for (int i = threadIdx.x; i < CB; i += 256) h[i] = 0;
        __syncthreads();
        int base = c * CHUNK;
        int end  = base + CHUNK; if (end > NE) end = NE;
        for (int i = base + threadIdx.x; i < end; i += 256)
            atomicAdd(&h[dst[i] >> CBSH], 1);
        __syncthreads();
        for (int i = threadIdx.x; i < CB; i += 256)
            ghist[(size_t)c * CB + i] = h[i];
    } else {
        int i = (b - 224 - NCH)*256 + threadIdx.x;
        if (i < NG*64) gbuf[i] = 0.f;
    }
}

// LDS-staged scan of ghist (196*98 ints = 77KB LDS); single-block kernel.
__global__ __launch_bounds__(256) void coarse_scan(int* __restrict__ ghist){
    __shared__ int sh[NCH * CB];
    __shared__ int sc[256];
    int t = threadIdx.x;
    for (int i = t; i < NCH * CB; i += 256) sh[i] = ghist[i];
    __syncthreads();
    int run = 0;
    if (t < CB){
        for (int c = 0; c < NCH; c++){
            int v = sh[c*CB + t];
            sh[c*CB + t] = run;
            run += v;
        }
    }
    sc[t] = (t < CB) ? run : 0;
    __syncthreads();
    for (int d = 1; d < 256; d <<= 1){
        int u = (t >= d) ? sc[t-d] : 0;
        __syncthreads();
        sc[t] += u;
        __syncthreads();
    }
    int bstart = (t == 0) ? 0 : sc[t-1];
    if (t < CB){
        for (int c = 0; c < NCH; c++) sh[c*CB + t] += bstart;
    }
    __syncthreads();
    for (int i = t; i < NCH * CB; i += 256) ghist[i] = sh[i];
}

// ---------------- fused: bin_lds (blocks [0,NCH)) + pre_emb (rest) ---------
// Union'd dynamic LDS: bin needs 35360B, pre needs 38912B -> launch with 38912.
__global__ __launch_bounds__(256) void bin_pre(
        const int* __restrict__ src, const int* __restrict__ dstp,
        const int* __restrict__ ghist, unsigned int* __restrict__ ebuf,
        const float* __restrict__ x, const float* __restrict__ preW,
        const float* __restrict__ preb,
        const float* __restrict__ s, const float* __restrict__ embW,
        const float* __restrict__ embb,
        unsigned short* __restrict__ xcb, int n)
{
    extern __shared__ char smem[];
    int t = threadIdx.x;
    if (blockIdx.x < NCH){
        // ---- bin_lds ----
        unsigned int* lbuf  = (unsigned int*)smem;
        unsigned int* lbuf2 = lbuf + CHUNK;
        int* hist   = (int*)(lbuf2 + CHUNK);
        int* lstart = hist + CB;
        int* cursor = lstart + CB;
        int* gbase  = cursor + CB;
        int* sc     = gbase + CB;
        int c = blockIdx.x;
        for (int i = t; i < CB; i += 256){
            hist[i] = 0;
            gbase[i] = ghist[(size_t)c*CB + i];
        }
        __syncthreads();
        int base = c * CHUNK;
        int nend = base + CHUNK; if (nend > NE) nend = NE;
        nend -= base;
        for (int i = t; i < nend; i += 256){
            int d = dstp[base + i];
            lbuf[i] = (unsigned int)src[base + i] | ((unsigned int)d << 16);
            atomicAdd(&hist[d >> CBSH], 1);
        }
        __syncthreads();
        sc[t] = (t < CB) ? hist[t] : 0;
        __syncthreads();
        for (int d = 1; d < 256; d <<= 1){
            int u = (t >= d) ? sc[t-d] : 0;
            __syncthreads();
            sc[t] += u;
            __syncthreads();
        }
        if (t < CB){
            lstart[t] = sc[t] - hist[t];
            cursor[t] = sc[t] - hist[t];
        }
        __syncthreads();
        for (int i = t; i < nend; i += 256){
            unsigned int u = lbuf[i];
            int b = (int)(u >> 16) >> CBSH;
            int p = atomicAdd(&cursor[b], 1);
            lbuf2[p] = u;
        }
        __syncthreads();
        for (int p = t; p < nend; p += 256){
            unsigned int u = lbuf2[p];
            int b = (int)(u >> 16) >> CBSH;
            ebuf[gbase[b] + (p - lstart[b])] = u;
        }
    } else {
        // ---- pre_emb ----
        float* atx = (float*)smem;        // 64*132
        float* ats = atx + 64*132;        // 64*20
        int r0 = (blockIdx.x - NCH) * 64;
        for (int idx = t; idx < 64 * 32; idx += 256){
            int row = idx >> 5, kq = idx & 31;
            float4 v = make_float4(0.f, 0.f, 0.f, 0.f);
            if (r0 + row < n) v = *(const float4*)(x + (size_t)(r0 + row) * 128 + kq * 4);
            *(float4*)(&atx[row * 132 + kq * 4]) = v;
        }
        for (int idx = t; idx < 64 * 4; idx += 256){
            int row = idx >> 2, kq = idx & 3;
            float4 v = make_float4(0.f, 0.f, 0.f, 0.f);
            if (r0 + row < n) v = *(const float4*)(s + (size_t)(r0 + row) * 16 + kq * 4);
            *(float4*)(&ats[row * 20 + kq * 4]) = v;
        }
        __syncthreads();
        int lane = t & 63;
        int c0 = __builtin_amdgcn_readfirstlane((t >> 6) << 4);
        int row = r0 + lane;
        if (row >= n) return;
        float acc[16];
#pragma unroll
        for (int j = 0; j < 16; j++) acc[j] = 0.f;
        for (int k = 0; k < 128; k += 4){
            float4 av = *(const float4*)(&atx[lane * 132 + k]);
            float aa[4] = {av.x, av.y, av.z, av.w};
#pragma unroll
            for (int kk = 0; kk < 4; kk++){
                const float* wr = preW + (k + kk) * 64 + c0;
#pragma unroll
                for (int j = 0; j < 16; j++)
                    acc[j] = fmaf(aa[kk], wr[j], acc[j]);
            }
        }
#pragma unroll
        for (int j = 0; j < 16; j++) acc[j] += preb[c0 + j];
        unsigned int pk[8];
#pragma unroll
        for (int j = 0; j < 8; j++) pk[j] = pack2bf(acc[2*j], acc[2*j+1]);
        {
            unsigned short* ob = xcb + (size_t)row * 128 + c0;
            uint4 u0; u0.x = pk[0]; u0.y = pk[1]; u0.z = pk[2]; u0.w = pk[3];
            uint4 u1; u1.x = pk[4]; u1.y = pk[5]; u1.z = pk[6]; u1.w = pk[7];
            *(uint4*)(ob)     = u0;
            *(uint4*)(ob + 8) = u1;
        }
#pragma unroll
        for (int j = 0; j < 16; j++) acc[j] = 0.f;
        for (int k = 0; k < 16; k += 4){
            float4 av = *(const float4*)(&ats[lane * 20 + k]);
            float aa[4] = {av.x, av.y, av.z, av.w};
#pragma unroll
            for (int kk = 0; kk < 4; kk++){
                const float* wr = embW + (k + kk) * 64 + c0;
#pragma unroll
                for (int j = 0; j < 16; j++)
                    acc[j] = fmaf(aa[kk], wr[j], acc[j]);
            }
        }
#pragma unroll
        for (int j = 0; j < 16; j++) acc[j] += embb[c0 + j];
#pragma unroll
        for (int j = 0; j < 8; j++) pk[j] = pack2bf(acc[2*j], acc[2*j+1]);
        {
            unsigned short* ob = xcb + (size_t)row * 128 + 64 + c0;
            uint4 u0; u0.x = pk[0]; u0.y = pk[1]; u0.z = pk[2]; u0.w = pk[3];
            uint4 u1; u1.x = pk[4]; u1.y = pk[5]; u1.z = pk[6]; u1.w = pk[7];
            *(uint4*)(ob)     = u0;
            *(uint4*)(ob + 8) = u1;
        }
    }
}

__global__ __launch_bounds__(256) void scatter_all(
        const unsigned int* __restrict__ ebuf, const int* __restrict__ ghist,
        int* __restrict__ off, float* __restrict__ dinv,
        int* __restrict__ csr, int n){
    __shared__ int lcnt[512];
    __shared__ int lex[512];
    __shared__ int sc[256];
    int t = threadIdx.x, b = blockIdx.x;
    int n0 = b << CBSH;
    int nn = n - n0; if (nn > 512) nn = 512;
    int lo = ghist[b];
    int hi = (b + 1 < CB) ? ghist[b + 1] : NE;
    lcnt[t] = 0; lcnt[t + 256] = 0;
    __syncthreads();
    for (int j = lo + t; j < hi; j += 256)
        atomicAdd(&lcnt[(int)(ebuf[j] >> 16) - n0], 1);
    __syncthreads();
    int c0 = lcnt[2*t], c1 = lcnt[2*t+1];
    sc[t] = c0 + c1;
    __syncthreads();
    for (int d = 1; d < 256; d <<= 1){
        int u = (t >= d) ? sc[t-d] : 0;
        __syncthreads();
        sc[t] += u;
        __syncthreads();
    }
    int bse = sc[t] - (c0 + c1);
    lex[2*t]   = bse;
    lex[2*t+1] = bse + c0;
    __syncthreads();
    for (int i = t; i < nn; i += 256){
        off[n0 + i]  = lo + lex[i];
        dinv[n0 + i] = rsqrtf((float)lcnt[i] + 1.0f);
    }
    if (b == 0 && t == 0) off[n] = NE;
    __syncthreads();
    for (int j = lo + t; j < hi; j += 256){
        unsigned int u = ebuf[j];
        int d = (int)(u >> 16) - n0;
        int p = atomicAdd(&lex[d], 1);
        csr[lo + p] = (int)(u & 0xffffu);
    }
}

// ---------------- merged aggregation: ONE gather feeds GIN + GCN -----------
// 8-edge unrolled main loop: 8 gathers + 8 dinv in flight per waitcnt drain.
__global__ __launch_bounds__(256) void merged_agg(
        const unsigned int* __restrict__ xcb_cur,
        const float* __restrict__ dinv,
        const int* __restrict__ off, const int* __restrict__ csr,
        unsigned int* __restrict__ hpreb, unsigned int* __restrict__ ub, int n)
{
    int node = __builtin_amdgcn_readfirstlane(blockIdx.x * 4 + (threadIdx.x >> 6));
    int lane = threadIdx.x & 63;
    if (node >= n) return;
    int beg = off[node], end = off[node+1];
    unsigned int ps = xcb_cur[(size_t)node*64 + lane];
    float s0f = bf_lo(ps), s1f = bf_hi(ps);
    float a0 = s0f, a1 = s1f;
    float g0 = 0.f, g1 = 0.f;
    int e = beg;
    for (; e + 8 <= end; e += 8){
        int s0 = csr[e],   s1 = csr[e+1], s2 = csr[e+2], s3 = csr[e+3];
        int s4 = csr[e+4], s5 = csr[e+5], s6 = csr[e+6], s7 = csr[e+7];
        unsigned int p0 = xcb_cur[(size_t)s0*64 + lane];
        unsigned int p1 = xcb_cur[(size_t)s1*64 + lane];
        unsigned int p2 = xcb_cur[(size_t)s2*64 + lane];
        unsigned int p3 = xcb_cur[(size_t)s3*64 + lane];
        unsigned int p4 = xcb_cur[(size_t)s4*64 + lane];
        unsigned int p5 = xcb_cur[(size_t)s5*64 + lane];
        unsigned int p6 = xcb_cur[(size_t)s6*64 + lane];
        unsigned int p7 = xcb_cur[(size_t)s7*64 + lane];
        float d0 = dinv[s0], d1 = dinv[s1], d2 = dinv[s2], d3 = dinv[s3];
        float d4 = dinv[s4], d5 = dinv[s5], d6 = dinv[s6], d7 = dinv[s7];
        float v0 = bf_lo(p0), v1 = bf_lo(p1), v2 = bf_lo(p2), v3 = bf_lo(p3);
        float v4 = bf_lo(p4), v5 = bf_lo(p5), v6 = bf_lo(p6), v7 = bf_lo(p7);
        float w0 = bf_hi(p0), w1 = bf_hi(p1), w2 = bf_hi(p2), w3 = bf_hi(p3);
        float w4 = bf_hi(p4), w5 = bf_hi(p5), w6 = bf_hi(p6), w7 = bf_hi(p7);
        a0 += ((v0 + v1) + (v2 + v3)) + ((v4 + v5) + (v6 + v7));
        a1 += ((w0 + w1) + (w2 + w3)) + ((w4 + w5) + (w6 + w7));
        float ga = fmaf(d0, v0, fmaf(d1, v1, fmaf(d2, v2, d3*v3)));
        float gb = fmaf(d4, v4, fmaf(d5, v5, fmaf(d6, v6, d7*v7)));
        g0 += ga + gb;
        float gc = fmaf(d0, w0, fmaf(d1, w1, fmaf(d2, w2, d3*w3)));
        float gd = fmaf(d4, w4, fmaf(d5, w5, fmaf(d6, w6, d7*w7)));
        g1 += gc + gd;
    }
    for (; e + 4 <= end; e += 4){
        int s0 = csr[e], s1 = csr[e+1], s2 = csr[e+2], s3 = csr[e+3];
        unsigned int p0 = xcb_cur[(size_t)s0*64 + lane];
        unsigned int p1 = xcb_cur[(size_t)s1*64 + lane];
        unsigned int p2 = xcb_cur[(size_t)s2*64 + lane];
        unsigned int p3 = xcb_cur[(size_t)s3*64 + lane];
        float d0 = dinv[s0], d1 = dinv[s1], d2 = dinv[s2], d3 = dinv[s3];
        float v0 = bf_lo(p0), v1 = bf_lo(p1), v2 = bf_lo(p2), v3 = bf_lo(p3);
        float w0 = bf_hi(p0), w1 = bf_hi(p1), w2 = bf_hi(p2), w3 = bf_hi(p3);
        a0 += (v0 + v1) + (v2 + v3);
        a1 += (w0 + w1) + (w2 + w3);
        g0 = fmaf(d0, v0, fmaf(d1, v1, fmaf(d2, v2, fmaf(d3, v3, g0))));
        g1 = fmaf(d0, w0, fmaf(d1, w1, fmaf(d2, w2, fmaf(d3, w3, g1))));
    }
    for (; e < end; e++){
        int s0 = csr[e];
        unsigned int p0 = xcb_cur[(size_t)s0*64 + lane];
        float d0 = dinv[s0];
        float v0 = bf_lo(p0), w0 = bf_hi(p0);
        a0 += v0; a1 += w0;
        g0 = fmaf(d0, v0, g0);
        g1 = fmaf(d0, w0, g1);
    }
    hpreb[(size_t)node*64 + lane] = pack2bf(a0, a1);
    if (lane >= 32){   // lanes 32..63 hold s_prev cols (64..127)
        float di = dinv[node];
        float u0 = fmaf(di, g0, di*di*s0f);
        float u1 = fmaf(di, g1, di*di*s1f);
        ub[(size_t)node*32 + (lane - 32)] = pack2bf(u0, u1);
    }
}

// ---------------- fused per-layer MFMA: GIN MLP + GCN linear ---------------
__global__ __launch_bounds__(256) void ginmlp3(
        const unsigned short* __restrict__ hpreb,   // [n,128] bf16
        const unsigned short* __restrict__ ub,      // [n,64]  bf16
        const unsigned short* __restrict__ W1T,     // [64][128]
        const float* __restrict__ b1,
        const unsigned short* __restrict__ W2T,     // [64][64]
        const float* __restrict__ b2,
        const unsigned short* __restrict__ gcnWT,   // [64][64]
        const float* __restrict__ gcnb,
        unsigned short* __restrict__ xcb_nxt, int n)
{
    __shared__ unsigned short hsh[64 * 72];
    int tid = threadIdx.x;
    int w = tid >> 6, l = tid & 63;
    int m = l & 15, q = l >> 4;
    int rbase = blockIdx.x * 64 + w * 16;
    int arow  = rbase + m;
    bool valid = arow < n;
    v8s z = {0,0,0,0,0,0,0,0};
    // GEMM3: s_new = tanh(ub @ gcnW + b)
    {
        v8s a3[2];
#pragma unroll
        for (int ko = 0; ko < 2; ko++)
            a3[ko] = valid ? *(const v8s*)(ub + (size_t)arow * 64 + ko*32 + q*8) : z;
#pragma unroll
        for (int ct = 0; ct < 4; ct++){
            v4f acc = {0.f, 0.f, 0.f, 0.f};
#pragma unroll
            for (int ko = 0; ko < 2; ko++){
                v8s b = *(const v8s*)(gcnWT + (size_t)(ct*16 + m) * 64 + ko*32 + q*8);
                acc = __builtin_amdgcn_mfma_f32_16x16x32_bf16(a3[ko], b, acc, 0, 0, 0);
            }
            int col = ct*16 + m;
            float bv = gcnb[col];
#pragma unroll
            for (int r = 0; r < 4; r++){
                int orow = rbase + q*4 + r;
                if (orow < n)
                    xcb_nxt[(size_t)orow * 128 + 64 + col] = f2bf(fast_tanh(acc[r] + bv));
            }
        }
    }
    // GEMM1: h = relu(hpreb @ W1 + b1) -> LDS (bf16)
    {
        v8s a[4];
#pragma unroll
        for (int ko = 0; ko < 4; ko++)
            a[ko] = valid ? *(const v8s*)(hpreb + (size_t)arow * 128 + ko*32 + q*8) : z;
#pragma unroll
        for (int ct = 0; ct < 4; ct++){
            v4f acc = {0.f, 0.f, 0.f, 0.f};
#pragma unroll
            for (int ko = 0; ko < 4; ko++){
                v8s b = *(const v8s*)(W1T + (size_t)(ct*16 + m) * 128 + ko*32 + q*8);
                acc = __builtin_amdgcn_mfma_f32_16x16x32_bf16(a[ko], b, acc, 0, 0, 0);
            }
            int col = ct*16 + m;
            float bv = b1[col];
#pragma unroll
            for (int r = 0; r < 4; r++){
                int lrow = w*16 + q*4 + r;
                hsh[lrow*72 + col] = f2bf(fmaxf(acc[r] + bv, 0.f));
            }
        }
    }
    __syncthreads();
    // GEMM2: x_new = relu(h @ W2 + b2)
    v8s a2[2];
#pragma unroll
    for (int ko = 0; ko < 2; ko++)
        a2[ko] = *(const v8s*)(&hsh[(w*16 + m)*72 + ko*32 + q*8]);
#pragma unroll
    for (int ct = 0; ct < 4; ct++){
        v4f acc = {0.f, 0.f, 0.f, 0.f};
#pragma unroll
        for (int ko = 0; ko < 2; ko++){
            v8s b = *(const v8s*)(W2T + (size_t)(ct*16 + m) * 64 + ko*32 + q*8);
            acc = __builtin_amdgcn_mfma_f32_16x16x32_bf16(a2[ko], b, acc, 0, 0, 0);
        }
        int col = ct*16 + m;
        float bv = b2[col];
#pragma unroll
        for (int r = 0; r < 4; r++){
            int orow = rbase + q*4 + r;
            if (orow < n)
                xcb_nxt[(size_t)orow * 128 + col] = f2bf(fmaxf(acc[r] + bv, 0.f));
        }
    }
}

// ---------------- fused whp linear + global_add_pool -----------------------
// Block of 64 rows; batch is sorted so a block spans few graphs. Reduce into
// LDS per-graph accumulators (span<=8), flush once per block; fallback to
// direct global atomics for pathological spans. gbuf must be pre-zeroed.
__global__ __launch_bounds__(256) void whp_pool(
        const unsigned short* __restrict__ A,       // [n,128] bf16
        const unsigned short* __restrict__ WT,      // [64][128] bf16
        const float* __restrict__ bias,
        const int* __restrict__ batch,
        float* __restrict__ gbuf, int n)
{
    __shared__ float gacc[8 * 64];
    int tid = threadIdx.x;
    int w = tid >> 6, l = tid & 63;
    int m = l & 15, q = l >> 4;
    int blk0  = blockIdx.x * 64;
    int rbase = blk0 + w * 16;
    int rmax  = blk0 + 63; if (rmax > n - 1) rmax = n - 1;
    int bmin = batch[blk0];
    int span = batch[rmax] - bmin + 1;
    bool useLds = (span <= 8);
    if (useLds){
        for (int i = tid; i < span * 64; i += 256) gacc[i] = 0.f;
    }
    __syncthreads();
    int arow = rbase + m;
    bool valid = arow < n;
    v8s z = {0,0,0,0,0,0,0,0};
    v8s a[4];
#pragma unroll
    for (int ko = 0; ko < 4; ko++)
        a[ko] = valid ? *(const v8s*)(A + (size_t)arow * 128 + ko*32 + q*8) : z;
    int bb[4];
#pragma unroll
    for (int r = 0; r < 4; r++){
        int orow = rbase + q*4 + r;
        bb[r] = (orow < n) ? batch[orow] : -1;
    }
#pragma unroll
    for (int ct = 0; ct < 4; ct++){
        v4f acc = {0.f, 0.f, 0.f, 0.f};
#pragma unroll
        for (int ko = 0; ko < 4; ko++){
            v8s b = *(const v8s*)(WT + (size_t)(ct*16 + m) * 128 + ko*32 + q*8);
            acc = __builtin_amdgcn_mfma_f32_16x16x32_bf16(a[ko], b, acc, 0, 0, 0);
        }
        int col = ct*16 + m;
        float bv = bias[col];
#pragma unroll
        for (int r = 0; r < 4; r++){
            if (bb[r] >= 0){
                float val = acc[r] + bv;
                if (useLds) atomicAdd(&gacc[(bb[r] - bmin) * 64 + col], val);
                else        atomicAdd(&gbuf[(size_t)bb[r] * 64 + col], val);
            }
        }
    }
    __syncthreads();
    if (useLds){
        for (int i = tid; i < span * 64; i += 256)
            atomicAdd(&gbuf[(size_t)(bmin + (i >> 6)) * 64 + (i & 63)], gacc[i]);
    }
}

// ---------------- head ----------------------------------------------------
__global__ __launch_bounds__(256) void head_kernel(
        const float* __restrict__ g, const float* __restrict__ postW,
        const float* __restrict__ postb, const float* __restrict__ roW,
        const float* __restrict__ rob, float* __restrict__ out, int ngraph)
{
    int gr = __builtin_amdgcn_readfirstlane(blockIdx.x * 4 + (threadIdx.x >> 6));
    int lane = threadIdx.x & 63;
    if (gr >= ngraph) return;
    float gv = g[(size_t)gr*64 + lane];
    float t = postb[lane];
    for (int k = 0; k < 64; k++){
        float a = __shfl(gv, k);
        t = fmaf(a, postW[k*64 + lane], t);
    }
    t = fmaxf(t, 0.f);
    float lg = (lane < NCLS) ? rob[lane] : 0.f;
    for (int k = 0; k < 64; k++){
        float a = __shfl(t, k);
        float w = (lane < NCLS) ? roW[k*NCLS + lane] : 0.f;
        lg = fmaf(a, w, lg);
    }
    float m = (lane < NCLS) ? lg : -INFINITY;
#pragma unroll
    for (int d = 1; d < 16; d <<= 1) m = fmaxf(m, __shfl_xor(m, d, 16));
    float ex = (lane < NCLS) ? expf(lg - m) : 0.f;
    float ssum = ex;
#pragma unroll
    for (int d = 1; d < 16; d <<= 1) ssum += __shfl_xor(ssum, d, 16);
    if (lane < NCLS) out[(size_t)gr*NCLS + lane] = lg - m - logf(ssum);
}

// ---------------- launch --------------------------------------------------
extern "C" void kernel_launch(void* const* d_in, const int* in_sizes, int n_in,
                              void* d_out, int out_size, void* d_ws, size_t ws_size,
                              hipStream_t stream) {
    const float* x      = (const float*)d_in[0];
    const float* s      = (const float*)d_in[1];
    const int*   ei     = (const int*)d_in[2];    // int32
    const int*   batch  = (const int*)d_in[3];    // int32
    const float* pre_W  = (const float*)d_in[4];
    const float* pre_b  = (const float*)d_in[5];
    const float* emb_W  = (const float*)d_in[6];
    const float* emb_b  = (const float*)d_in[7];
    const float* gin_W1 = (const float*)d_in[8];
    const float* gin_b1 = (const float*)d_in[9];
    const float* gin_W2 = (const float*)d_in[10];
    const float* gin_b2 = (const float*)d_in[11];
    const float* gcn_W  = (const float*)d_in[12];
    const float* gcn_b  = (const float*)d_in[13];
    const float* whp_W  = (const float*)d_in[14];
    const float* whp_b  = (const float*)d_in[15];
    const float* post_W = (const float*)d_in[16];
    const float* post_b = (const float*)d_in[17];
    const float* ro_W   = (const float*)d_in[18];
    const float* ro_b   = (const float*)d_in[19];
    float* out = (float*)d_out;

    char* w = (char*)d_ws;
    auto alloc = [&](size_t bytes) -> void* {
        void* p = (void*)w;
        w += (bytes + 255) & ~(size_t)255;
        return p;
    };
    int*   off   = (int*)  alloc((size_t)(NN+1) * 4);
    int*   csr   = (int*)  alloc((size_t)NE * 4);
    int*   ghist = (int*)  alloc((size_t)NCH * CB * 4);
    unsigned int* ebuf = (unsigned int*)alloc((size_t)NE * 4);
    float* dinv = (float*)alloc((size_t)NN * 4);
    unsigned short* xcb0 = (unsigned short*)alloc((size_t)NN * 128 * 2);
    unsigned short* xcb1 = (unsigned short*)alloc((size_t)NN * 128 * 2);
    unsigned int*   hpreb = (unsigned int*)alloc((size_t)NN * 64 * 4);  // bf16 [n,128]
    unsigned int*   ub    = (unsigned int*)alloc((size_t)NN * 32 * 4);  // bf16 [n,64]
    float* gbuf = (float*)alloc((size_t)NG * 64 * 4);
    unsigned short* gcnWT = (unsigned short*)alloc((size_t)3 * 4096 * 2);
    unsigned short* W1T   = (unsigned short*)alloc((size_t)3 * 8192 * 2);
    unsigned short* W2T   = (unsigned short*)alloc((size_t)3 * 4096 * 2);
    unsigned short* whpWT = (unsigned short*)alloc((size_t)8192 * 2);

    const int B   = 256;
    const int GL  = (NN + 63) / 64;        // 782
    const int GA  = (NN + 3) / 4;          // 12500
    const int GZB = (NG*64 + 255) / 256;   // 126

    // fused prep (wprep + coarse_hist + gbuf zero), then scan, then fused
    // bin+pre_emb (union'd dynamic LDS = 38912B), then scatter.
    k_prep<<<224 + NCH + GZB, B, 0, stream>>>(gcn_W, gin_W1, gin_W2, whp_W,
                                              gcnWT, W1T, W2T, whpWT,
                                              ei + NE, ghist, gbuf);
    coarse_scan<<<1, B, 0, stream>>>(ghist);
    bin_pre<<<NCH + GL, B, 38912, stream>>>(ei, ei + NE, ghist, ebuf,
                                            x, pre_W, pre_b, s, emb_W, emb_b,
                                            xcb0, NN);
    scatter_all<<<CB, B, 0, stream>>>(ebuf, ghist, off, dinv, csr, NN);

    for (int i = 0; i < NLAY; i++){
        unsigned short* cur = (i & 1) ? xcb1 : xcb0;
        unsigned short* nxt = (i & 1) ? xcb0 : xcb1;
        merged_agg<<<GA, B, 0, stream>>>((const unsigned int*)cur, dinv, off, csr,
                                         hpreb, ub, NN);
        ginmlp3<<<GL, B, 0, stream>>>((const unsigned short*)hpreb,
                                      (const unsigned short*)ub,
                                      W1T + (size_t)i*8192, gin_b1 + i*64,
                                      W2T + (size_t)i*4096, gin_b2 + i*64,
                                      gcnWT + (size_t)i*4096, gcn_b + i*64,
                                      nxt, NN);
    }

    // fused whp linear + pool (gbuf pre-zeroed in k_prep), then head
    whp_pool<<<GL, B, 0, stream>>>(xcb1, whpWT, whp_b, batch, gbuf, NN);
    head_kernel<<<(NG + 3)/4, B, 0, stream>>>(gbuf, post_W, post_b, ro_W, ro_b, out, NG);
}

// Round 9
// 359.745 us; speedup vs baseline: 1.3217x; 1.0207x over previous
//
#include <hip/hip_runtime.h>
#include <math.h>

#define NN   50000
#define NE   800000
#define FEATD 128
#define SED  16
#define HD   64
#define NCLS 10
#define NLAY 3
#define NG   500

// two-level counting sort params
#define CHUNK 4096
#define NCH   ((NE + CHUNK - 1) / CHUNK)  // 196
#define CBSH  9
#define CB    ((NN + (1 << CBSH) - 1) >> CBSH)  // 98

typedef short  v8s __attribute__((ext_vector_type(8)));
typedef float  v4f __attribute__((ext_vector_type(4)));

// ---- bf16 helpers ---------------------------------------------------------
__device__ inline unsigned short f2bf(float f){
    unsigned int u = __float_as_uint(f);
    u += 0x7fffu + ((u >> 16) & 1u);
    return (unsigned short)(u >> 16);
}
__device__ inline unsigned int pack2bf(float a, float b){
    return (unsigned int)f2bf(a) | ((unsigned int)f2bf(b) << 16);
}
__device__ inline float bf_lo(unsigned int p){ return __uint_as_float(p << 16); }
__device__ inline float bf_hi(unsigned int p){ return __uint_as_float(p & 0xffff0000u); }

// fast tanh via v_exp (accuracy ~1e-7 rel, far below bf16 storage error)
__device__ inline float fast_tanh(float x){
    float ax = fabsf(x);
    float t  = __expf(-2.f * ax);
    float r  = (1.f - t) / (1.f + t);
    return copysignf(r, x);
}

// ---------------- fused prep: weight transpose + coarse hist + gbuf zero ---
// blocks [0,224): wprep; [224,224+NCH): coarse_hist; rest: zero gbuf.
__global__ __launch_bounds__(256) void k_prep(
        const float* __restrict__ gcn_W, const float* __restrict__ gin_W1,
        const float* __restrict__ gin_W2, const float* __restrict__ whp_W,
        unsigned short* __restrict__ gcnWT, unsigned short* __restrict__ W1T,
        unsigned short* __restrict__ W2T,  unsigned short* __restrict__ whpWT,
        const int* __restrict__ dst, int* __restrict__ ghist,
        float* __restrict__ gbuf)
{
    __shared__ int h[CB];
    int b = blockIdx.x;
    if (b < 224){
        int i = b*256 + threadIdx.x;
        if (i < 12288){
            int li = i / 4096, r = i % 4096, nn = r / 64, kk = r % 64;
            gcnWT[li*4096 + nn*64 + kk] = f2bf(gcn_W[li*4096 + kk*64 + nn]);
        } else if (i < 36864){
            int j = i - 12288; int li = j / 8192, r = j % 8192, nn = r / 128, kk = r % 128;
            W1T[li*8192 + nn*128 + kk] = f2bf(gin_W1[li*8192 + kk*64 + nn]);
        } else if (i < 49152){
            int j = i - 36864; int li = j / 4096, r = j % 4096, nn = r / 64, kk = r % 64;
            W2T[li*4096 + nn*64 + kk] = f2bf(gin_W2[li*4096 + kk*64 + nn]);
        } else if (i < 57344){
            int j = i - 49152; int nn = j / 128, kk = j % 128;
            whpWT[nn*128 + kk] = f2bf(whp_W[kk*64 + nn]);
        }
    } else if (b < 224 + NCH){
        int c = b - 224;
        for (int i = threadIdx.x; i < CB; i += 256) h[i] = 0;
        __syncthreads();
        int base = c * CHUNK;
        int end  = base + CHUNK; if (end > NE) end = NE;
        for (int i = base + threadIdx.x; i < end; i += 256)
            atomicAdd(&h[dst[i] >> CBSH], 1);
        __syncthreads();
        for (int i = threadIdx.x; i < CB; i += 256)
            ghist[(size_t)c * CB + i] = h[i];
    } else {
        int i = (b - 224 - NCH)*256 + threadIdx.x;
        if (i < NG*64) gbuf[i] = 0.f;
    }
}

// LDS-staged scan of ghist (196*98 ints = 77KB LDS); single-block kernel.
__global__ __launch_bounds__(256) void coarse_scan(int* __restrict__ ghist){
    __shared__ int sh[NCH * CB];
    __shared__ int sc[256];
    int t = threadIdx.x;
    for (int i = t; i < NCH * CB; i += 256) sh[i] = ghist[i];
    __syncthreads();
    int run = 0;
    if (t < CB){
        for (int c = 0; c < NCH; c++){
            int v = sh[c*CB + t];
            sh[c*CB + t] = run;
            run += v;
        }
    }
    sc[t] = (t < CB) ? run : 0;
    __syncthreads();
    for (int d = 1; d < 256; d <<= 1){
        int u = (t >= d) ? sc[t-d] : 0;
        __syncthreads();
        sc[t] += u;
        __syncthreads();
    }
    int bstart = (t == 0) ? 0 : sc[t-1];
    if (t < CB){
        for (int c = 0; c < NCH; c++) sh[c*CB + t] += bstart;
    }
    __syncthreads();
    for (int i = t; i < NCH * CB; i += 256) ghist[i] = sh[i];
}

// ---------------- fused: bin_lds (blocks [0,NCH)) + pre_emb (rest) ---------
// Union'd dynamic LDS: bin needs 35360B, pre needs 38912B -> launch with 38912.
__global__ __launch_bounds__(256) void bin_pre(
        const int* __restrict__ src, const int* __restrict__ dstp,
        const int* __restrict__ ghist, unsigned int* __restrict__ ebuf,
        const float* __restrict__ x, const float* __restrict__ preW,
        const float* __restrict__ preb,
        const float* __restrict__ s, const float* __restrict__ embW,
        const float* __restrict__ embb,
        unsigned short* __restrict__ xcb, int n)
{
    extern __shared__ char smem[];
    int t = threadIdx.x;
    if (blockIdx.x < NCH){
        // ---- bin_lds ----
        unsigned int* lbuf  = (unsigned int*)smem;
        unsigned int* lbuf2 = lbuf + CHUNK;
        int* hist   = (int*)(lbuf2 + CHUNK);
        int* lstart = hist + CB;
        int* cursor = lstart + CB;
        int* gbase  = cursor + CB;
        int* sc     = gbase + CB;
        int c = blockIdx.x;
        for (int i = t; i < CB; i += 256){
            hist[i] = 0;
            gbase[i] = ghist[(size_t)c*CB + i];
        }
        __syncthreads();
        int base = c * CHUNK;
        int nend = base + CHUNK; if (nend > NE) nend = NE;
        nend -= base;
        for (int i = t; i < nend; i += 256){
            int d = dstp[base + i];
            lbuf[i] = (unsigned int)src[base + i] | ((unsigned int)d << 16);
            atomicAdd(&hist[d >> CBSH], 1);
        }
        __syncthreads();
        sc[t] = (t < CB) ? hist[t] : 0;
        __syncthreads();
        for (int d = 1; d < 256; d <<= 1){
            int u = (t >= d) ? sc[t-d] : 0;
            __syncthreads();
            sc[t] += u;
            __syncthreads();
        }
        if (t < CB){
            lstart[t] = sc[t] - hist[t];
            cursor[t] = sc[t] - hist[t];
        }
        __syncthreads();
        for (int i = t; i < nend; i += 256){
            unsigned int u = lbuf[i];
            int b = (int)(u >> 16) >> CBSH;
            int p = atomicAdd(&cursor[b], 1);
            lbuf2[p] = u;
        }
        __syncthreads();
        for (int p = t; p < nend; p += 256){
            unsigned int u = lbuf2[p];
            int b = (int)(u >> 16) >> CBSH;
            ebuf[gbase[b] + (p - lstart[b])] = u;
        }
    } else {
        // ---- pre_emb ----
        float* atx = (float*)smem;        // 64*132
        float* ats = atx + 64*132;        // 64*20
        int r0 = (blockIdx.x - NCH) * 64;
        for (int idx = t; idx < 64 * 32; idx += 256){
            int row = idx >> 5, kq = idx & 31;
            float4 v = make_float4(0.f, 0.f, 0.f, 0.f);
            if (r0 + row < n) v = *(const float4*)(x + (size_t)(r0 + row) * 128 + kq * 4);
            *(float4*)(&atx[row * 132 + kq * 4]) = v;
        }
        for (int idx = t; idx < 64 * 4; idx += 256){
            int row = idx >> 2, kq = idx & 3;
            float4 v = make_float4(0.f, 0.f, 0.f, 0.f);
            if (r0 + row < n) v = *(const float4*)(s + (size_t)(r0 + row) * 16 + kq * 4);
            *(float4*)(&ats[row * 20 + kq * 4]) = v;
        }
        __syncthreads();
        int lane = t & 63;
        int c0 = __builtin_amdgcn_readfirstlane((t >> 6) << 4);
        int row = r0 + lane;
        if (row >= n) return;
        float acc[16];
#pragma unroll
        for (int j = 0; j < 16; j++) acc[j] = 0.f;
        for (int k = 0; k < 128; k += 4){
            float4 av = *(const float4*)(&atx[lane * 132 + k]);
            float aa[4] = {av.x, av.y, av.z, av.w};
#pragma unroll
            for (int kk = 0; kk < 4; kk++){
                const float* wr = preW + (k + kk) * 64 + c0;
#pragma unroll
                for (int j = 0; j < 16; j++)
                    acc[j] = fmaf(aa[kk], wr[j], acc[j]);
            }
        }
#pragma unroll
        for (int j = 0; j < 16; j++) acc[j] += preb[c0 + j];
        unsigned int pk[8];
#pragma unroll
        for (int j = 0; j < 8; j++) pk[j] = pack2bf(acc[2*j], acc[2*j+1]);
        {
            unsigned short* ob = xcb + (size_t)row * 128 + c0;
            uint4 u0; u0.x = pk[0]; u0.y = pk[1]; u0.z = pk[2]; u0.w = pk[3];
            uint4 u1; u1.x = pk[4]; u1.y = pk[5]; u1.z = pk[6]; u1.w = pk[7];
            *(uint4*)(ob)     = u0;
            *(uint4*)(ob + 8) = u1;
        }
#pragma unroll
        for (int j = 0; j < 16; j++) acc[j] = 0.f;
        for (int k = 0; k < 16; k += 4){
            float4 av = *(const float4*)(&ats[lane * 20 + k]);
            float aa[4] = {av.x, av.y, av.z, av.w};
#pragma unroll
            for (int kk = 0; kk < 4; kk++){
                const float* wr = embW + (k + kk) * 64 + c0;
#pragma unroll
                for (int j = 0; j < 16; j++)
                    acc[j] = fmaf(aa[kk], wr[j], acc[j]);
            }
        }
#pragma unroll
        for (int j = 0; j < 16; j++) acc[j] += embb[c0 + j];
#pragma unroll
        for (int j = 0; j < 8; j++) pk[j] = pack2bf(acc[2*j], acc[2*j+1]);
        {
            unsigned short* ob = xcb + (size_t)row * 128 + 64 + c0;
            uint4 u0; u0.x = pk[0]; u0.y = pk[1]; u0.z = pk[2]; u0.w = pk[3];
            uint4 u1; u1.x = pk[4]; u1.y = pk[5]; u1.z = pk[6]; u1.w = pk[7];
            *(uint4*)(ob)     = u0;
            *(uint4*)(ob + 8) = u1;
        }
    }
}

__global__ __launch_bounds__(256) void scatter_all(
        const unsigned int* __restrict__ ebuf, const int* __restrict__ ghist,
        int* __restrict__ off, float* __restrict__ dinv,
        int* __restrict__ csr, int n){
    __shared__ int lcnt[512];
    __shared__ int lex[512];
    __shared__ int sc[256];
    int t = threadIdx.x, b = blockIdx.x;
    int n0 = b << CBSH;
    int nn = n - n0; if (nn > 512) nn = 512;
    int lo = ghist[b];
    int hi = (b + 1 < CB) ? ghist[b + 1] : NE;
    lcnt[t] = 0; lcnt[t + 256] = 0;
    __syncthreads();
    for (int j = lo + t; j < hi; j += 256)
        atomicAdd(&lcnt[(int)(ebuf[j] >> 16) - n0], 1);
    __syncthreads();
    int c0 = lcnt[2*t], c1 = lcnt[2*t+1];
    sc[t] = c0 + c1;
    __syncthreads();
    for (int d = 1; d < 256; d <<= 1){
        int u = (t >= d) ? sc[t-d] : 0;
        __syncthreads();
        sc[t] += u;
        __syncthreads();
    }
    int bse = sc[t] - (c0 + c1);
    lex[2*t]   = bse;
    lex[2*t+1] = bse + c0;
    __syncthreads();
    for (int i = t; i < nn; i += 256){
        off[n0 + i]  = lo + lex[i];
        dinv[n0 + i] = rsqrtf((float)lcnt[i] + 1.0f);
    }
    if (b == 0 && t == 0) off[n] = NE;
    __syncthreads();
    for (int j = lo + t; j < hi; j += 256){
        unsigned int u = ebuf[j];
        int d = (int)(u >> 16) - n0;
        int p = atomicAdd(&lex[d], 1);
        csr[lo + p] = (int)(u & 0xffffu);
    }
}

// ---------------- merged aggregation: ONE gather feeds GIN + GCN -----------
// 8-edge unrolled main loop: 8 gathers + 8 dinv in flight per waitcnt drain.
__global__ __launch_bounds__(256) void merged_agg(
        const unsigned int* __restrict__ xcb_cur,
        const float* __restrict__ dinv,
        const int* __restrict__ off, const int* __restrict__ csr,
        unsigned int* __restrict__ hpreb, unsigned int* __restrict__ ub, int n)
{
    int node = __builtin_amdgcn_readfirstlane(blockIdx.x * 4 + (threadIdx.x >> 6));
    int lane = threadIdx.x & 63;
    if (node >= n) return;
    int beg = off[node], end = off[node+1];
    unsigned int ps = xcb_cur[(size_t)node*64 + lane];
    float s0f = bf_lo(ps), s1f = bf_hi(ps);
    float a0 = s0f, a1 = s1f;
    float g0 = 0.f, g1 = 0.f;
    int e = beg;
    for (; e + 8 <= end; e += 8){
        int s0 = csr[e],   s1 = csr[e+1], s2 = csr[e+2], s3 = csr[e+3];
        int s4 = csr[e+4], s5 = csr[e+5], s6 = csr[e+6], s7 = csr[e+7];
        unsigned int p0 = xcb_cur[(size_t)s0*64 + lane];
        unsigned int p1 = xcb_cur[(size_t)s1*64 + lane];
        unsigned int p2 = xcb_cur[(size_t)s2*64 + lane];
        unsigned int p3 = xcb_cur[(size_t)s3*64 + lane];
        unsigned int p4 = xcb_cur[(size_t)s4*64 + lane];
        unsigned int p5 = xcb_cur[(size_t)s5*64 + lane];
        unsigned int p6 = xcb_cur[(size_t)s6*64 + lane];
        unsigned int p7 = xcb_cur[(size_t)s7*64 + lane];
        float d0 = dinv[s0], d1 = dinv[s1], d2 = dinv[s2], d3 = dinv[s3];
        float d4 = dinv[s4], d5 = dinv[s5], d6 = dinv[s6], d7 = dinv[s7];
        float v0 = bf_lo(p0), v1 = bf_lo(p1), v2 = bf_lo(p2), v3 = bf_lo(p3);
        float v4 = bf_lo(p4), v5 = bf_lo(p5), v6 = bf_lo(p6), v7 = bf_lo(p7);
        float w0 = bf_hi(p0), w1 = bf_hi(p1), w2 = bf_hi(p2), w3 = bf_hi(p3);
        float w4 = bf_hi(p4), w5 = bf_hi(p5), w6 = bf_hi(p6), w7 = bf_hi(p7);
        a0 += ((v0 + v1) + (v2 + v3)) + ((v4 + v5) + (v6 + v7));
        a1 += ((w0 + w1) + (w2 + w3)) + ((w4 + w5) + (w6 + w7));
        float ga = fmaf(d0, v0, fmaf(d1, v1, fmaf(d2, v2, d3*v3)));
        float gb = fmaf(d4, v4, fmaf(d5, v5, fmaf(d6, v6, d7*v7)));
        g0 += ga + gb;
        float gc = fmaf(d0, w0, fmaf(d1, w1, fmaf(d2, w2, d3*w3)));
        float gd = fmaf(d4, w4, fmaf(d5, w5, fmaf(d6, w6, d7*w7)));
        g1 += gc + gd;
    }
    for (; e + 4 <= end; e += 4){
        int s0 = csr[e], s1 = csr[e+1], s2 = csr[e+2], s3 = csr[e+3];
        unsigned int p0 = xcb_cur[(size_t)s0*64 + lane];
        unsigned int p1 = xcb_cur[(size_t)s1*64 + lane];
        unsigned int p2 = xcb_cur[(size_t)s2*64 + lane];
        unsigned int p3 = xcb_cur[(size_t)s3*64 + lane];
        float d0 = dinv[s0], d1 = dinv[s1], d2 = dinv[s2], d3 = dinv[s3];
        float v0 = bf_lo(p0), v1 = bf_lo(p1), v2 = bf_lo(p2), v3 = bf_lo(p3);
        float w0 = bf_hi(p0), w1 = bf_hi(p1), w2 = bf_hi(p2), w3 = bf_hi(p3);
        a0 += (v0 + v1) + (v2 + v3);
        a1 += (w0 + w1) + (w2 + w3);
        g0 = fmaf(d0, v0, fmaf(d1, v1, fmaf(d2, v2, fmaf(d3, v3, g0))));
        g1 = fmaf(d0, w0, fmaf(d1, w1, fmaf(d2, w2, fmaf(d3, w3, g1))));
    }
    for (; e < end; e++){
        int s0 = csr[e];
        unsigned int p0 = xcb_cur[(size_t)s0*64 + lane];
        float d0 = dinv[s0];
        float v0 = bf_lo(p0), w0 = bf_hi(p0);
        a0 += v0; a1 += w0;
        g0 = fmaf(d0, v0, g0);
        g1 = fmaf(d0, w0, g1);
    }
    hpreb[(size_t)node*64 + lane] = pack2bf(a0, a1);
    if (lane >= 32){   // lanes 32..63 hold s_prev cols (64..127)
        float di = dinv[node];
        float u0 = fmaf(di, g0, di*di*s0f);
        float u1 = fmaf(di, g1, di*di*s1f);
        ub[(size_t)node*32 + (lane - 32)] = pack2bf(u0, u1);
    }
}

// ---------------- fused per-layer MFMA: GIN MLP + GCN linear ---------------
// do_whp (last layer): GEMM2/GEMM3 outputs stay in LDS (bit-identical bf16),
// then GEMM4 = [x_new|s_new]@whpW + global_add_pool, skipping the xcb round
// trip and the separate whp_pool launch entirely.
__global__ __launch_bounds__(256) void ginmlp3(
        const unsigned short* __restrict__ hpreb,   // [n,128] bf16
        const unsigned short* __restrict__ ub,      // [n,64]  bf16
        const unsigned short* __restrict__ W1T,     // [64][128]
        const float* __restrict__ b1,
        const unsigned short* __restrict__ W2T,     // [64][64]
        const float* __restrict__ b2,
        const unsigned short* __restrict__ gcnWT,   // [64][64]
        const float* __restrict__ gcnb,
        unsigned short* __restrict__ xcb_nxt,
        const unsigned short* __restrict__ whpWT,   // [64][128]
        const float* __restrict__ whpb,
        const int* __restrict__ batch,
        float* __restrict__ gbuf,
        int do_whp, int n)
{
    __shared__ unsigned short hsh[64 * 72];
    __shared__ unsigned short xsh[64 * 132];   // [row][col] bf16, stride 132
    __shared__ float gacc[8 * 64];
    int tid = threadIdx.x;
    int w = tid >> 6, l = tid & 63;
    int m = l & 15, q = l >> 4;
    int rbase = blockIdx.x * 64 + w * 16;
    int arow  = rbase + m;
    bool valid = arow < n;
    v8s z = {0,0,0,0,0,0,0,0};

    int bmin = 0, span = 0;
    bool useLds = false;
    if (do_whp){
        int blk0 = blockIdx.x * 64;
        int rmax = blk0 + 63; if (rmax > n - 1) rmax = n - 1;
        bmin = batch[blk0];
        span = batch[rmax] - bmin + 1;
        useLds = (span <= 8);
        for (int i = tid; i < 64 * 132; i += 256) xsh[i] = 0;
        if (useLds)
            for (int i = tid; i < span * 64; i += 256) gacc[i] = 0.f;
    }
    __syncthreads();

    // GEMM3: s_new = tanh(ub @ gcnW + b)
    {
        v8s a3[2];
#pragma unroll
        for (int ko = 0; ko < 2; ko++)
            a3[ko] = valid ? *(const v8s*)(ub + (size_t)arow * 64 + ko*32 + q*8) : z;
#pragma unroll
        for (int ct = 0; ct < 4; ct++){
            v4f acc = {0.f, 0.f, 0.f, 0.f};
#pragma unroll
            for (int ko = 0; ko < 2; ko++){
                v8s b = *(const v8s*)(gcnWT + (size_t)(ct*16 + m) * 64 + ko*32 + q*8);
                acc = __builtin_amdgcn_mfma_f32_16x16x32_bf16(a3[ko], b, acc, 0, 0, 0);
            }
            int col = ct*16 + m;
            float bv = gcnb[col];
#pragma unroll
            for (int r = 0; r < 4; r++){
                int orow = rbase + q*4 + r;
                if (orow < n){
                    unsigned short v = f2bf(fast_tanh(acc[r] + bv));
                    if (do_whp) xsh[(w*16 + q*4 + r)*132 + 64 + col] = v;
                    else        xcb_nxt[(size_t)orow * 128 + 64 + col] = v;
                }
            }
        }
    }
    // GEMM1: h = relu(hpreb @ W1 + b1) -> LDS (bf16)
    {
        v8s a[4];
#pragma unroll
        for (int ko = 0; ko < 4; ko++)
            a[ko] = valid ? *(const v8s*)(hpreb + (size_t)arow * 128 + ko*32 + q*8) : z;
#pragma unroll
        for (int ct = 0; ct < 4; ct++){
            v4f acc = {0.f, 0.f, 0.f, 0.f};
#pragma unroll
            for (int ko = 0; ko < 4; ko++){
                v8s b = *(const v8s*)(W1T + (size_t)(ct*16 + m) * 128 + ko*32 + q*8);
                acc = __builtin_amdgcn_mfma_f32_16x16x32_bf16(a[ko], b, acc, 0, 0, 0);
            }
            int col = ct*16 + m;
            float bv = b1[col];
#pragma unroll
            for (int r = 0; r < 4; r++){
                int lrow = w*16 + q*4 + r;
                hsh[lrow*72 + col] = f2bf(fmaxf(acc[r] + bv, 0.f));
            }
        }
    }
    __syncthreads();
    // GEMM2: x_new = relu(h @ W2 + b2)
    v8s a2[2];
#pragma unroll
    for (int ko = 0; ko < 2; ko++)
        a2[ko] = *(const v8s*)(&hsh[(w*16 + m)*72 + ko*32 + q*8]);
#pragma unroll
    for (int ct = 0; ct < 4; ct++){
        v4f acc = {0.f, 0.f, 0.f, 0.f};
#pragma unroll
        for (int ko = 0; ko < 2; ko++){
            v8s b = *(const v8s*)(W2T + (size_t)(ct*16 + m) * 64 + ko*32 + q*8);
            acc = __builtin_amdgcn_mfma_f32_16x16x32_bf16(a2[ko], b, acc, 0, 0, 0);
        }
        int col = ct*16 + m;
        float bv = b2[col];
#pragma unroll
        for (int r = 0; r < 4; r++){
            int orow = rbase + q*4 + r;
            if (orow < n){
                unsigned short v = f2bf(fmaxf(acc[r] + bv, 0.f));
                if (do_whp) xsh[(w*16 + q*4 + r)*132 + col] = v;
                else        xcb_nxt[(size_t)orow * 128 + col] = v;
            }
        }
    }

    if (do_whp){
        __syncthreads();   // xsh complete (GEMM2 + GEMM3 from all waves)
        // GEMM4: xw = [x_new|s_new] @ whpW + b, pooled by graph
        v8s a4[4];
#pragma unroll
        for (int ko = 0; ko < 4; ko++)
            a4[ko] = *(const v8s*)(&xsh[(w*16 + m)*132 + ko*32 + q*8]);
        int bb[4];
#pragma unroll
        for (int r = 0; r < 4; r++){
            int orow = rbase + q*4 + r;
            bb[r] = (orow < n) ? batch[orow] : -1;
        }
#pragma unroll
        for (int ct = 0; ct < 4; ct++){
            v4f acc = {0.f, 0.f, 0.f, 0.f};
#pragma unroll
            for (int ko = 0; ko < 4; ko++){
                v8s b = *(const v8s*)(whpWT + (size_t)(ct*16 + m) * 128 + ko*32 + q*8);
                acc = __builtin_amdgcn_mfma_f32_16x16x32_bf16(a4[ko], b, acc, 0, 0, 0);
            }
            int col = ct*16 + m;
            float bv = whpb[col];
#pragma unroll
            for (int r = 0; r < 4; r++){
                if (bb[r] >= 0){
                    float val = acc[r] + bv;
                    if (useLds) atomicAdd(&gacc[(bb[r] - bmin) * 64 + col], val);
                    else        atomicAdd(&gbuf[(size_t)bb[r] * 64 + col], val);
                }
            }
        }
        __syncthreads();
        if (useLds){
            for (int i = tid; i < span * 64; i += 256)
                atomicAdd(&gbuf[(size_t)(bmin + (i >> 6)) * 64 + (i & 63)], gacc[i]);
        }
    }
}

// ---------------- head ----------------------------------------------------
__global__ __launch_bounds__(256) void head_kernel(
        const float* __restrict__ g, const float* __restrict__ postW,
        const float* __restrict__ postb, const float* __restrict__ roW,
        const float* __restrict__ rob, float* __restrict__ out, int ngraph)
{
    int gr = __builtin_amdgcn_readfirstlane(blockIdx.x * 4 + (threadIdx.x >> 6));
    int lane = threadIdx.x & 63;
    if (gr >= ngraph) return;
    float gv = g[(size_t)gr*64 + lane];
    float t = postb[lane];
    for (int k = 0; k < 64; k++){
        float a = __shfl(gv, k);
        t = fmaf(a, postW[k*64 + lane], t);
    }
    t = fmaxf(t, 0.f);
    float lg = (lane < NCLS) ? rob[lane] : 0.f;
    for (int k = 0; k < 64; k++){
        float a = __shfl(t, k);
        float w = (lane < NCLS) ? roW[k*NCLS + lane] : 0.f;
        lg = fmaf(a, w, lg);
    }
    float m = (lane < NCLS) ? lg : -INFINITY;
#pragma unroll
    for (int d = 1; d < 16; d <<= 1) m = fmaxf(m, __shfl_xor(m, d, 16));
    float ex = (lane < NCLS) ? expf(lg - m) : 0.f;
    float ssum = ex;
#pragma unroll
    for (int d = 1; d < 16; d <<= 1) ssum += __shfl_xor(ssum, d, 16);
    if (lane < NCLS) out[(size_t)gr*NCLS + lane] = lg - m - logf(ssum);
}

// ---------------- launch --------------------------------------------------
extern "C" void kernel_launch(void* const* d_in, const int* in_sizes, int n_in,
                              void* d_out, int out_size, void* d_ws, size_t ws_size,
                              hipStream_t stream) {
    const float* x      = (const float*)d_in[0];
    const float* s      = (const float*)d_in[1];
    const int*   ei     = (const int*)d_in[2];    // int32
    const int*   batch  = (const int*)d_in[3];    // int32
    const float* pre_W  = (const float*)d_in[4];
    const float* pre_b  = (const float*)d_in[5];
    const float* emb_W  = (const float*)d_in[6];
    const float* emb_b  = (const float*)d_in[7];
    const float* gin_W1 = (const float*)d_in[8];
    const float* gin_b1 = (const float*)d_in[9];
    const float* gin_W2 = (const float*)d_in[10];
    const float* gin_b2 = (const float*)d_in[11];
    const float* gcn_W  = (const float*)d_in[12];
    const float* gcn_b  = (const float*)d_in[13];
    const float* whp_W  = (const float*)d_in[14];
    const float* whp_b  = (const float*)d_in[15];
    const float* post_W = (const float*)d_in[16];
    const float* post_b = (const float*)d_in[17];
    const float* ro_W   = (const float*)d_in[18];
    const float* ro_b   = (const float*)d_in[19];
    float* out = (float*)d_out;

    char* w = (char*)d_ws;
    auto alloc = [&](size_t bytes) -> void* {
        void* p = (void*)w;
        w += (bytes + 255) & ~(size_t)255;
        return p;
    };
    int*   off   = (int*)  alloc((size_t)(NN+1) * 4);
    int*   csr   = (int*)  alloc((size_t)NE * 4);
    int*   ghist = (int*)  alloc((size_t)NCH * CB * 4);
    unsigned int* ebuf = (unsigned int*)alloc((size_t)NE * 4);
    float* dinv = (float*)alloc((size_t)NN * 4);
    unsigned short* xcb0 = (unsigned short*)alloc((size_t)NN * 128 * 2);
    unsigned short* xcb1 = (unsigned short*)alloc((size_t)NN * 128 * 2);
    unsigned int*   hpreb = (unsigned int*)alloc((size_t)NN * 64 * 4);  // bf16 [n,128]
    unsigned int*   ub    = (unsigned int*)alloc((size_t)NN * 32 * 4);  // bf16 [n,64]
    float* gbuf = (float*)alloc((size_t)NG * 64 * 4);
    unsigned short* gcnWT = (unsigned short*)alloc((size_t)3 * 4096 * 2);
    unsigned short* W1T   = (unsigned short*)alloc((size_t)3 * 8192 * 2);
    unsigned short* W2T   = (unsigned short*)alloc((size_t)3 * 4096 * 2);
    unsigned short* whpWT = (unsigned short*)alloc((size_t)8192 * 2);

    const int B   = 256;
    const int GL  = (NN + 63) / 64;        // 782
    const int GA  = (NN + 3) / 4;          // 12500
    const int GZB = (NG*64 + 255) / 256;   // 126

    // fused prep (wprep + coarse_hist + gbuf zero), then scan, then fused
    // bin+pre_emb (union'd dynamic LDS = 38912B), then scatter.
    k_prep<<<224 + NCH + GZB, B, 0, stream>>>(gcn_W, gin_W1, gin_W2, whp_W,
                                              gcnWT, W1T, W2T, whpWT,
                                              ei + NE, ghist, gbuf);
    coarse_scan<<<1, B, 0, stream>>>(ghist);
    bin_pre<<<NCH + GL, B, 38912, stream>>>(ei, ei + NE, ghist, ebuf,
                                            x, pre_W, pre_b, s, emb_W, emb_b,
                                            xcb0, NN);
    scatter_all<<<CB, B, 0, stream>>>(ebuf, ghist, off, dinv, csr, NN);

    for (int i = 0; i < NLAY; i++){
        unsigned short* cur = (i & 1) ? xcb1 : xcb0;
        unsigned short* nxt = (i & 1) ? xcb0 : xcb1;
        merged_agg<<<GA, B, 0, stream>>>((const unsigned int*)cur, dinv, off, csr,
                                         hpreb, ub, NN);
        ginmlp3<<<GL, B, 0, stream>>>((const unsigned short*)hpreb,
                                      (const unsigned short*)ub,
                                      W1T + (size_t)i*8192, gin_b1 + i*64,
                                      W2T + (size_t)i*4096, gin_b2 + i*64,
                                      gcnWT + (size_t)i*4096, gcn_b + i*64,
                                      nxt,
                                      whpWT, whp_b, batch, gbuf,
                                      (i == NLAY - 1) ? 1 : 0, NN);
    }

    // pool already fused into last ginmlp3; head reads gbuf
    head_kernel<<<(NG + 3)/4, B, 0, stream>>>(gbuf, post_W, post_b, ro_W, ro_b, out, NG);
}

// Round 10
// 358.748 us; speedup vs baseline: 1.3253x; 1.0028x over previous
//
#include <hip/hip_runtime.h>
#include <math.h>

#define NN   50000
#define NE   800000
#define FEATD 128
#define SED  16
#define HD   64
#define NCLS 10
#define NLAY 3
#define NG   500

// two-level counting sort params
#define CHUNK 4096
#define NCH   ((NE + CHUNK - 1) / CHUNK)  // 196
#define CBSH  9
#define CB    ((NN + (1 << CBSH) - 1) >> CBSH)  // 98

typedef short  v8s __attribute__((ext_vector_type(8)));
typedef float  v4f __attribute__((ext_vector_type(4)));

// ---- bf16 helpers ---------------------------------------------------------
__device__ inline unsigned short f2bf(float f){
    unsigned int u = __float_as_uint(f);
    u += 0x7fffu + ((u >> 16) & 1u);
    return (unsigned short)(u >> 16);
}
__device__ inline unsigned int pack2bf(float a, float b){
    return (unsigned int)f2bf(a) | ((unsigned int)f2bf(b) << 16);
}
__device__ inline float bf_lo(unsigned int p){ return __uint_as_float(p << 16); }
__device__ inline float bf_hi(unsigned int p){ return __uint_as_float(p & 0xffff0000u); }

// fast tanh via v_exp (accuracy ~1e-7 rel, far below bf16 storage error)
__device__ inline float fast_tanh(float x){
    float ax = fabsf(x);
    float t  = __expf(-2.f * ax);
    float r  = (1.f - t) / (1.f + t);
    return copysignf(r, x);
}

// ---------------- fused prep: weight transpose + coarse hist + gbuf zero ---
// blocks [0,224): wprep; [224,224+NCH): coarse_hist; rest: zero gbuf.
__global__ __launch_bounds__(256) void k_prep(
        const float* __restrict__ gcn_W, const float* __restrict__ gin_W1,
        const float* __restrict__ gin_W2, const float* __restrict__ whp_W,
        unsigned short* __restrict__ gcnWT, unsigned short* __restrict__ W1T,
        unsigned short* __restrict__ W2T,  unsigned short* __restrict__ whpWT,
        const int* __restrict__ dst, int* __restrict__ ghist,
        float* __restrict__ gbuf)
{
    __shared__ int h[CB];
    int b = blockIdx.x;
    if (b < 224){
        int i = b*256 + threadIdx.x;
        if (i < 12288){
            int li = i / 4096, r = i % 4096, nn = r / 64, kk = r % 64;
            gcnWT[li*4096 + nn*64 + kk] = f2bf(gcn_W[li*4096 + kk*64 + nn]);
        } else if (i < 36864){
            int j = i - 12288; int li = j / 8192, r = j % 8192, nn = r / 128, kk = r % 128;
            W1T[li*8192 + nn*128 + kk] = f2bf(gin_W1[li*8192 + kk*64 + nn]);
        } else if (i < 49152){
            int j = i - 36864; int li = j / 4096, r = j % 4096, nn = r / 64, kk = r % 64;
            W2T[li*4096 + nn*64 + kk] = f2bf(gin_W2[li*4096 + kk*64 + nn]);
        } else if (i < 57344){
            int j = i - 49152; int nn = j / 128, kk = j % 128;
            whpWT[nn*128 + kk] = f2bf(whp_W[kk*64 + nn]);
        }
    } else if (b < 224 + NCH){
        int c = b - 224;
        for (int i = threadIdx.x; i < CB; i += 256) h[i] = 0;
        __syncthreads();
        int base = c * CHUNK;
        int end  = base + CHUNK; if (end > NE) end = NE;
        for (int i = base + threadIdx.x; i < end; i += 256)
            atomicAdd(&h[dst[i] >> CBSH], 1);
        __syncthreads();
        for (int i = threadIdx.x; i < CB; i += 256)
            ghist[(size_t)c * CB + i] = h[i];
    } else {
        int i = (b - 224 - NCH)*256 + threadIdx.x;
        if (i < NG*64) gbuf[i] = 0.f;
    }
}

// LDS-staged scan of ghist (196*98 ints = 77KB LDS); single-block kernel.
__global__ __launch_bounds__(256) void coarse_scan(int* __restrict__ ghist){
    __shared__ int sh[NCH * CB];
    __shared__ int sc[256];
    int t = threadIdx.x;
    for (int i = t; i < NCH * CB; i += 256) sh[i] = ghist[i];
    __syncthreads();
    int run = 0;
    if (t < CB){
        for (int c = 0; c < NCH; c++){
            int v = sh[c*CB + t];
            sh[c*CB + t] = run;
            run += v;
        }
    }
    sc[t] = (t < CB) ? run : 0;
    __syncthreads();
    for (int d = 1; d < 256; d <<= 1){
        int u = (t >= d) ? sc[t-d] : 0;
        __syncthreads();
        sc[t] += u;
        __syncthreads();
    }
    int bstart = (t == 0) ? 0 : sc[t-1];
    if (t < CB){
        for (int c = 0; c < NCH; c++) sh[c*CB + t] += bstart;
    }
    __syncthreads();
    for (int i = t; i < NCH * CB; i += 256) ghist[i] = sh[i];
}

// ---------------- fused: bin_lds (blocks [0,NCH)) + pre_emb (rest) ---------
// Union'd dynamic LDS: bin needs 35360B, pre needs 38912B -> launch with 38912.
__global__ __launch_bounds__(256) void bin_pre(
        const int* __restrict__ src, const int* __restrict__ dstp,
        const int* __restrict__ ghist, unsigned int* __restrict__ ebuf,
        const float* __restrict__ x, const float* __restrict__ preW,
        const float* __restrict__ preb,
        const float* __restrict__ s, const float* __restrict__ embW,
        const float* __restrict__ embb,
        unsigned short* __restrict__ xcb, int n)
{
    extern __shared__ char smem[];
    int t = threadIdx.x;
    if (blockIdx.x < NCH){
        // ---- bin_lds ----
        unsigned int* lbuf  = (unsigned int*)smem;
        unsigned int* lbuf2 = lbuf + CHUNK;
        int* hist   = (int*)(lbuf2 + CHUNK);
        int* lstart = hist + CB;
        int* cursor = lstart + CB;
        int* gbase  = cursor + CB;
        int* sc     = gbase + CB;
        int c = blockIdx.x;
        for (int i = t; i < CB; i += 256){
            hist[i] = 0;
            gbase[i] = ghist[(size_t)c*CB + i];
        }
        __syncthreads();
        int base = c * CHUNK;
        int nend = base + CHUNK; if (nend > NE) nend = NE;
        nend -= base;
        for (int i = t; i < nend; i += 256){
            int d = dstp[base + i];
            lbuf[i] = (unsigned int)src[base + i] | ((unsigned int)d << 16);
            atomicAdd(&hist[d >> CBSH], 1);
        }
        __syncthreads();
        sc[t] = (t < CB) ? hist[t] : 0;
        __syncthreads();
        for (int d = 1; d < 256; d <<= 1){
            int u = (t >= d) ? sc[t-d] : 0;
            __syncthreads();
            sc[t] += u;
            __syncthreads();
        }
        if (t < CB){
            lstart[t] = sc[t] - hist[t];
            cursor[t] = sc[t] - hist[t];
        }
        __syncthreads();
        for (int i = t; i < nend; i += 256){
            unsigned int u = lbuf[i];
            int b = (int)(u >> 16) >> CBSH;
            int p = atomicAdd(&cursor[b], 1);
            lbuf2[p] = u;
        }
        __syncthreads();
        for (int p = t; p < nend; p += 256){
            unsigned int u = lbuf2[p];
            int b = (int)(u >> 16) >> CBSH;
            ebuf[gbase[b] + (p - lstart[b])] = u;
        }
    } else {
        // ---- pre_emb ----
        float* atx = (float*)smem;        // 64*132
        float* ats = atx + 64*132;        // 64*20
        int r0 = (blockIdx.x - NCH) * 64;
        for (int idx = t; idx < 64 * 32; idx += 256){
            int row = idx >> 5, kq = idx & 31;
            float4 v = make_float4(0.f, 0.f, 0.f, 0.f);
            if (r0 + row < n) v = *(const float4*)(x + (size_t)(r0 + row) * 128 + kq * 4);
            *(float4*)(&atx[row * 132 + kq * 4]) = v;
        }
        for (int idx = t; idx < 64 * 4; idx += 256){
            int row = idx >> 2, kq = idx & 3;
            float4 v = make_float4(0.f, 0.f, 0.f, 0.f);
            if (r0 + row < n) v = *(const float4*)(s + (size_t)(r0 + row) * 16 + kq * 4);
            *(float4*)(&ats[row * 20 + kq * 4]) = v;
        }
        __syncthreads();
        int lane = t & 63;
        int c0 = __builtin_amdgcn_readfirstlane((t >> 6) << 4);
        int row = r0 + lane;
        if (row >= n) return;
        float acc[16];
#pragma unroll
        for (int j = 0; j < 16; j++) acc[j] = 0.f;
        for (int k = 0; k < 128; k += 4){
            float4 av = *(const float4*)(&atx[lane * 132 + k]);
            float aa[4] = {av.x, av.y, av.z, av.w};
#pragma unroll
            for (int kk = 0; kk < 4; kk++){
                const float* wr = preW + (k + kk) * 64 + c0;
#pragma unroll
                for (int j = 0; j < 16; j++)
                    acc[j] = fmaf(aa[kk], wr[j], acc[j]);
            }
        }
#pragma unroll
        for (int j = 0; j < 16; j++) acc[j] += preb[c0 + j];
        unsigned int pk[8];
#pragma unroll
        for (int j = 0; j < 8; j++) pk[j] = pack2bf(acc[2*j], acc[2*j+1]);
        {
            unsigned short* ob = xcb + (size_t)row * 128 + c0;
            uint4 u0; u0.x = pk[0]; u0.y = pk[1]; u0.z = pk[2]; u0.w = pk[3];
            uint4 u1; u1.x = pk[4]; u1.y = pk[5]; u1.z = pk[6]; u1.w = pk[7];
            *(uint4*)(ob)     = u0;
            *(uint4*)(ob + 8) = u1;
        }
#pragma unroll
        for (int j = 0; j < 16; j++) acc[j] = 0.f;
        for (int k = 0; k < 16; k += 4){
            float4 av = *(const float4*)(&ats[lane * 20 + k]);
            float aa[4] = {av.x, av.y, av.z, av.w};
#pragma unroll
            for (int kk = 0; kk < 4; kk++){
                const float* wr = embW + (k + kk) * 64 + c0;
#pragma unroll
                for (int j = 0; j < 16; j++)
                    acc[j] = fmaf(aa[kk], wr[j], acc[j]);
            }
        }
#pragma unroll
        for (int j = 0; j < 16; j++) acc[j] += embb[c0 + j];
#pragma unroll
        for (int j = 0; j < 8; j++) pk[j] = pack2bf(acc[2*j], acc[2*j+1]);
        {
            unsigned short* ob = xcb + (size_t)row * 128 + 64 + c0;
            uint4 u0; u0.x = pk[0]; u0.y = pk[1]; u0.z = pk[2]; u0.w = pk[3];
            uint4 u1; u1.x = pk[4]; u1.y = pk[5]; u1.z = pk[6]; u1.w = pk[7];
            *(uint4*)(ob)     = u0;
            *(uint4*)(ob + 8) = u1;
        }
    }
}

__global__ __launch_bounds__(256) void scatter_all(
        const unsigned int* __restrict__ ebuf, const int* __restrict__ ghist,
        int* __restrict__ off, float* __restrict__ dinv,
        int* __restrict__ csr, int n){
    __shared__ int lcnt[512];
    __shared__ int lex[512];
    __shared__ int sc[256];
    int t = threadIdx.x, b = blockIdx.x;
    int n0 = b << CBSH;
    int nn = n - n0; if (nn > 512) nn = 512;
    int lo = ghist[b];
    int hi = (b + 1 < CB) ? ghist[b + 1] : NE;
    lcnt[t] = 0; lcnt[t + 256] = 0;
    __syncthreads();
    for (int j = lo + t; j < hi; j += 256)
        atomicAdd(&lcnt[(int)(ebuf[j] >> 16) - n0], 1);
    __syncthreads();
    int c0 = lcnt[2*t], c1 = lcnt[2*t+1];
    sc[t] = c0 + c1;
    __syncthreads();
    for (int d = 1; d < 256; d <<= 1){
        int u = (t >= d) ? sc[t-d] : 0;
        __syncthreads();
        sc[t] += u;
        __syncthreads();
    }
    int bse = sc[t] - (c0 + c1);
    lex[2*t]   = bse;
    lex[2*t+1] = bse + c0;
    __syncthreads();
    for (int i = t; i < nn; i += 256){
        off[n0 + i]  = lo + lex[i];
        dinv[n0 + i] = rsqrtf((float)lcnt[i] + 1.0f);
    }
    if (b == 0 && t == 0) off[n] = NE;
    __syncthreads();
    for (int j = lo + t; j < hi; j += 256){
        unsigned int u = ebuf[j];
        int d = (int)(u >> 16) - n0;
        int p = atomicAdd(&lex[d], 1);
        csr[lo + p] = (int)(u & 0xffffu);
    }
}

// ---------------- merged aggregation: ONE gather feeds GIN + GCN -----------
// 8-edge unrolled main loop: 8 gathers + 8 dinv in flight per waitcnt drain.
__global__ __launch_bounds__(256) void merged_agg(
        const unsigned int* __restrict__ xcb_cur,
        const float* __restrict__ dinv,
        const int* __restrict__ off, const int* __restrict__ csr,
        unsigned int* __restrict__ hpreb, unsigned int* __restrict__ ub, int n)
{
    int node = __builtin_amdgcn_readfirstlane(blockIdx.x * 4 + (threadIdx.x >> 6));
    int lane = threadIdx.x & 63;
    if (node >= n) return;
    int beg = off[node], end = off[node+1];
    unsigned int ps = xcb_cur[(size_t)node*64 + lane];
    float s0f = bf_lo(ps), s1f = bf_hi(ps);
    float a0 = s0f, a1 = s1f;
    float g0 = 0.f, g1 = 0.f;
    int e = beg;
    for (; e + 8 <= end; e += 8){
        int s0 = csr[e],   s1 = csr[e+1], s2 = csr[e+2], s3 = csr[e+3];
        int s4 = csr[e+4], s5 = csr[e+5], s6 = csr[e+6], s7 = csr[e+7];
        unsigned int p0 = xcb_cur[(size_t)s0*64 + lane];
        unsigned int p1 = xcb_cur[(size_t)s1*64 + lane];
        unsigned int p2 = xcb_cur[(size_t)s2*64 + lane];
        unsigned int p3 = xcb_cur[(size_t)s3*64 + lane];
        unsigned int p4 = xcb_cur[(size_t)s4*64 + lane];
        unsigned int p5 = xcb_cur[(size_t)s5*64 + lane];
        unsigned int p6 = xcb_cur[(size_t)s6*64 + lane];
        unsigned int p7 = xcb_cur[(size_t)s7*64 + lane];
        float d0 = dinv[s0], d1 = dinv[s1], d2 = dinv[s2], d3 = dinv[s3];
        float d4 = dinv[s4], d5 = dinv[s5], d6 = dinv[s6], d7 = dinv[s7];
        float v0 = bf_lo(p0), v1 = bf_lo(p1), v2 = bf_lo(p2), v3 = bf_lo(p3);
        float v4 = bf_lo(p4), v5 = bf_lo(p5), v6 = bf_lo(p6), v7 = bf_lo(p7);
        float w0 = bf_hi(p0), w1 = bf_hi(p1), w2 = bf_hi(p2), w3 = bf_hi(p3);
        float w4 = bf_hi(p4), w5 = bf_hi(p5), w6 = bf_hi(p6), w7 = bf_hi(p7);
        a0 += ((v0 + v1) + (v2 + v3)) + ((v4 + v5) + (v6 + v7));
        a1 += ((w0 + w1) + (w2 + w3)) + ((w4 + w5) + (w6 + w7));
        float ga = fmaf(d0, v0, fmaf(d1, v1, fmaf(d2, v2, d3*v3)));
        float gb = fmaf(d4, v4, fmaf(d5, v5, fmaf(d6, v6, d7*v7)));
        g0 += ga + gb;
        float gc = fmaf(d0, w0, fmaf(d1, w1, fmaf(d2, w2, d3*w3)));
        float gd = fmaf(d4, w4, fmaf(d5, w5, fmaf(d6, w6, d7*w7)));
        g1 += gc + gd;
    }
    for (; e + 4 <= end; e += 4){
        int s0 = csr[e], s1 = csr[e+1], s2 = csr[e+2], s3 = csr[e+3];
        unsigned int p0 = xcb_cur[(size_t)s0*64 + lane];
        unsigned int p1 = xcb_cur[(size_t)s1*64 + lane];
        unsigned int p2 = xcb_cur[(size_t)s2*64 + lane];
        unsigned int p3 = xcb_cur[(size_t)s3*64 + lane];
        float d0 = dinv[s0], d1 = dinv[s1], d2 = dinv[s2], d3 = dinv[s3];
        float v0 = bf_lo(p0), v1 = bf_lo(p1), v2 = bf_lo(p2), v3 = bf_lo(p3);
        float w0 = bf_hi(p0), w1 = bf_hi(p1), w2 = bf_hi(p2), w3 = bf_hi(p3);
        a0 += (v0 + v1) + (v2 + v3);
        a1 += (w0 + w1) + (w2 + w3);
        g0 = fmaf(d0, v0, fmaf(d1, v1, fmaf(d2, v2, fmaf(d3, v3, g0))));
        g1 = fmaf(d0, w0, fmaf(d1, w1, fmaf(d2, w2, fmaf(d3, w3, g1))));
    }
    for (; e < end; e++){
        int s0 = csr[e];
        unsigned int p0 = xcb_cur[(size_t)s0*64 + lane];
        float d0 = dinv[s0];
        float v0 = bf_lo(p0), w0 = bf_hi(p0);
        a0 += v0; a1 += w0;
        g0 = fmaf(d0, v0, g0);
        g1 = fmaf(d0, w0, g1);
    }
    hpreb[(size_t)node*64 + lane] = pack2bf(a0, a1);
    if (lane >= 32){   // lanes 32..63 hold s_prev cols (64..127)
        float di = dinv[node];
        float u0 = fmaf(di, g0, di*di*s0f);
        float u1 = fmaf(di, g1, di*di*s1f);
        ub[(size_t)node*32 + (lane - 32)] = pack2bf(u0, u1);
    }
}

// ---------------- fused per-layer MFMA: GIN MLP + GCN linear ---------------
// Quadrant-split decomposition: block = 16 rows, 4 waves; wave w owns output
// cols [w*16, w*16+16). 4x the wave-parallelism of the old 64-row block
// (R9 counters: MfmaUtil 1.9%, Occ 21% -> grid-starved latency-bound).
// Per-output math identical (same K-order per MFMA chain) -> bit-exact.
// do_whp (last layer): outputs stay in LDS, then GEMM4 + pooled atomics.
__global__ __launch_bounds__(256) void ginmlp3(
        const unsigned short* __restrict__ hpreb,   // [n,128] bf16
        const unsigned short* __restrict__ ub,      // [n,64]  bf16
        const unsigned short* __restrict__ W1T,     // [64][128]
        const float* __restrict__ b1,
        const unsigned short* __restrict__ W2T,     // [64][64]
        const float* __restrict__ b2,
        const unsigned short* __restrict__ gcnWT,   // [64][64]
        const float* __restrict__ gcnb,
        unsigned short* __restrict__ xcb_nxt,
        const unsigned short* __restrict__ whpWT,   // [64][128]
        const float* __restrict__ whpb,
        const int* __restrict__ batch,
        float* __restrict__ gbuf,
        int do_whp, int n)
{
    __shared__ unsigned short hsh[16 * 72];
    __shared__ unsigned short xsh[16 * 132];   // [row][col] bf16, stride 132
    __shared__ float gacc[8 * 64];
    int tid = threadIdx.x;
    int w = tid >> 6, l = tid & 63;
    int m = l & 15, q = l >> 4;
    int rbase = blockIdx.x * 16;
    int arow  = rbase + m;
    int col   = w*16 + m;
    bool valid = arow < n;
    v8s z = {0,0,0,0,0,0,0,0};

    int bmin = 0, span = 0;
    bool useLds = false;
    if (do_whp){
        int rmax = rbase + 15; if (rmax > n - 1) rmax = n - 1;
        bmin = batch[rbase];
        span = batch[rmax] - bmin + 1;
        useLds = (span <= 8);
        for (int i = tid; i < 16 * 132; i += 256) xsh[i] = 0;
        if (useLds)
            for (int i = tid; i < span * 64; i += 256) gacc[i] = 0.f;
        __syncthreads();
    }

    // GEMM3 (quadrant w): s_new cols [w*16,w*16+16) = tanh(ub @ gcnW + b)
    {
        v8s a3[2];
#pragma unroll
        for (int ko = 0; ko < 2; ko++)
            a3[ko] = valid ? *(const v8s*)(ub + (size_t)arow * 64 + ko*32 + q*8) : z;
        v4f acc = {0.f, 0.f, 0.f, 0.f};
#pragma unroll
        for (int ko = 0; ko < 2; ko++){
            v8s b = *(const v8s*)(gcnWT + (size_t)col * 64 + ko*32 + q*8);
            acc = __builtin_amdgcn_mfma_f32_16x16x32_bf16(a3[ko], b, acc, 0, 0, 0);
        }
        float bv = gcnb[col];
#pragma unroll
        for (int r = 0; r < 4; r++){
            int orow = rbase + q*4 + r;
            if (orow < n){
                unsigned short v = f2bf(fast_tanh(acc[r] + bv));
                if (do_whp) xsh[(q*4 + r)*132 + 64 + col] = v;
                else        xcb_nxt[(size_t)orow * 128 + 64 + col] = v;
            }
        }
    }
    // GEMM1 (quadrant w): h cols [w*16,w*16+16) = relu(hpreb @ W1 + b1) -> LDS
    {
        v8s a[4];
#pragma unroll
        for (int ko = 0; ko < 4; ko++)
            a[ko] = valid ? *(const v8s*)(hpreb + (size_t)arow * 128 + ko*32 + q*8) : z;
        v4f acc = {0.f, 0.f, 0.f, 0.f};
#pragma unroll
        for (int ko = 0; ko < 4; ko++){
            v8s b = *(const v8s*)(W1T + (size_t)col * 128 + ko*32 + q*8);
            acc = __builtin_amdgcn_mfma_f32_16x16x32_bf16(a[ko], b, acc, 0, 0, 0);
        }
        float bv = b1[col];
#pragma unroll
        for (int r = 0; r < 4; r++)
            hsh[(q*4 + r)*72 + col] = f2bf(fmaxf(acc[r] + bv, 0.f));
    }
    __syncthreads();
    // GEMM2 (quadrant w): x_new cols [w*16,w*16+16) = relu(h @ W2 + b2)
    {
        v8s a2[2];
#pragma unroll
        for (int ko = 0; ko < 2; ko++)
            a2[ko] = *(const v8s*)(&hsh[m*72 + ko*32 + q*8]);
        v4f acc = {0.f, 0.f, 0.f, 0.f};
#pragma unroll
        for (int ko = 0; ko < 2; ko++){
            v8s b = *(const v8s*)(W2T + (size_t)col * 64 + ko*32 + q*8);
            acc = __builtin_amdgcn_mfma_f32_16x16x32_bf16(a2[ko], b, acc, 0, 0, 0);
        }
        float bv = b2[col];
#pragma unroll
        for (int r = 0; r < 4; r++){
            int orow = rbase + q*4 + r;
            if (orow < n){
                unsigned short v = f2bf(fmaxf(acc[r] + bv, 0.f));
                if (do_whp) xsh[(q*4 + r)*132 + col] = v;
                else        xcb_nxt[(size_t)orow * 128 + col] = v;
            }
        }
    }

    if (do_whp){
        __syncthreads();   // xsh complete (GEMM2 + GEMM3 from all waves)
        // GEMM4 (quadrant w): xw = [x_new|s_new] @ whpW + b, pooled by graph
        v8s a4[4];
#pragma unroll
        for (int ko = 0; ko < 4; ko++)
            a4[ko] = *(const v8s*)(&xsh[m*132 + ko*32 + q*8]);
        int bb[4];
#pragma unroll
        for (int r = 0; r < 4; r++){
            int orow = rbase + q*4 + r;
            bb[r] = (orow < n) ? batch[orow] : -1;
        }
        v4f acc = {0.f, 0.f, 0.f, 0.f};
#pragma unroll
        for (int ko = 0; ko < 4; ko++){
            v8s b = *(const v8s*)(whpWT + (size_t)col * 128 + ko*32 + q*8);
            acc = __builtin_amdgcn_mfma_f32_16x16x32_bf16(a4[ko], b, acc, 0, 0, 0);
        }
        float bv = whpb[col];
#pragma unroll
        for (int r = 0; r < 4; r++){
            if (bb[r] >= 0){
                float val = acc[r] + bv;
                if (useLds) atomicAdd(&gacc[(bb[r] - bmin) * 64 + col], val);
                else        atomicAdd(&gbuf[(size_t)bb[r] * 64 + col], val);
            }
        }
        __syncthreads();
        if (useLds){
            for (int i = tid; i < span * 64; i += 256)
                atomicAdd(&gbuf[(size_t)(bmin + (i >> 6)) * 64 + (i & 63)], gacc[i]);
        }
    }
}

// ---------------- head ----------------------------------------------------
__global__ __launch_bounds__(256) void head_kernel(
        const float* __restrict__ g, const float* __restrict__ postW,
        const float* __restrict__ postb, const float* __restrict__ roW,
        const float* __restrict__ rob, float* __restrict__ out, int ngraph)
{
    int gr = __builtin_amdgcn_readfirstlane(blockIdx.x * 4 + (threadIdx.x >> 6));
    int lane = threadIdx.x & 63;
    if (gr >= ngraph) return;
    float gv = g[(size_t)gr*64 + lane];
    float t = postb[lane];
    for (int k = 0; k < 64; k++){
        float a = __shfl(gv, k);
        t = fmaf(a, postW[k*64 + lane], t);
    }
    t = fmaxf(t, 0.f);
    float lg = (lane < NCLS) ? rob[lane] : 0.f;
    for (int k = 0; k < 64; k++){
        float a = __shfl(t, k);
        float w = (lane < NCLS) ? roW[k*NCLS + lane] : 0.f;
        lg = fmaf(a, w, lg);
    }
    float m = (lane < NCLS) ? lg : -INFINITY;
#pragma unroll
    for (int d = 1; d < 16; d <<= 1) m = fmaxf(m, __shfl_xor(m, d, 16));
    float ex = (lane < NCLS) ? expf(lg - m) : 0.f;
    float ssum = ex;
#pragma unroll
    for (int d = 1; d < 16; d <<= 1) ssum += __shfl_xor(ssum, d, 16);
    if (lane < NCLS) out[(size_t)gr*NCLS + lane] = lg - m - logf(ssum);
}

// ---------------- launch --------------------------------------------------
extern "C" void kernel_launch(void* const* d_in, const int* in_sizes, int n_in,
                              void* d_out, int out_size, void* d_ws, size_t ws_size,
                              hipStream_t stream) {
    const float* x      = (const float*)d_in[0];
    const float* s      = (const float*)d_in[1];
    const int*   ei     = (const int*)d_in[2];    // int32
    const int*   batch  = (const int*)d_in[3];    // int32
    const float* pre_W  = (const float*)d_in[4];
    const float* pre_b  = (const float*)d_in[5];
    const float* emb_W  = (const float*)d_in[6];
    const float* emb_b  = (const float*)d_in[7];
    const float* gin_W1 = (const float*)d_in[8];
    const float* gin_b1 = (const float*)d_in[9];
    const float* gin_W2 = (const float*)d_in[10];
    const float* gin_b2 = (const float*)d_in[11];
    const float* gcn_W  = (const float*)d_in[12];
    const float* gcn_b  = (const float*)d_in[13];
    const float* whp_W  = (const float*)d_in[14];
    const float* whp_b  = (const float*)d_in[15];
    const float* post_W = (const float*)d_in[16];
    const float* post_b = (const float*)d_in[17];
    const float* ro_W   = (const float*)d_in[18];
    const float* ro_b   = (const float*)d_in[19];
    float* out = (float*)d_out;

    char* w = (char*)d_ws;
    auto alloc = [&](size_t bytes) -> void* {
        void* p = (void*)w;
        w += (bytes + 255) & ~(size_t)255;
        return p;
    };
    int*   off   = (int*)  alloc((size_t)(NN+1) * 4);
    int*   csr   = (int*)  alloc((size_t)NE * 4);
    int*   ghist = (int*)  alloc((size_t)NCH * CB * 4);
    unsigned int* ebuf = (unsigned int*)alloc((size_t)NE * 4);
    float* dinv = (float*)alloc((size_t)NN * 4);
    unsigned short* xcb0 = (unsigned short*)alloc((size_t)NN * 128 * 2);
    unsigned short* xcb1 = (unsigned short*)alloc((size_t)NN * 128 * 2);
    unsigned int*   hpreb = (unsigned int*)alloc((size_t)NN * 64 * 4);  // bf16 [n,128]
    unsigned int*   ub    = (unsigned int*)alloc((size_t)NN * 32 * 4);  // bf16 [n,64]
    float* gbuf = (float*)alloc((size_t)NG * 64 * 4);
    unsigned short* gcnWT = (unsigned short*)alloc((size_t)3 * 4096 * 2);
    unsigned short* W1T   = (unsigned short*)alloc((size_t)3 * 8192 * 2);
    unsigned short* W2T   = (unsigned short*)alloc((size_t)3 * 4096 * 2);
    unsigned short* whpWT = (unsigned short*)alloc((size_t)8192 * 2);

    const int B   = 256;
    const int GL  = (NN + 63) / 64;        // 782  (pre_emb blocks in bin_pre)
    const int GT  = (NN + 15) / 16;        // 3125 (ginmlp3 16-row tiles)
    const int GA  = (NN + 3) / 4;          // 12500
    const int GZB = (NG*64 + 255) / 256;   // 126

    // fused prep (wprep + coarse_hist + gbuf zero), then scan, then fused
    // bin+pre_emb (union'd dynamic LDS = 38912B), then scatter.
    k_prep<<<224 + NCH + GZB, B, 0, stream>>>(gcn_W, gin_W1, gin_W2, whp_W,
                                              gcnWT, W1T, W2T, whpWT,
                                              ei + NE, ghist, gbuf);
    coarse_scan<<<1, B, 0, stream>>>(ghist);
    bin_pre<<<NCH + GL, B, 38912, stream>>>(ei, ei + NE, ghist, ebuf,
                                            x, pre_W, pre_b, s, emb_W, emb_b,
                                            xcb0, NN);
    scatter_all<<<CB, B, 0, stream>>>(ebuf, ghist, off, dinv, csr, NN);

    for (int i = 0; i < NLAY; i++){
        unsigned short* cur = (i & 1) ? xcb1 : xcb0;
        unsigned short* nxt = (i & 1) ? xcb0 : xcb1;
        merged_agg<<<GA, B, 0, stream>>>((const unsigned int*)cur, dinv, off, csr,
                                         hpreb, ub, NN);
        ginmlp3<<<GT, B, 0, stream>>>((const unsigned short*)hpreb,
                                      (const unsigned short*)ub,
                                      W1T + (size_t)i*8192, gin_b1 + i*64,
                                      W2T + (size_t)i*4096, gin_b2 + i*64,
                                      gcnWT + (size_t)i*4096, gcn_b + i*64,
                                      nxt,
                                      whpWT, whp_b, batch, gbuf,
                                      (i == NLAY - 1) ? 1 : 0, NN);
    }

    // pool already fused into last ginmlp3; head reads gbuf
    head_kernel<<<(NG + 3)/4, B, 0, stream>>>(gbuf, post_W, post_b, ro_W, ro_b, out, NG);
}

// Round 11
// 315.085 us; speedup vs baseline: 1.5090x; 1.1386x over previous
//
#include <hip/hip_runtime.h>
#include <math.h>

#define NN   50000
#define NE   800000
#define FEATD 128
#define SED  16
#define HD   64
#define NCLS 10
#define NLAY 3
#define NG   500

// two-level counting sort params
#define CHUNK 4096
#define NCH   ((NE + CHUNK - 1) / CHUNK)  // 196
#define CBSH  9
#define CB    ((NN + (1 << CBSH) - 1) >> CBSH)  // 98

typedef short  v8s __attribute__((ext_vector_type(8)));
typedef float  v4f __attribute__((ext_vector_type(4)));

// ---- bf16 helpers ---------------------------------------------------------
__device__ inline unsigned short f2bf(float f){
    unsigned int u = __float_as_uint(f);
    u += 0x7fffu + ((u >> 16) & 1u);
    return (unsigned short)(u >> 16);
}
__device__ inline unsigned int pack2bf(float a, float b){
    return (unsigned int)f2bf(a) | ((unsigned int)f2bf(b) << 16);
}
__device__ inline float bf_lo(unsigned int p){ return __uint_as_float(p << 16); }
__device__ inline float bf_hi(unsigned int p){ return __uint_as_float(p & 0xffff0000u); }

// fast tanh via v_exp (accuracy ~1e-7 rel, far below bf16 storage error)
__device__ inline float fast_tanh(float x){
    float ax = fabsf(x);
    float t  = __expf(-2.f * ax);
    float r  = (1.f - t) / (1.f + t);
    return copysignf(r, x);
}

// ---------------- fused prep: weight transpose + coarse hist + gbuf zero ---
// Weights are written in MFMA FRAGMENT ORDER: element W[k][col] lands at
//   (((col/16)*NKO + k/32)*4 + (k/8)%4)*16 + (col%16))*8 + (k%8)
// so a wave's v8s fragment load for (ct,ko) is base + lane*16B -- fully
// coalesced (the old [col][k] layout made every fragment load a 16-line
// gather: lane stride 256B; R9/R10 counters showed ginmlp3 stuck ~41-44us
// with everything idle -- request-stream-bound, not latency-bound).
// blocks [0,224): wprep; [224,224+NCH): coarse_hist; rest: zero gbuf.
__global__ __launch_bounds__(256) void k_prep(
        const float* __restrict__ gcn_W, const float* __restrict__ gin_W1,
        const float* __restrict__ gin_W2, const float* __restrict__ whp_W,
        unsigned short* __restrict__ gcnWF, unsigned short* __restrict__ W1F,
        unsigned short* __restrict__ W2F,  unsigned short* __restrict__ whpWF,
        const int* __restrict__ dst, int* __restrict__ ghist,
        float* __restrict__ gbuf)
{
    __shared__ int h[CB];
    int b = blockIdx.x;
    if (b < 224){
        int i = b*256 + threadIdx.x;
        if (i < 12288){            // gcn: 3 x [64][64], NKO=2
            int li = i / 4096, r = i % 4096, k = r >> 6, col = r & 63;
            int dfr = (((((col>>4)*2 + (k>>5))*4 + ((k>>3)&3))*16 + (col&15))<<3) + (k&7);
            gcnWF[li*4096 + dfr] = f2bf(gcn_W[li*4096 + k*64 + col]);
        } else if (i < 36864){     // W1: 3 x [128][64], NKO=4
            int j = i - 12288; int li = j / 8192, r = j % 8192, k = r >> 6, col = r & 63;
            int dfr = (((((col>>4)*4 + (k>>5))*4 + ((k>>3)&3))*16 + (col&15))<<3) + (k&7);
            W1F[li*8192 + dfr] = f2bf(gin_W1[li*8192 + k*64 + col]);
        } else if (i < 49152){     // W2: 3 x [64][64], NKO=2
            int j = i - 36864; int li = j / 4096, r = j % 4096, k = r >> 6, col = r & 63;
            int dfr = (((((col>>4)*2 + (k>>5))*4 + ((k>>3)&3))*16 + (col&15))<<3) + (k&7);
            W2F[li*4096 + dfr] = f2bf(gin_W2[li*4096 + k*64 + col]);
        } else if (i < 57344){     // whp: [128][64], NKO=4
            int j = i - 49152; int k = j >> 6, col = j & 63;
            int dfr = (((((col>>4)*4 + (k>>5))*4 + ((k>>3)&3))*16 + (col&15))<<3) + (k&7);
            whpWF[dfr] = f2bf(whp_W[k*64 + col]);
        }
    } else if (b < 224 + NCH){
        int c = b - 224;
        for (int i = threadIdx.x; i < CB; i += 256) h[i] = 0;
        __syncthreads();
        int base = c * CHUNK;
        int end  = base + CHUNK; if (end > NE) end = NE;
        for (int i = base + threadIdx.x; i < end; i += 256)
            atomicAdd(&h[dst[i] >> CBSH], 1);
        __syncthreads();
        for (int i = threadIdx.x; i < CB; i += 256)
            ghist[(size_t)c * CB + i] = h[i];
    } else {
        int i = (b - 224 - NCH)*256 + threadIdx.x;
        if (i < NG*64) gbuf[i] = 0.f;
    }
}

// LDS-staged scan of ghist (196*98 ints = 77KB LDS); single-block kernel.
__global__ __launch_bounds__(256) void coarse_scan(int* __restrict__ ghist){
    __shared__ int sh[NCH * CB];
    __shared__ int sc[256];
    int t = threadIdx.x;
    for (int i = t; i < NCH * CB; i += 256) sh[i] = ghist[i];
    __syncthreads();
    int run = 0;
    if (t < CB){
        for (int c = 0; c < NCH; c++){
            int v = sh[c*CB + t];
            sh[c*CB + t] = run;
            run += v;
        }
    }
    sc[t] = (t < CB) ? run : 0;
    __syncthreads();
    for (int d = 1; d < 256; d <<= 1){
        int u = (t >= d) ? sc[t-d] : 0;
        __syncthreads();
        sc[t] += u;
        __syncthreads();
    }
    int bstart = (t == 0) ? 0 : sc[t-1];
    if (t < CB){
        for (int c = 0; c < NCH; c++) sh[c*CB + t] += bstart;
    }
    __syncthreads();
    for (int i = t; i < NCH * CB; i += 256) ghist[i] = sh[i];
}

// ---------------- fused: bin_lds (blocks [0,NCH)) + pre_emb (rest) ---------
// Union'd dynamic LDS: bin needs 35360B, pre needs 38912B -> launch with 38912.
__global__ __launch_bounds__(256) void bin_pre(
        const int* __restrict__ src, const int* __restrict__ dstp,
        const int* __restrict__ ghist, unsigned int* __restrict__ ebuf,
        const float* __restrict__ x, const float* __restrict__ preW,
        const float* __restrict__ preb,
        const float* __restrict__ s, const float* __restrict__ embW,
        const float* __restrict__ embb,
        unsigned short* __restrict__ xcb, int n)
{
    extern __shared__ char smem[];
    int t = threadIdx.x;
    if (blockIdx.x < NCH){
        // ---- bin_lds ----
        unsigned int* lbuf  = (unsigned int*)smem;
        unsigned int* lbuf2 = lbuf + CHUNK;
        int* hist   = (int*)(lbuf2 + CHUNK);
        int* lstart = hist + CB;
        int* cursor = lstart + CB;
        int* gbase  = cursor + CB;
        int* sc     = gbase + CB;
        int c = blockIdx.x;
        for (int i = t; i < CB; i += 256){
            hist[i] = 0;
            gbase[i] = ghist[(size_t)c*CB + i];
        }
        __syncthreads();
        int base = c * CHUNK;
        int nend = base + CHUNK; if (nend > NE) nend = NE;
        nend -= base;
        for (int i = t; i < nend; i += 256){
            int d = dstp[base + i];
            lbuf[i] = (unsigned int)src[base + i] | ((unsigned int)d << 16);
            atomicAdd(&hist[d >> CBSH], 1);
        }
        __syncthreads();
        sc[t] = (t < CB) ? hist[t] : 0;
        __syncthreads();
        for (int d = 1; d < 256; d <<= 1){
            int u = (t >= d) ? sc[t-d] : 0;
            __syncthreads();
            sc[t] += u;
            __syncthreads();
        }
        if (t < CB){
            lstart[t] = sc[t] - hist[t];
            cursor[t] = sc[t] - hist[t];
        }
        __syncthreads();
        for (int i = t; i < nend; i += 256){
            unsigned int u = lbuf[i];
            int b = (int)(u >> 16) >> CBSH;
            int p = atomicAdd(&cursor[b], 1);
            lbuf2[p] = u;
        }
        __syncthreads();
        for (int p = t; p < nend; p += 256){
            unsigned int u = lbuf2[p];
            int b = (int)(u >> 16) >> CBSH;
            ebuf[gbase[b] + (p - lstart[b])] = u;
        }
    } else {
        // ---- pre_emb ----
        float* atx = (float*)smem;        // 64*132
        float* ats = atx + 64*132;        // 64*20
        int r0 = (blockIdx.x - NCH) * 64;
        for (int idx = t; idx < 64 * 32; idx += 256){
            int row = idx >> 5, kq = idx & 31;
            float4 v = make_float4(0.f, 0.f, 0.f, 0.f);
            if (r0 + row < n) v = *(const float4*)(x + (size_t)(r0 + row) * 128 + kq * 4);
            *(float4*)(&atx[row * 132 + kq * 4]) = v;
        }
        for (int idx = t; idx < 64 * 4; idx += 256){
            int row = idx >> 2, kq = idx & 3;
            float4 v = make_float4(0.f, 0.f, 0.f, 0.f);
            if (r0 + row < n) v = *(const float4*)(s + (size_t)(r0 + row) * 16 + kq * 4);
            *(float4*)(&ats[row * 20 + kq * 4]) = v;
        }
        __syncthreads();
        int lane = t & 63;
        int c0 = __builtin_amdgcn_readfirstlane((t >> 6) << 4);
        int row = r0 + lane;
        if (row >= n) return;
        float acc[16];
#pragma unroll
        for (int j = 0; j < 16; j++) acc[j] = 0.f;
        for (int k = 0; k < 128; k += 4){
            float4 av = *(const float4*)(&atx[lane * 132 + k]);
            float aa[4] = {av.x, av.y, av.z, av.w};
#pragma unroll
            for (int kk = 0; kk < 4; kk++){
                const float* wr = preW + (k + kk) * 64 + c0;
#pragma unroll
                for (int j = 0; j < 16; j++)
                    acc[j] = fmaf(aa[kk], wr[j], acc[j]);
            }
        }
#pragma unroll
        for (int j = 0; j < 16; j++) acc[j] += preb[c0 + j];
        unsigned int pk[8];
#pragma unroll
        for (int j = 0; j < 8; j++) pk[j] = pack2bf(acc[2*j], acc[2*j+1]);
        {
            unsigned short* ob = xcb + (size_t)row * 128 + c0;
            uint4 u0; u0.x = pk[0]; u0.y = pk[1]; u0.z = pk[2]; u0.w = pk[3];
            uint4 u1; u1.x = pk[4]; u1.y = pk[5]; u1.z = pk[6]; u1.w = pk[7];
            *(uint4*)(ob)     = u0;
            *(uint4*)(ob + 8) = u1;
        }
#pragma unroll
        for (int j = 0; j < 16; j++) acc[j] = 0.f;
        for (int k = 0; k < 16; k += 4){
            float4 av = *(const float4*)(&ats[lane * 20 + k]);
            float aa[4] = {av.x, av.y, av.z, av.w};
#pragma unroll
            for (int kk = 0; kk < 4; kk++){
                const float* wr = embW + (k + kk) * 64 + c0;
#pragma unroll
                for (int j = 0; j < 16; j++)
                    acc[j] = fmaf(aa[kk], wr[j], acc[j]);
            }
        }
#pragma unroll
        for (int j = 0; j < 16; j++) acc[j] += embb[c0 + j];
#pragma unroll
        for (int j = 0; j < 8; j++) pk[j] = pack2bf(acc[2*j], acc[2*j+1]);
        {
            unsigned short* ob = xcb + (size_t)row * 128 + 64 + c0;
            uint4 u0; u0.x = pk[0]; u0.y = pk[1]; u0.z = pk[2]; u0.w = pk[3];
            uint4 u1; u1.x = pk[4]; u1.y = pk[5]; u1.z = pk[6]; u1.w = pk[7];
            *(uint4*)(ob)     = u0;
            *(uint4*)(ob + 8) = u1;
        }
    }
}

__global__ __launch_bounds__(256) void scatter_all(
        const unsigned int* __restrict__ ebuf, const int* __restrict__ ghist,
        int* __restrict__ off, float* __restrict__ dinv,
        int* __restrict__ csr, int n){
    __shared__ int lcnt[512];
    __shared__ int lex[512];
    __shared__ int sc[256];
    int t = threadIdx.x, b = blockIdx.x;
    int n0 = b << CBSH;
    int nn = n - n0; if (nn > 512) nn = 512;
    int lo = ghist[b];
    int hi = (b + 1 < CB) ? ghist[b + 1] : NE;
    lcnt[t] = 0; lcnt[t + 256] = 0;
    __syncthreads();
    for (int j = lo + t; j < hi; j += 256)
        atomicAdd(&lcnt[(int)(ebuf[j] >> 16) - n0], 1);
    __syncthreads();
    int c0 = lcnt[2*t], c1 = lcnt[2*t+1];
    sc[t] = c0 + c1;
    __syncthreads();
    for (int d = 1; d < 256; d <<= 1){
        int u = (t >= d) ? sc[t-d] : 0;
        __syncthreads();
        sc[t] += u;
        __syncthreads();
    }
    int bse = sc[t] - (c0 + c1);
    lex[2*t]   = bse;
    lex[2*t+1] = bse + c0;
    __syncthreads();
    for (int i = t; i < nn; i += 256){
        off[n0 + i]  = lo + lex[i];
        dinv[n0 + i] = rsqrtf((float)lcnt[i] + 1.0f);
    }
    if (b == 0 && t == 0) off[n] = NE;
    __syncthreads();
    for (int j = lo + t; j < hi; j += 256){
        unsigned int u = ebuf[j];
        int d = (int)(u >> 16) - n0;
        int p = atomicAdd(&lex[d], 1);
        csr[lo + p] = (int)(u & 0xffffu);
    }
}

// ---------------- merged aggregation: ONE gather feeds GIN + GCN -----------
// 8-edge unrolled main loop: 8 gathers + 8 dinv in flight per waitcnt drain.
__global__ __launch_bounds__(256) void merged_agg(
        const unsigned int* __restrict__ xcb_cur,
        const float* __restrict__ dinv,
        const int* __restrict__ off, const int* __restrict__ csr,
        unsigned int* __restrict__ hpreb, unsigned int* __restrict__ ub, int n)
{
    int node = __builtin_amdgcn_readfirstlane(blockIdx.x * 4 + (threadIdx.x >> 6));
    int lane = threadIdx.x & 63;
    if (node >= n) return;
    int beg = off[node], end = off[node+1];
    unsigned int ps = xcb_cur[(size_t)node*64 + lane];
    float s0f = bf_lo(ps), s1f = bf_hi(ps);
    float a0 = s0f, a1 = s1f;
    float g0 = 0.f, g1 = 0.f;
    int e = beg;
    for (; e + 8 <= end; e += 8){
        int s0 = csr[e],   s1 = csr[e+1], s2 = csr[e+2], s3 = csr[e+3];
        int s4 = csr[e+4], s5 = csr[e+5], s6 = csr[e+6], s7 = csr[e+7];
        unsigned int p0 = xcb_cur[(size_t)s0*64 + lane];
        unsigned int p1 = xcb_cur[(size_t)s1*64 + lane];
        unsigned int p2 = xcb_cur[(size_t)s2*64 + lane];
        unsigned int p3 = xcb_cur[(size_t)s3*64 + lane];
        unsigned int p4 = xcb_cur[(size_t)s4*64 + lane];
        unsigned int p5 = xcb_cur[(size_t)s5*64 + lane];
        unsigned int p6 = xcb_cur[(size_t)s6*64 + lane];
        unsigned int p7 = xcb_cur[(size_t)s7*64 + lane];
        float d0 = dinv[s0], d1 = dinv[s1], d2 = dinv[s2], d3 = dinv[s3];
        float d4 = dinv[s4], d5 = dinv[s5], d6 = dinv[s6], d7 = dinv[s7];
        float v0 = bf_lo(p0), v1 = bf_lo(p1), v2 = bf_lo(p2), v3 = bf_lo(p3);
        float v4 = bf_lo(p4), v5 = bf_lo(p5), v6 = bf_lo(p6), v7 = bf_lo(p7);
        float w0 = bf_hi(p0), w1 = bf_hi(p1), w2 = bf_hi(p2), w3 = bf_hi(p3);
        float w4 = bf_hi(p4), w5 = bf_hi(p5), w6 = bf_hi(p6), w7 = bf_hi(p7);
        a0 += ((v0 + v1) + (v2 + v3)) + ((v4 + v5) + (v6 + v7));
        a1 += ((w0 + w1) + (w2 + w3)) + ((w4 + w5) + (w6 + w7));
        float ga = fmaf(d0, v0, fmaf(d1, v1, fmaf(d2, v2, d3*v3)));
        float gb = fmaf(d4, v4, fmaf(d5, v5, fmaf(d6, v6, d7*v7)));
        g0 += ga + gb;
        float gc = fmaf(d0, w0, fmaf(d1, w1, fmaf(d2, w2, d3*w3)));
        float gd = fmaf(d4, w4, fmaf(d5, w5, fmaf(d6, w6, d7*w7)));
        g1 += gc + gd;
    }
    for (; e + 4 <= end; e += 4){
        int s0 = csr[e], s1 = csr[e+1], s2 = csr[e+2], s3 = csr[e+3];
        unsigned int p0 = xcb_cur[(size_t)s0*64 + lane];
        unsigned int p1 = xcb_cur[(size_t)s1*64 + lane];
        unsigned int p2 = xcb_cur[(size_t)s2*64 + lane];
        unsigned int p3 = xcb_cur[(size_t)s3*64 + lane];
        float d0 = dinv[s0], d1 = dinv[s1], d2 = dinv[s2], d3 = dinv[s3];
        float v0 = bf_lo(p0), v1 = bf_lo(p1), v2 = bf_lo(p2), v3 = bf_lo(p3);
        float w0 = bf_hi(p0), w1 = bf_hi(p1), w2 = bf_hi(p2), w3 = bf_hi(p3);
        a0 += (v0 + v1) + (v2 + v3);
        a1 += (w0 + w1) + (w2 + w3);
        g0 = fmaf(d0, v0, fmaf(d1, v1, fmaf(d2, v2, fmaf(d3, v3, g0))));
        g1 = fmaf(d0, w0, fmaf(d1, w1, fmaf(d2, w2, fmaf(d3, w3, g1))));
    }
    for (; e < end; e++){
        int s0 = csr[e];
        unsigned int p0 = xcb_cur[(size_t)s0*64 + lane];
        float d0 = dinv[s0];
        float v0 = bf_lo(p0), w0 = bf_hi(p0);
        a0 += v0; a1 += w0;
        g0 = fmaf(d0, v0, g0);
        g1 = fmaf(d0, w0, g1);
    }
    hpreb[(size_t)node*64 + lane] = pack2bf(a0, a1);
    if (lane >= 32){   // lanes 32..63 hold s_prev cols (64..127)
        float di = dinv[node];
        float u0 = fmaf(di, g0, di*di*s0f);
        float u1 = fmaf(di, g1, di*di*s1f);
        ub[(size_t)node*32 + (lane - 32)] = pack2bf(u0, u1);
    }
}

// ---------------- fused per-layer MFMA: GIN MLP + GCN linear ---------------
// 16-row blocks, wave w owns output quadrant ct=w. ALL memory access is now
// coalesced: A-tiles (hpreb/ub) staged to LDS via one uint4 pass; weights
// read directly from global in fragment order (lane*16B); outputs staged in
// xsh and written back as one uint4 pass. (R9/R10: direct-from-global MFMA
// fragments were 256B-lane-stride 16-line gathers -> request-bound ~41us.)
// do_whp (last layer): GEMM4 from xsh + pooled atomics, no xcb round trip.
__global__ __launch_bounds__(256) void ginmlp3(
        const unsigned short* __restrict__ hpreb,   // [n,128] bf16 row-major
        const unsigned short* __restrict__ ub,      // [n,64]  bf16 row-major
        const unsigned short* __restrict__ W1F,     // frag order, K=128
        const float* __restrict__ b1,
        const unsigned short* __restrict__ W2F,     // frag order, K=64
        const float* __restrict__ b2,
        const unsigned short* __restrict__ gcnWF,   // frag order, K=64
        const float* __restrict__ gcnb,
        unsigned short* __restrict__ xcb_nxt,
        const unsigned short* __restrict__ whpWF,   // frag order, K=128
        const float* __restrict__ whpb,
        const int* __restrict__ batch,
        float* __restrict__ gbuf,
        int do_whp, int n)
{
    __shared__ unsigned short ash[16 * 136];   // hpreb tile, 272B rows (16B-mult)
    __shared__ unsigned short bsh[16 * 72];    // ub tile, 144B rows
    __shared__ unsigned short hsh[16 * 72];    // GEMM1 output
    __shared__ unsigned short xsh[16 * 136];   // [x_new|s_new] tile
    __shared__ float gacc[8 * 64];
    int tid = threadIdx.x;
    int w = tid >> 6, l = tid & 63;
    int m = l & 15, q = l >> 4;
    int rbase = blockIdx.x * 16;
    int col   = w*16 + m;

    // ---- stage A-tiles (coalesced uint4) ----
    {
        int row = tid >> 4, ch = tid & 15;   // 16 rows x 16 chunks of 8 shorts
        int orow = rbase + row;
        uint4 v = make_uint4(0,0,0,0);
        if (orow < n) v = *(const uint4*)(hpreb + (size_t)orow * 128 + ch*8);
        *(uint4*)(&ash[row*136 + ch*8]) = v;
    }
    if (tid < 128){
        int row = tid >> 3, ch = tid & 7;    // 16 rows x 8 chunks of 8 shorts
        int orow = rbase + row;
        uint4 v = make_uint4(0,0,0,0);
        if (orow < n) v = *(const uint4*)(ub + (size_t)orow * 64 + ch*8);
        *(uint4*)(&bsh[row*72 + ch*8]) = v;
    }
    int bmin = 0, span = 0;
    bool useLds = false;
    if (do_whp){
        int rmax = rbase + 15; if (rmax > n - 1) rmax = n - 1;
        bmin = batch[rbase];
        span = batch[rmax] - bmin + 1;
        useLds = (span <= 8);
        if (useLds)
            for (int i = tid; i < span * 64; i += 256) gacc[i] = 0.f;
    }
    __syncthreads();

    // GEMM3 (quadrant w): s_new = tanh(ub @ gcnW + b) -> xsh cols 64+
    {
        v8s a3[2];
#pragma unroll
        for (int ko = 0; ko < 2; ko++)
            a3[ko] = *(const v8s*)(&bsh[m*72 + ko*32 + q*8]);
        v4f acc = {0.f, 0.f, 0.f, 0.f};
#pragma unroll
        for (int ko = 0; ko < 2; ko++){
            v8s b = *(const v8s*)(gcnWF + (size_t)((w*2 + ko)*64 + l) * 8);
            acc = __builtin_amdgcn_mfma_f32_16x16x32_bf16(a3[ko], b, acc, 0, 0, 0);
        }
        float bv = gcnb[col];
#pragma unroll
        for (int r = 0; r < 4; r++)
            xsh[(q*4 + r)*136 + 64 + col] = f2bf(fast_tanh(acc[r] + bv));
    }
    // GEMM1 (quadrant w): h = relu(hpreb @ W1 + b1) -> hsh
    {
        v8s a[4];
#pragma unroll
        for (int ko = 0; ko < 4; ko++)
            a[ko] = *(const v8s*)(&ash[m*136 + ko*32 + q*8]);
        v4f acc = {0.f, 0.f, 0.f, 0.f};
#pragma unroll
        for (int ko = 0; ko < 4; ko++){
            v8s b = *(const v8s*)(W1F + (size_t)((w*4 + ko)*64 + l) * 8);
            acc = __builtin_amdgcn_mfma_f32_16x16x32_bf16(a[ko], b, acc, 0, 0, 0);
        }
        float bv = b1[col];
#pragma unroll
        for (int r = 0; r < 4; r++)
            hsh[(q*4 + r)*72 + col] = f2bf(fmaxf(acc[r] + bv, 0.f));
    }
    __syncthreads();
    // GEMM2 (quadrant w): x_new = relu(h @ W2 + b2) -> xsh cols 0..63
    {
        v8s a2[2];
#pragma unroll
        for (int ko = 0; ko < 2; ko++)
            a2[ko] = *(const v8s*)(&hsh[m*72 + ko*32 + q*8]);
        v4f acc = {0.f, 0.f, 0.f, 0.f};
#pragma unroll
        for (int ko = 0; ko < 2; ko++){
            v8s b = *(const v8s*)(W2F + (size_t)((w*2 + ko)*64 + l) * 8);
            acc = __builtin_amdgcn_mfma_f32_16x16x32_bf16(a2[ko], b, acc, 0, 0, 0);
        }
        float bv = b2[col];
#pragma unroll
        for (int r = 0; r < 4; r++)
            xsh[(q*4 + r)*136 + col] = f2bf(fmaxf(acc[r] + bv, 0.f));
    }
    __syncthreads();   // xsh complete (GEMM2 cols 0-63 + GEMM3 cols 64-127)

    if (!do_whp){
        // coalesced writeback: 16 rows x 256B, one uint4 per thread
        int row = tid >> 4, ch = tid & 15;
        int orow = rbase + row;
        if (orow < n)
            *(uint4*)(xcb_nxt + (size_t)orow * 128 + ch*8) =
                *(const uint4*)(&xsh[row*136 + ch*8]);
    } else {
        // GEMM4 (quadrant w): xw = [x_new|s_new] @ whpW + b, pooled by graph
        v8s a4[4];
#pragma unroll
        for (int ko = 0; ko < 4; ko++)
            a4[ko] = *(const v8s*)(&xsh[m*136 + ko*32 + q*8]);
        int bb[4];
#pragma unroll
        for (int r = 0; r < 4; r++){
            int orow = rbase + q*4 + r;
            bb[r] = (orow < n) ? batch[orow] : -1;
        }
        v4f acc = {0.f, 0.f, 0.f, 0.f};
#pragma unroll
        for (int ko = 0; ko < 4; ko++){
            v8s b = *(const v8s*)(whpWF + (size_t)((w*4 + ko)*64 + l) * 8);
            acc = __builtin_amdgcn_mfma_f32_16x16x32_bf16(a4[ko], b, acc, 0, 0, 0);
        }
        float bv = whpb[col];
#pragma unroll
        for (int r = 0; r < 4; r++){
            if (bb[r] >= 0){
                float val = acc[r] + bv;
                if (useLds) atomicAdd(&gacc[(bb[r] - bmin) * 64 + col], val);
                else        atomicAdd(&gbuf[(size_t)bb[r] * 64 + col], val);
            }
        }
        __syncthreads();
        if (useLds){
            for (int i = tid; i < span * 64; i += 256)
                atomicAdd(&gbuf[(size_t)(bmin + (i >> 6)) * 64 + (i & 63)], gacc[i]);
        }
    }
}

// ---------------- head ----------------------------------------------------
__global__ __launch_bounds__(256) void head_kernel(
        const float* __restrict__ g, const float* __restrict__ postW,
        const float* __restrict__ postb, const float* __restrict__ roW,
        const float* __restrict__ rob, float* __restrict__ out, int ngraph)
{
    int gr = __builtin_amdgcn_readfirstlane(blockIdx.x * 4 + (threadIdx.x >> 6));
    int lane = threadIdx.x & 63;
    if (gr >= ngraph) return;
    float gv = g[(size_t)gr*64 + lane];
    float t = postb[lane];
    for (int k = 0; k < 64; k++){
        float a = __shfl(gv, k);
        t = fmaf(a, postW[k*64 + lane], t);
    }
    t = fmaxf(t, 0.f);
    float lg = (lane < NCLS) ? rob[lane] : 0.f;
    for (int k = 0; k < 64; k++){
        float a = __shfl(t, k);
        float w = (lane < NCLS) ? roW[k*NCLS + lane] : 0.f;
        lg = fmaf(a, w, lg);
    }
    float m = (lane < NCLS) ? lg : -INFINITY;
#pragma unroll
    for (int d = 1; d < 16; d <<= 1) m = fmaxf(m, __shfl_xor(m, d, 16));
    float ex = (lane < NCLS) ? expf(lg - m) : 0.f;
    float ssum = ex;
#pragma unroll
    for (int d = 1; d < 16; d <<= 1) ssum += __shfl_xor(ssum, d, 16);
    if (lane < NCLS) out[(size_t)gr*NCLS + lane] = lg - m - logf(ssum);
}

// ---------------- launch --------------------------------------------------
extern "C" void kernel_launch(void* const* d_in, const int* in_sizes, int n_in,
                              void* d_out, int out_size, void* d_ws, size_t ws_size,
                              hipStream_t stream) {
    const float* x      = (const float*)d_in[0];
    const float* s      = (const float*)d_in[1];
    const int*   ei     = (const int*)d_in[2];    // int32
    const int*   batch  = (const int*)d_in[3];    // int32
    const float* pre_W  = (const float*)d_in[4];
    const float* pre_b  = (const float*)d_in[5];
    const float* emb_W  = (const float*)d_in[6];
    const float* emb_b  = (const float*)d_in[7];
    const float* gin_W1 = (const float*)d_in[8];
    const float* gin_b1 = (const float*)d_in[9];
    const float* gin_W2 = (const float*)d_in[10];
    const float* gin_b2 = (const float*)d_in[11];
    const float* gcn_W  = (const float*)d_in[12];
    const float* gcn_b  = (const float*)d_in[13];
    const float* whp_W  = (const float*)d_in[14];
    const float* whp_b  = (const float*)d_in[15];
    const float* post_W = (const float*)d_in[16];
    const float* post_b = (const float*)d_in[17];
    const float* ro_W   = (const float*)d_in[18];
    const float* ro_b   = (const float*)d_in[19];
    float* out = (float*)d_out;

    char* w = (char*)d_ws;
    auto alloc = [&](size_t bytes) -> void* {
        void* p = (void*)w;
        w += (bytes + 255) & ~(size_t)255;
        return p;
    };
    int*   off   = (int*)  alloc((size_t)(NN+1) * 4);
    int*   csr   = (int*)  alloc((size_t)NE * 4);
    int*   ghist = (int*)  alloc((size_t)NCH * CB * 4);
    unsigned int* ebuf = (unsigned int*)alloc((size_t)NE * 4);
    float* dinv = (float*)alloc((size_t)NN * 4);
    unsigned short* xcb0 = (unsigned short*)alloc((size_t)NN * 128 * 2);
    unsigned short* xcb1 = (unsigned short*)alloc((size_t)NN * 128 * 2);
    unsigned int*   hpreb = (unsigned int*)alloc((size_t)NN * 64 * 4);  // bf16 [n,128]
    unsigned int*   ub    = (unsigned int*)alloc((size_t)NN * 32 * 4);  // bf16 [n,64]
    float* gbuf = (float*)alloc((size_t)NG * 64 * 4);
    unsigned short* gcnWF = (unsigned short*)alloc((size_t)3 * 4096 * 2);
    unsigned short* W1F   = (unsigned short*)alloc((size_t)3 * 8192 * 2);
    unsigned short* W2F   = (unsigned short*)alloc((size_t)3 * 4096 * 2);
    unsigned short* whpWF = (unsigned short*)alloc((size_t)8192 * 2);

    const int B   = 256;
    const int GL  = (NN + 63) / 64;        // 782  (pre_emb blocks in bin_pre)
    const int GT  = (NN + 15) / 16;        // 3125 (ginmlp3 16-row tiles)
    const int GA  = (NN + 3) / 4;          // 12500
    const int GZB = (NG*64 + 255) / 256;   // 126

    // fused prep (wprep-frag + coarse_hist + gbuf zero), then scan, then
    // fused bin+pre_emb (union'd dynamic LDS = 38912B), then scatter.
    k_prep<<<224 + NCH + GZB, B, 0, stream>>>(gcn_W, gin_W1, gin_W2, whp_W,
                                              gcnWF, W1F, W2F, whpWF,
                                              ei + NE, ghist, gbuf);
    coarse_scan<<<1, B, 0, stream>>>(ghist);
    bin_pre<<<NCH + GL, B, 38912, stream>>>(ei, ei + NE, ghist, ebuf,
                                            x, pre_W, pre_b, s, emb_W, emb_b,
                                            xcb0, NN);
    scatter_all<<<CB, B, 0, stream>>>(ebuf, ghist, off, dinv, csr, NN);

    for (int i = 0; i < NLAY; i++){
        unsigned short* cur = (i & 1) ? xcb1 : xcb0;
        unsigned short* nxt = (i & 1) ? xcb0 : xcb1;
        merged_agg<<<GA, B, 0, stream>>>((const unsigned int*)cur, dinv, off, csr,
                                         hpreb, ub, NN);
        ginmlp3<<<GT, B, 0, stream>>>((const unsigned short*)hpreb,
                                      (const unsigned short*)ub,
                                      W1F + (size_t)i*8192, gin_b1 + i*64,
                                      W2F + (size_t)i*4096, gin_b2 + i*64,
                                      gcnWF + (size_t)i*4096, gcn_b + i*64,
                                      nxt,
                                      whpWF, whp_b, batch, gbuf,
                                      (i == NLAY - 1) ? 1 : 0, NN);
    }

    // pool already fused into last ginmlp3; head reads gbuf
    head_kernel<<<(NG + 3)/4, B, 0, stream>>>(gbuf, post_W, post_b, ro_W, ro_b, out, NG);
}

// Round 12
// 301.036 us; speedup vs baseline: 1.5794x; 1.0467x over previous
//
#include <hip/hip_runtime.h>
#include <math.h>

#define NN   50000
#define NE   800000
#define FEATD 128
#define SED  16
#define HD   64
#define NCLS 10
#define NLAY 3
#define NG   500

// two-level counting sort params
#define CHUNK 4096
#define NCH   ((NE + CHUNK - 1) / CHUNK)  // 196
#define CBSH  9
#define CB    ((NN + (1 << CBSH) - 1) >> CBSH)  // 98

typedef short  v8s __attribute__((ext_vector_type(8)));
typedef float  v4f __attribute__((ext_vector_type(4)));

// ---- bf16 helpers ---------------------------------------------------------
__device__ inline unsigned short f2bf(float f){
    unsigned int u = __float_as_uint(f);
    u += 0x7fffu + ((u >> 16) & 1u);
    return (unsigned short)(u >> 16);
}
__device__ inline unsigned int pack2bf(float a, float b){
    return (unsigned int)f2bf(a) | ((unsigned int)f2bf(b) << 16);
}
__device__ inline float bf_lo(unsigned int p){ return __uint_as_float(p << 16); }
__device__ inline float bf_hi(unsigned int p){ return __uint_as_float(p & 0xffff0000u); }

// fast tanh via v_exp (accuracy ~1e-7 rel, far below bf16 storage error)
__device__ inline float fast_tanh(float x){
    float ax = fabsf(x);
    float t  = __expf(-2.f * ax);
    float r  = (1.f - t) / (1.f + t);
    return copysignf(r, x);
}

// ---------------- fused prep: weight transposes + coarse hist + gbuf zero --
// All weights emitted in MFMA FRAGMENT ORDER: W[k][col] lands at
//   ((((col/16)*NKO + k/32)*4 + (k/8)%4)*16 + col%16)*8 + k%8
// so a wave's v8s fragment load is base + lane*16B (fully coalesced).
// blocks [0,264): wprep (incl. preWF K=128 and embWF K=16->32 zero-pad);
// [264,264+NCH): coarse_hist; rest: zero gbuf.
__global__ __launch_bounds__(256) void k_prep(
        const float* __restrict__ gcn_W, const float* __restrict__ gin_W1,
        const float* __restrict__ gin_W2, const float* __restrict__ whp_W,
        const float* __restrict__ pre_W, const float* __restrict__ emb_W,
        unsigned short* __restrict__ gcnWF, unsigned short* __restrict__ W1F,
        unsigned short* __restrict__ W2F,  unsigned short* __restrict__ whpWF,
        unsigned short* __restrict__ preWF, unsigned short* __restrict__ embWF,
        const int* __restrict__ dst, int* __restrict__ ghist,
        float* __restrict__ gbuf)
{
    __shared__ int h[CB];
    int b = blockIdx.x;
    if (b < 264){
        int i = b*256 + threadIdx.x;
        if (i < 12288){            // gcn: 3 x [64][64], NKO=2
            int li = i / 4096, r = i % 4096, k = r >> 6, col = r & 63;
            int dfr = (((((col>>4)*2 + (k>>5))*4 + ((k>>3)&3))*16 + (col&15))<<3) + (k&7);
            gcnWF[li*4096 + dfr] = f2bf(gcn_W[li*4096 + k*64 + col]);
        } else if (i < 36864){     // W1: 3 x [128][64], NKO=4
            int j = i - 12288; int li = j / 8192, r = j % 8192, k = r >> 6, col = r & 63;
            int dfr = (((((col>>4)*4 + (k>>5))*4 + ((k>>3)&3))*16 + (col&15))<<3) + (k&7);
            W1F[li*8192 + dfr] = f2bf(gin_W1[li*8192 + k*64 + col]);
        } else if (i < 49152){     // W2: 3 x [64][64], NKO=2
            int j = i - 36864; int li = j / 4096, r = j % 4096, k = r >> 6, col = r & 63;
            int dfr = (((((col>>4)*2 + (k>>5))*4 + ((k>>3)&3))*16 + (col&15))<<3) + (k&7);
            W2F[li*4096 + dfr] = f2bf(gin_W2[li*4096 + k*64 + col]);
        } else if (i < 57344){     // whp: [128][64], NKO=4
            int j = i - 49152; int k = j >> 6, col = j & 63;
            int dfr = (((((col>>4)*4 + (k>>5))*4 + ((k>>3)&3))*16 + (col&15))<<3) + (k&7);
            whpWF[dfr] = f2bf(whp_W[k*64 + col]);
        } else if (i < 65536){     // pre: [128][64], NKO=4
            int j = i - 57344; int k = j >> 6, col = j & 63;
            int dfr = (((((col>>4)*4 + (k>>5))*4 + ((k>>3)&3))*16 + (col&15))<<3) + (k&7);
            preWF[dfr] = f2bf(pre_W[k*64 + col]);
        } else if (i < 67584){     // emb: [16][64] zero-padded to K=32, NKO=1
            int j = i - 65536; int k = j >> 6, col = j & 63;   // k in [0,32)
            int dfr = (((((col>>4)*1 + (k>>5))*4 + ((k>>3)&3))*16 + (col&15))<<3) + (k&7);
            embWF[dfr] = (k < 16) ? f2bf(emb_W[k*64 + col]) : (unsigned short)0;
        }
    } else if (b < 264 + NCH){
        int c = b - 264;
        for (int i = threadIdx.x; i < CB; i += 256) h[i] = 0;
        __syncthreads();
        int base = c * CHUNK;
        int end  = base + CHUNK; if (end > NE) end = NE;
        for (int i = base + threadIdx.x; i < end; i += 256)
            atomicAdd(&h[dst[i] >> CBSH], 1);
        __syncthreads();
        for (int i = threadIdx.x; i < CB; i += 256)
            ghist[(size_t)c * CB + i] = h[i];
    } else {
        int i = (b - 264 - NCH)*256 + threadIdx.x;
        if (i < NG*64) gbuf[i] = 0.f;
    }
}

// LDS-staged scan of ghist (196*98 ints = 77KB LDS); single-block kernel.
__global__ __launch_bounds__(256) void coarse_scan(int* __restrict__ ghist){
    __shared__ int sh[NCH * CB];
    __shared__ int sc[256];
    int t = threadIdx.x;
    for (int i = t; i < NCH * CB; i += 256) sh[i] = ghist[i];
    __syncthreads();
    int run = 0;
    if (t < CB){
        for (int c = 0; c < NCH; c++){
            int v = sh[c*CB + t];
            sh[c*CB + t] = run;
            run += v;
        }
    }
    sc[t] = (t < CB) ? run : 0;
    __syncthreads();
    for (int d = 1; d < 256; d <<= 1){
        int u = (t >= d) ? sc[t-d] : 0;
        __syncthreads();
        sc[t] += u;
        __syncthreads();
    }
    int bstart = (t == 0) ? 0 : sc[t-1];
    if (t < CB){
        for (int c = 0; c < NCH; c++) sh[c*CB + t] += bstart;
    }
    __syncthreads();
    for (int i = t; i < NCH * CB; i += 256) ghist[i] = sh[i];
}

// ---------------- fused: bin_lds (blocks [0,NCH)) + pre_emb MFMA (rest) ----
// Pre blocks: 16-row tiles, 4 waves, wave w = col quadrant. x staged to LDS
// as bf16 (coalesced float4), s zero-padded to K=32; 4+1 MFMA chains/wave;
// xsh-staged coalesced uint4 writeback (same proven shape as ginmlp3).
// Union'd dynamic LDS: bin needs 35360B, pre needs 9984B -> launch 38912.
__global__ __launch_bounds__(256) void bin_pre(
        const int* __restrict__ src, const int* __restrict__ dstp,
        const int* __restrict__ ghist, unsigned int* __restrict__ ebuf,
        const float* __restrict__ x, const unsigned short* __restrict__ preWF,
        const float* __restrict__ preb,
        const float* __restrict__ s, const unsigned short* __restrict__ embWF,
        const float* __restrict__ embb,
        unsigned short* __restrict__ xcb, int n)
{
    extern __shared__ char smem[];
    int t = threadIdx.x;
    if (blockIdx.x < NCH){
        // ---- bin_lds ----
        unsigned int* lbuf  = (unsigned int*)smem;
        unsigned int* lbuf2 = lbuf + CHUNK;
        int* hist   = (int*)(lbuf2 + CHUNK);
        int* lstart = hist + CB;
        int* cursor = lstart + CB;
        int* gbase  = cursor + CB;
        int* sc     = gbase + CB;
        int c = blockIdx.x;
        for (int i = t; i < CB; i += 256){
            hist[i] = 0;
            gbase[i] = ghist[(size_t)c*CB + i];
        }
        __syncthreads();
        int base = c * CHUNK;
        int nend = base + CHUNK; if (nend > NE) nend = NE;
        nend -= base;
        for (int i = t; i < nend; i += 256){
            int d = dstp[base + i];
            lbuf[i] = (unsigned int)src[base + i] | ((unsigned int)d << 16);
            atomicAdd(&hist[d >> CBSH], 1);
        }
        __syncthreads();
        sc[t] = (t < CB) ? hist[t] : 0;
        __syncthreads();
        for (int d = 1; d < 256; d <<= 1){
            int u = (t >= d) ? sc[t-d] : 0;
            __syncthreads();
            sc[t] += u;
            __syncthreads();
        }
        if (t < CB){
            lstart[t] = sc[t] - hist[t];
            cursor[t] = sc[t] - hist[t];
        }
        __syncthreads();
        for (int i = t; i < nend; i += 256){
            unsigned int u = lbuf[i];
            int b = (int)(u >> 16) >> CBSH;
            int p = atomicAdd(&cursor[b], 1);
            lbuf2[p] = u;
        }
        __syncthreads();
        for (int p = t; p < nend; p += 256){
            unsigned int u = lbuf2[p];
            int b = (int)(u >> 16) >> CBSH;
            ebuf[gbase[b] + (p - lstart[b])] = u;
        }
    } else {
        // ---- pre_emb via MFMA ----
        unsigned short* ash = (unsigned short*)smem;   // 16*136 (x tile bf16)
        unsigned short* bsh = ash + 16*136;            // 16*40  (s tile, K pad 32)
        unsigned short* xsh = bsh + 16*40;             // 16*136 (output tile)
        int pblk  = blockIdx.x - NCH;
        int rbase = pblk * 16;
        int w = t >> 6, l = t & 63;
        int m = l & 15, q = l >> 4;
        int col = w*16 + m;
        // zero bsh (incl. K pad), stage x tile coalesced
        for (int i = t; i < 16*40; i += 256) bsh[i] = 0;
#pragma unroll
        for (int j = 0; j < 2; j++){
            int cid = t*2 + j;                  // 512 chunks of 4 floats
            int row = cid >> 5, c4 = cid & 31;
            int orow = rbase + row;
            float4 v = make_float4(0.f, 0.f, 0.f, 0.f);
            if (orow < n) v = *(const float4*)(x + (size_t)orow * 128 + c4*4);
            *(unsigned int*)(&ash[row*136 + c4*4])     = pack2bf(v.x, v.y);
            *(unsigned int*)(&ash[row*136 + c4*4 + 2]) = pack2bf(v.z, v.w);
        }
        __syncthreads();
        // stage s (16 rows x 16 k, coalesced scalar)
        {
            int row = t >> 4, k = t & 15;
            int orow = rbase + row;
            bsh[row*40 + k] = (orow < n) ? f2bf(s[(size_t)orow*16 + k]) : (unsigned short)0;
        }
        __syncthreads();
        // pre GEMM (cols 0..63 quadrant w) + emb GEMM (cols 64..127)
        {
            v8s ap[4];
#pragma unroll
            for (int ko = 0; ko < 4; ko++)
                ap[ko] = *(const v8s*)(&ash[m*136 + ko*32 + q*8]);
            v4f accp = {0.f, 0.f, 0.f, 0.f};
#pragma unroll
            for (int ko = 0; ko < 4; ko++){
                v8s b = *(const v8s*)(preWF + (size_t)((w*4 + ko)*64 + l) * 8);
                accp = __builtin_amdgcn_mfma_f32_16x16x32_bf16(ap[ko], b, accp, 0, 0, 0);
            }
            v8s ae = *(const v8s*)(&bsh[m*40 + q*8]);
            v8s be = *(const v8s*)(embWF + (size_t)(w*64 + l) * 8);
            v4f acce = {0.f, 0.f, 0.f, 0.f};
            acce = __builtin_amdgcn_mfma_f32_16x16x32_bf16(ae, be, acce, 0, 0, 0);
            float bvp = preb[col];
            float bve = embb[col];
#pragma unroll
            for (int r = 0; r < 4; r++){
                xsh[(q*4 + r)*136 + col]      = f2bf(accp[r] + bvp);
                xsh[(q*4 + r)*136 + 64 + col] = f2bf(acce[r] + bve);
            }
        }
        __syncthreads();
        // coalesced writeback
        {
            int row = t >> 4, ch = t & 15;
            int orow = rbase + row;
            if (orow < n)
                *(uint4*)(xcb + (size_t)orow * 128 + ch*8) =
                    *(const uint4*)(&xsh[row*136 + ch*8]);
        }
    }
}

__global__ __launch_bounds__(256) void scatter_all(
        const unsigned int* __restrict__ ebuf, const int* __restrict__ ghist,
        int* __restrict__ off, float* __restrict__ dinv,
        int* __restrict__ csr, int n){
    __shared__ int lcnt[512];
    __shared__ int lex[512];
    __shared__ int sc[256];
    int t = threadIdx.x, b = blockIdx.x;
    int n0 = b << CBSH;
    int nn = n - n0; if (nn > 512) nn = 512;
    int lo = ghist[b];
    int hi = (b + 1 < CB) ? ghist[b + 1] : NE;
    lcnt[t] = 0; lcnt[t + 256] = 0;
    __syncthreads();
    for (int j = lo + t; j < hi; j += 256)
        atomicAdd(&lcnt[(int)(ebuf[j] >> 16) - n0], 1);
    __syncthreads();
    int c0 = lcnt[2*t], c1 = lcnt[2*t+1];
    sc[t] = c0 + c1;
    __syncthreads();
    for (int d = 1; d < 256; d <<= 1){
        int u = (t >= d) ? sc[t-d] : 0;
        __syncthreads();
        sc[t] += u;
        __syncthreads();
    }
    int bse = sc[t] - (c0 + c1);
    lex[2*t]   = bse;
    lex[2*t+1] = bse + c0;
    __syncthreads();
    for (int i = t; i < nn; i += 256){
        off[n0 + i]  = lo + lex[i];
        dinv[n0 + i] = rsqrtf((float)lcnt[i] + 1.0f);
    }
    if (b == 0 && t == 0) off[n] = NE;
    __syncthreads();
    for (int j = lo + t; j < hi; j += 256){
        unsigned int u = ebuf[j];
        int d = (int)(u >> 16) - n0;
        int p = atomicAdd(&lex[d], 1);
        csr[lo + p] = (int)(u & 0xffffu);
    }
}

// ---------------- merged aggregation: ONE gather feeds GIN + GCN -----------
// 8-edge unrolled main loop: 8 gathers + 8 dinv in flight per waitcnt drain.
__global__ __launch_bounds__(256) void merged_agg(
        const unsigned int* __restrict__ xcb_cur,
        const float* __restrict__ dinv,
        const int* __restrict__ off, const int* __restrict__ csr,
        unsigned int* __restrict__ hpreb, unsigned int* __restrict__ ub, int n)
{
    int node = __builtin_amdgcn_readfirstlane(blockIdx.x * 4 + (threadIdx.x >> 6));
    int lane = threadIdx.x & 63;
    if (node >= n) return;
    int beg = off[node], end = off[node+1];
    unsigned int ps = xcb_cur[(size_t)node*64 + lane];
    float s0f = bf_lo(ps), s1f = bf_hi(ps);
    float a0 = s0f, a1 = s1f;
    float g0 = 0.f, g1 = 0.f;
    int e = beg;
    for (; e + 8 <= end; e += 8){
        int s0 = csr[e],   s1 = csr[e+1], s2 = csr[e+2], s3 = csr[e+3];
        int s4 = csr[e+4], s5 = csr[e+5], s6 = csr[e+6], s7 = csr[e+7];
        unsigned int p0 = xcb_cur[(size_t)s0*64 + lane];
        unsigned int p1 = xcb_cur[(size_t)s1*64 + lane];
        unsigned int p2 = xcb_cur[(size_t)s2*64 + lane];
        unsigned int p3 = xcb_cur[(size_t)s3*64 + lane];
        unsigned int p4 = xcb_cur[(size_t)s4*64 + lane];
        unsigned int p5 = xcb_cur[(size_t)s5*64 + lane];
        unsigned int p6 = xcb_cur[(size_t)s6*64 + lane];
        unsigned int p7 = xcb_cur[(size_t)s7*64 + lane];
        float d0 = dinv[s0], d1 = dinv[s1], d2 = dinv[s2], d3 = dinv[s3];
        float d4 = dinv[s4], d5 = dinv[s5], d6 = dinv[s6], d7 = dinv[s7];
        float v0 = bf_lo(p0), v1 = bf_lo(p1), v2 = bf_lo(p2), v3 = bf_lo(p3);
        float v4 = bf_lo(p4), v5 = bf_lo(p5), v6 = bf_lo(p6), v7 = bf_lo(p7);
        float w0 = bf_hi(p0), w1 = bf_hi(p1), w2 = bf_hi(p2), w3 = bf_hi(p3);
        float w4 = bf_hi(p4), w5 = bf_hi(p5), w6 = bf_hi(p6), w7 = bf_hi(p7);
        a0 += ((v0 + v1) + (v2 + v3)) + ((v4 + v5) + (v6 + v7));
        a1 += ((w0 + w1) + (w2 + w3)) + ((w4 + w5) + (w6 + w7));
        float ga = fmaf(d0, v0, fmaf(d1, v1, fmaf(d2, v2, d3*v3)));
        float gb = fmaf(d4, v4, fmaf(d5, v5, fmaf(d6, v6, d7*v7)));
        g0 += ga + gb;
        float gc = fmaf(d0, w0, fmaf(d1, w1, fmaf(d2, w2, d3*w3)));
        float gd = fmaf(d4, w4, fmaf(d5, w5, fmaf(d6, w6, d7*w7)));
        g1 += gc + gd;
    }
    for (; e + 4 <= end; e += 4){
        int s0 = csr[e], s1 = csr[e+1], s2 = csr[e+2], s3 = csr[e+3];
        unsigned int p0 = xcb_cur[(size_t)s0*64 + lane];
        unsigned int p1 = xcb_cur[(size_t)s1*64 + lane];
        unsigned int p2 = xcb_cur[(size_t)s2*64 + lane];
        unsigned int p3 = xcb_cur[(size_t)s3*64 + lane];
        float d0 = dinv[s0], d1 = dinv[s1], d2 = dinv[s2], d3 = dinv[s3];
        float v0 = bf_lo(p0), v1 = bf_lo(p1), v2 = bf_lo(p2), v3 = bf_lo(p3);
        float w0 = bf_hi(p0), w1 = bf_hi(p1), w2 = bf_hi(p2), w3 = bf_hi(p3);
        a0 += (v0 + v1) + (v2 + v3);
        a1 += (w0 + w1) + (w2 + w3);
        g0 = fmaf(d0, v0, fmaf(d1, v1, fmaf(d2, v2, fmaf(d3, v3, g0))));
        g1 = fmaf(d0, w0, fmaf(d1, w1, fmaf(d2, w2, fmaf(d3, w3, g1))));
    }
    for (; e < end; e++){
        int s0 = csr[e];
        unsigned int p0 = xcb_cur[(size_t)s0*64 + lane];
        float d0 = dinv[s0];
        float v0 = bf_lo(p0), w0 = bf_hi(p0);
        a0 += v0; a1 += w0;
        g0 = fmaf(d0, v0, g0);
        g1 = fmaf(d0, w0, g1);
    }
    hpreb[(size_t)node*64 + lane] = pack2bf(a0, a1);
    if (lane >= 32){   // lanes 32..63 hold s_prev cols (64..127)
        float di = dinv[node];
        float u0 = fmaf(di, g0, di*di*s0f);
        float u1 = fmaf(di, g1, di*di*s1f);
        ub[(size_t)node*32 + (lane - 32)] = pack2bf(u0, u1);
    }
}

// ---------------- fused per-layer MFMA: GIN MLP + GCN linear ---------------
// 16-row blocks, wave w owns output quadrant ct=w. A-tiles staged to LDS
// (coalesced uint4); weights in fragment order (lane*16B); outputs staged in
// xsh, written back as one uint4 pass. do_whp (last layer): GEMM4 from xsh +
// pooled atomics, no xcb round trip.
__global__ __launch_bounds__(256) void ginmlp3(
        const unsigned short* __restrict__ hpreb,   // [n,128] bf16 row-major
        const unsigned short* __restrict__ ub,      // [n,64]  bf16 row-major
        const unsigned short* __restrict__ W1F,     // frag order, K=128
        const float* __restrict__ b1,
        const unsigned short* __restrict__ W2F,     // frag order, K=64
        const float* __restrict__ b2,
        const unsigned short* __restrict__ gcnWF,   // frag order, K=64
        const float* __restrict__ gcnb,
        unsigned short* __restrict__ xcb_nxt,
        const unsigned short* __restrict__ whpWF,   // frag order, K=128
        const float* __restrict__ whpb,
        const int* __restrict__ batch,
        float* __restrict__ gbuf,
        int do_whp, int n)
{
    __shared__ unsigned short ash[16 * 136];   // hpreb tile
    __shared__ unsigned short bsh[16 * 72];    // ub tile
    __shared__ unsigned short hsh[16 * 72];    // GEMM1 output
    __shared__ unsigned short xsh[16 * 136];   // [x_new|s_new] tile
    __shared__ float gacc[8 * 64];
    int tid = threadIdx.x;
    int w = tid >> 6, l = tid & 63;
    int m = l & 15, q = l >> 4;
    int rbase = blockIdx.x * 16;
    int col   = w*16 + m;

    // ---- stage A-tiles (coalesced uint4) ----
    {
        int row = tid >> 4, ch = tid & 15;
        int orow = rbase + row;
        uint4 v = make_uint4(0,0,0,0);
        if (orow < n) v = *(const uint4*)(hpreb + (size_t)orow * 128 + ch*8);
        *(uint4*)(&ash[row*136 + ch*8]) = v;
    }
    if (tid < 128){
        int row = tid >> 3, ch = tid & 7;
        int orow = rbase + row;
        uint4 v = make_uint4(0,0,0,0);
        if (orow < n) v = *(const uint4*)(ub + (size_t)orow * 64 + ch*8);
        *(uint4*)(&bsh[row*72 + ch*8]) = v;
    }
    int bmin = 0, span = 0;
    bool useLds = false;
    if (do_whp){
        int rmax = rbase + 15; if (rmax > n - 1) rmax = n - 1;
        bmin = batch[rbase];
        span = batch[rmax] - bmin + 1;
        useLds = (span <= 8);
        if (useLds)
            for (int i = tid; i < span * 64; i += 256) gacc[i] = 0.f;
    }
    __syncthreads();

    // GEMM3 (quadrant w): s_new = tanh(ub @ gcnW + b) -> xsh cols 64+
    {
        v8s a3[2];
#pragma unroll
        for (int ko = 0; ko < 2; ko++)
            a3[ko] = *(const v8s*)(&bsh[m*72 + ko*32 + q*8]);
        v4f acc = {0.f, 0.f, 0.f, 0.f};
#pragma unroll
        for (int ko = 0; ko < 2; ko++){
            v8s b = *(const v8s*)(gcnWF + (size_t)((w*2 + ko)*64 + l) * 8);
            acc = __builtin_amdgcn_mfma_f32_16x16x32_bf16(a3[ko], b, acc, 0, 0, 0);
        }
        float bv = gcnb[col];
#pragma unroll
        for (int r = 0; r < 4; r++)
            xsh[(q*4 + r)*136 + 64 + col] = f2bf(fast_tanh(acc[r] + bv));
    }
    // GEMM1 (quadrant w): h = relu(hpreb @ W1 + b1) -> hsh
    {
        v8s a[4];
#pragma unroll
        for (int ko = 0; ko < 4; ko++)
            a[ko] = *(const v8s*)(&ash[m*136 + ko*32 + q*8]);
        v4f acc = {0.f, 0.f, 0.f, 0.f};
#pragma unroll
        for (int ko = 0; ko < 4; ko++){
            v8s b = *(const v8s*)(W1F + (size_t)((w*4 + ko)*64 + l) * 8);
            acc = __builtin_amdgcn_mfma_f32_16x16x32_bf16(a[ko], b, acc, 0, 0, 0);
        }
        float bv = b1[col];
#pragma unroll
        for (int r = 0; r < 4; r++)
            hsh[(q*4 + r)*72 + col] = f2bf(fmaxf(acc[r] + bv, 0.f));
    }
    __syncthreads();
    // GEMM2 (quadrant w): x_new = relu(h @ W2 + b2) -> xsh cols 0..63
    {
        v8s a2[2];
#pragma unroll
        for (int ko = 0; ko < 2; ko++)
            a2[ko] = *(const v8s*)(&hsh[m*72 + ko*32 + q*8]);
        v4f acc = {0.f, 0.f, 0.f, 0.f};
#pragma unroll
        for (int ko = 0; ko < 2; ko++){
            v8s b = *(const v8s*)(W2F + (size_t)((w*2 + ko)*64 + l) * 8);
            acc = __builtin_amdgcn_mfma_f32_16x16x32_bf16(a2[ko], b, acc, 0, 0, 0);
        }
        float bv = b2[col];
#pragma unroll
        for (int r = 0; r < 4; r++)
            xsh[(q*4 + r)*136 + col] = f2bf(fmaxf(acc[r] + bv, 0.f));
    }
    __syncthreads();   // xsh complete

    if (!do_whp){
        int row = tid >> 4, ch = tid & 15;
        int orow = rbase + row;
        if (orow < n)
            *(uint4*)(xcb_nxt + (size_t)orow * 128 + ch*8) =
                *(const uint4*)(&xsh[row*136 + ch*8]);
    } else {
        // GEMM4 (quadrant w): xw = [x_new|s_new] @ whpW + b, pooled by graph
        v8s a4[4];
#pragma unroll
        for (int ko = 0; ko < 4; ko++)
            a4[ko] = *(const v8s*)(&xsh[m*136 + ko*32 + q*8]);
        int bb[4];
#pragma unroll
        for (int r = 0; r < 4; r++){
            int orow = rbase + q*4 + r;
            bb[r] = (orow < n) ? batch[orow] : -1;
        }
        v4f acc = {0.f, 0.f, 0.f, 0.f};
#pragma unroll
        for (int ko = 0; ko < 4; ko++){
            v8s b = *(const v8s*)(whpWF + (size_t)((w*4 + ko)*64 + l) * 8);
            acc = __builtin_amdgcn_mfma_f32_16x16x32_bf16(a4[ko], b, acc, 0, 0, 0);
        }
        float bv = whpb[col];
#pragma unroll
        for (int r = 0; r < 4; r++){
            if (bb[r] >= 0){
                float val = acc[r] + bv;
                if (useLds) atomicAdd(&gacc[(bb[r] - bmin) * 64 + col], val);
                else        atomicAdd(&gbuf[(size_t)bb[r] * 64 + col], val);
            }
        }
        __syncthreads();
        if (useLds){
            for (int i = tid; i < span * 64; i += 256)
                atomicAdd(&gbuf[(size_t)(bmin + (i >> 6)) * 64 + (i & 63)], gacc[i]);
        }
    }
}

// ---------------- head ----------------------------------------------------
__global__ __launch_bounds__(256) void head_kernel(
        const float* __restrict__ g, const float* __restrict__ postW,
        const float* __restrict__ postb, const float* __restrict__ roW,
        const float* __restrict__ rob, float* __restrict__ out, int ngraph)
{
    int gr = __builtin_amdgcn_readfirstlane(blockIdx.x * 4 + (threadIdx.x >> 6));
    int lane = threadIdx.x & 63;
    if (gr >= ngraph) return;
    float gv = g[(size_t)gr*64 + lane];
    float t = postb[lane];
    for (int k = 0; k < 64; k++){
        float a = __shfl(gv, k);
        t = fmaf(a, postW[k*64 + lane], t);
    }
    t = fmaxf(t, 0.f);
    float lg = (lane < NCLS) ? rob[lane] : 0.f;
    for (int k = 0; k < 64; k++){
        float a = __shfl(t, k);
        float w = (lane < NCLS) ? roW[k*NCLS + lane] : 0.f;
        lg = fmaf(a, w, lg);
    }
    float m = (lane < NCLS) ? lg : -INFINITY;
#pragma unroll
    for (int d = 1; d < 16; d <<= 1) m = fmaxf(m, __shfl_xor(m, d, 16));
    float ex = (lane < NCLS) ? expf(lg - m) : 0.f;
    float ssum = ex;
#pragma unroll
    for (int d = 1; d < 16; d <<= 1) ssum += __shfl_xor(ssum, d, 16);
    if (lane < NCLS) out[(size_t)gr*NCLS + lane] = lg - m - logf(ssum);
}

// ---------------- launch --------------------------------------------------
extern "C" void kernel_launch(void* const* d_in, const int* in_sizes, int n_in,
                              void* d_out, int out_size, void* d_ws, size_t ws_size,
                              hipStream_t stream) {
    const float* x      = (const float*)d_in[0];
    const float* s      = (const float*)d_in[1];
    const int*   ei     = (const int*)d_in[2];    // int32
    const int*   batch  = (const int*)d_in[3];    // int32
    const float* pre_W  = (const float*)d_in[4];
    const float* pre_b  = (const float*)d_in[5];
    const float* emb_W  = (const float*)d_in[6];
    const float* emb_b  = (const float*)d_in[7];
    const float* gin_W1 = (const float*)d_in[8];
    const float* gin_b1 = (const float*)d_in[9];
    const float* gin_W2 = (const float*)d_in[10];
    const float* gin_b2 = (const float*)d_in[11];
    const float* gcn_W  = (const float*)d_in[12];
    const float* gcn_b  = (const float*)d_in[13];
    const float* whp_W  = (const float*)d_in[14];
    const float* whp_b  = (const float*)d_in[15];
    const float* post_W = (const float*)d_in[16];
    const float* post_b = (const float*)d_in[17];
    const float* ro_W   = (const float*)d_in[18];
    const float* ro_b   = (const float*)d_in[19];
    float* out = (float*)d_out;

    char* w = (char*)d_ws;
    auto alloc = [&](size_t bytes) -> void* {
        void* p = (void*)w;
        w += (bytes + 255) & ~(size_t)255;
        return p;
    };
    int*   off   = (int*)  alloc((size_t)(NN+1) * 4);
    int*   csr   = (int*)  alloc((size_t)NE * 4);
    int*   ghist = (int*)  alloc((size_t)NCH * CB * 4);
    unsigned int* ebuf = (unsigned int*)alloc((size_t)NE * 4);
    float* dinv = (float*)alloc((size_t)NN * 4);
    unsigned short* xcb0 = (unsigned short*)alloc((size_t)NN * 128 * 2);
    unsigned short* xcb1 = (unsigned short*)alloc((size_t)NN * 128 * 2);
    unsigned int*   hpreb = (unsigned int*)alloc((size_t)NN * 64 * 4);  // bf16 [n,128]
    unsigned int*   ub    = (unsigned int*)alloc((size_t)NN * 32 * 4);  // bf16 [n,64]
    float* gbuf = (float*)alloc((size_t)NG * 64 * 4);
    unsigned short* gcnWF = (unsigned short*)alloc((size_t)3 * 4096 * 2);
    unsigned short* W1F   = (unsigned short*)alloc((size_t)3 * 8192 * 2);
    unsigned short* W2F   = (unsigned short*)alloc((size_t)3 * 4096 * 2);
    unsigned short* whpWF = (unsigned short*)alloc((size_t)8192 * 2);
    unsigned short* preWF = (unsigned short*)alloc((size_t)8192 * 2);
    unsigned short* embWF = (unsigned short*)alloc((size_t)2048 * 2);

    const int B   = 256;
    const int GT  = (NN + 15) / 16;        // 3125 (16-row tiles: pre & ginmlp3)
    const int GA  = (NN + 3) / 4;          // 12500
    const int GZB = (NG*64 + 255) / 256;   // 126

    // fused prep (wprep-frag + coarse_hist + gbuf zero), then scan, then
    // fused bin+pre_emb-MFMA (dynamic LDS = 38912B), then scatter.
    k_prep<<<264 + NCH + GZB, B, 0, stream>>>(gcn_W, gin_W1, gin_W2, whp_W,
                                              pre_W, emb_W,
                                              gcnWF, W1F, W2F, whpWF,
                                              preWF, embWF,
                                              ei + NE, ghist, gbuf);
    coarse_scan<<<1, B, 0, stream>>>(ghist);
    bin_pre<<<NCH + GT, B, 38912, stream>>>(ei, ei + NE, ghist, ebuf,
                                            x, preWF, pre_b, s, embWF, emb_b,
                                            xcb0, NN);
    scatter_all<<<CB, B, 0, stream>>>(ebuf, ghist, off, dinv, csr, NN);

    for (int i = 0; i < NLAY; i++){
        unsigned short* cur = (i & 1) ? xcb1 : xcb0;
        unsigned short* nxt = (i & 1) ? xcb0 : xcb1;
        merged_agg<<<GA, B, 0, stream>>>((const unsigned int*)cur, dinv, off, csr,
                                         hpreb, ub, NN);
        ginmlp3<<<GT, B, 0, stream>>>((const unsigned short*)hpreb,
                                      (const unsigned short*)ub,
                                      W1F + (size_t)i*8192, gin_b1 + i*64,
                                      W2F + (size_t)i*4096, gin_b2 + i*64,
                                      gcnWF + (size_t)i*4096, gcn_b + i*64,
                                      nxt,
                                      whpWF, whp_b, batch, gbuf,
                                      (i == NLAY - 1) ? 1 : 0, NN);
    }

    // pool already fused into last ginmlp3; head reads gbuf
    head_kernel<<<(NG + 3)/4, B, 0, stream>>>(gbuf, post_W, post_b, ro_W, ro_b, out, NG);
}

// Round 13
// 285.749 us; speedup vs baseline: 1.6639x; 1.0535x over previous
//
#include <hip/hip_runtime.h>
#include <math.h>

#define NN   50000
#define NE   800000
#define FEATD 128
#define SED  16
#define HD   64
#define NCLS 10
#define NLAY 3
#define NG   500

// two-level counting sort params
#define CHUNK 4096
#define NCH   ((NE + CHUNK - 1) / CHUNK)  // 196
#define CBSH  9
#define CB    ((NN + (1 << CBSH) - 1) >> CBSH)  // 98

typedef short  v8s __attribute__((ext_vector_type(8)));
typedef float  v4f __attribute__((ext_vector_type(4)));

// ---- bf16 helpers ---------------------------------------------------------
__device__ inline unsigned short f2bf(float f){
    unsigned int u = __float_as_uint(f);
    u += 0x7fffu + ((u >> 16) & 1u);
    return (unsigned short)(u >> 16);
}
__device__ inline unsigned int pack2bf(float a, float b){
    return (unsigned int)f2bf(a) | ((unsigned int)f2bf(b) << 16);
}
__device__ inline float bf_lo(unsigned int p){ return __uint_as_float(p << 16); }
__device__ inline float bf_hi(unsigned int p){ return __uint_as_float(p & 0xffff0000u); }

// fast tanh via v_exp (accuracy ~1e-7 rel, far below bf16 storage error)
__device__ inline float fast_tanh(float x){
    float ax = fabsf(x);
    float t  = __expf(-2.f * ax);
    float r  = (1.f - t) / (1.f + t);
    return copysignf(r, x);
}

// ---------------- fused prep: weight transposes + coarse hist + gbuf zero --
// All weights emitted in MFMA FRAGMENT ORDER: W[k][col] lands at
//   ((((col/16)*NKO + k/32)*4 + (k/8)%4)*16 + col%16)*8 + k%8
// so a wave's v8s fragment load is base + lane*16B (fully coalesced).
// blocks [0,264): wprep (incl. preWF K=128 and embWF K=16->32 zero-pad);
// [264,264+NCH): coarse_hist; rest: zero gbuf.
__global__ __launch_bounds__(256) void k_prep(
        const float* __restrict__ gcn_W, const float* __restrict__ gin_W1,
        const float* __restrict__ gin_W2, const float* __restrict__ whp_W,
        const float* __restrict__ pre_W, const float* __restrict__ emb_W,
        unsigned short* __restrict__ gcnWF, unsigned short* __restrict__ W1F,
        unsigned short* __restrict__ W2F,  unsigned short* __restrict__ whpWF,
        unsigned short* __restrict__ preWF, unsigned short* __restrict__ embWF,
        const int* __restrict__ dst, int* __restrict__ ghist,
        float* __restrict__ gbuf)
{
    __shared__ int h[CB];
    int b = blockIdx.x;
    if (b < 264){
        int i = b*256 + threadIdx.x;
        if (i < 12288){            // gcn: 3 x [64][64], NKO=2
            int li = i / 4096, r = i % 4096, k = r >> 6, col = r & 63;
            int dfr = (((((col>>4)*2 + (k>>5))*4 + ((k>>3)&3))*16 + (col&15))<<3) + (k&7);
            gcnWF[li*4096 + dfr] = f2bf(gcn_W[li*4096 + k*64 + col]);
        } else if (i < 36864){     // W1: 3 x [128][64], NKO=4
            int j = i - 12288; int li = j / 8192, r = j % 8192, k = r >> 6, col = r & 63;
            int dfr = (((((col>>4)*4 + (k>>5))*4 + ((k>>3)&3))*16 + (col&15))<<3) + (k&7);
            W1F[li*8192 + dfr] = f2bf(gin_W1[li*8192 + k*64 + col]);
        } else if (i < 49152){     // W2: 3 x [64][64], NKO=2
            int j = i - 36864; int li = j / 4096, r = j % 4096, k = r >> 6, col = r & 63;
            int dfr = (((((col>>4)*2 + (k>>5))*4 + ((k>>3)&3))*16 + (col&15))<<3) + (k&7);
            W2F[li*4096 + dfr] = f2bf(gin_W2[li*4096 + k*64 + col]);
        } else if (i < 57344){     // whp: [128][64], NKO=4
            int j = i - 49152; int k = j >> 6, col = j & 63;
            int dfr = (((((col>>4)*4 + (k>>5))*4 + ((k>>3)&3))*16 + (col&15))<<3) + (k&7);
            whpWF[dfr] = f2bf(whp_W[k*64 + col]);
        } else if (i < 65536){     // pre: [128][64], NKO=4
            int j = i - 57344; int k = j >> 6, col = j & 63;
            int dfr = (((((col>>4)*4 + (k>>5))*4 + ((k>>3)&3))*16 + (col&15))<<3) + (k&7);
            preWF[dfr] = f2bf(pre_W[k*64 + col]);
        } else if (i < 67584){     // emb: [16][64] zero-padded to K=32, NKO=1
            int j = i - 65536; int k = j >> 6, col = j & 63;   // k in [0,32)
            int dfr = (((((col>>4)*1 + (k>>5))*4 + ((k>>3)&3))*16 + (col&15))<<3) + (k&7);
            embWF[dfr] = (k < 16) ? f2bf(emb_W[k*64 + col]) : (unsigned short)0;
        }
    } else if (b < 264 + NCH){
        int c = b - 264;
        for (int i = threadIdx.x; i < CB; i += 256) h[i] = 0;
        __syncthreads();
        int base = c * CHUNK;
        int end  = base + CHUNK; if (end > NE) end = NE;
        for (int i = base + threadIdx.x; i < end; i += 256)
            atomicAdd(&h[dst[i] >> CBSH], 1);
        __syncthreads();
        for (int i = threadIdx.x; i < CB; i += 256)
            ghist[(size_t)c * CB + i] = h[i];
    } else {
        int i = (b - 264 - NCH)*256 + threadIdx.x;
        if (i < NG*64) gbuf[i] = 0.f;
    }
}

// LDS-staged scan of ghist (196*98 ints = 77KB LDS); single-block kernel.
__global__ __launch_bounds__(256) void coarse_scan(int* __restrict__ ghist){
    __shared__ int sh[NCH * CB];
    __shared__ int sc[256];
    int t = threadIdx.x;
    for (int i = t; i < NCH * CB; i += 256) sh[i] = ghist[i];
    __syncthreads();
    int run = 0;
    if (t < CB){
        for (int c = 0; c < NCH; c++){
            int v = sh[c*CB + t];
            sh[c*CB + t] = run;
            run += v;
        }
    }
    sc[t] = (t < CB) ? run : 0;
    __syncthreads();
    for (int d = 1; d < 256; d <<= 1){
        int u = (t >= d) ? sc[t-d] : 0;
        __syncthreads();
        sc[t] += u;
        __syncthreads();
    }
    int bstart = (t == 0) ? 0 : sc[t-1];
    if (t < CB){
        for (int c = 0; c < NCH; c++) sh[c*CB + t] += bstart;
    }
    __syncthreads();
    for (int i = t; i < NCH * CB; i += 256) ghist[i] = sh[i];
}

// ---------------- fused: bin_lds (blocks [0,NCH)) + pre_emb MFMA (rest) ----
// Pre blocks: 16-row tiles, 4 waves, wave w = col quadrant; MFMA with
// fragment-order weights; xsh-staged coalesced writeback.
// Union'd dynamic LDS: bin needs 35360B, pre needs 9984B -> launch 38912.
__global__ __launch_bounds__(256) void bin_pre(
        const int* __restrict__ src, const int* __restrict__ dstp,
        const int* __restrict__ ghist, unsigned int* __restrict__ ebuf,
        const float* __restrict__ x, const unsigned short* __restrict__ preWF,
        const float* __restrict__ preb,
        const float* __restrict__ s, const unsigned short* __restrict__ embWF,
        const float* __restrict__ embb,
        unsigned short* __restrict__ xcb, int n)
{
    extern __shared__ char smem[];
    int t = threadIdx.x;
    if (blockIdx.x < NCH){
        // ---- bin_lds ----
        unsigned int* lbuf  = (unsigned int*)smem;
        unsigned int* lbuf2 = lbuf + CHUNK;
        int* hist   = (int*)(lbuf2 + CHUNK);
        int* lstart = hist + CB;
        int* cursor = lstart + CB;
        int* gbase  = cursor + CB;
        int* sc     = gbase + CB;
        int c = blockIdx.x;
        for (int i = t; i < CB; i += 256){
            hist[i] = 0;
            gbase[i] = ghist[(size_t)c*CB + i];
        }
        __syncthreads();
        int base = c * CHUNK;
        int nend = base + CHUNK; if (nend > NE) nend = NE;
        nend -= base;
        for (int i = t; i < nend; i += 256){
            int d = dstp[base + i];
            lbuf[i] = (unsigned int)src[base + i] | ((unsigned int)d << 16);
            atomicAdd(&hist[d >> CBSH], 1);
        }
        __syncthreads();
        sc[t] = (t < CB) ? hist[t] : 0;
        __syncthreads();
        for (int d = 1; d < 256; d <<= 1){
            int u = (t >= d) ? sc[t-d] : 0;
            __syncthreads();
            sc[t] += u;
            __syncthreads();
        }
        if (t < CB){
            lstart[t] = sc[t] - hist[t];
            cursor[t] = sc[t] - hist[t];
        }
        __syncthreads();
        for (int i = t; i < nend; i += 256){
            unsigned int u = lbuf[i];
            int b = (int)(u >> 16) >> CBSH;
            int p = atomicAdd(&cursor[b], 1);
            lbuf2[p] = u;
        }
        __syncthreads();
        for (int p = t; p < nend; p += 256){
            unsigned int u = lbuf2[p];
            int b = (int)(u >> 16) >> CBSH;
            ebuf[gbase[b] + (p - lstart[b])] = u;
        }
    } else {
        // ---- pre_emb via MFMA ----
        unsigned short* ash = (unsigned short*)smem;   // 16*136 (x tile bf16)
        unsigned short* bsh = ash + 16*136;            // 16*40  (s tile, K pad 32)
        unsigned short* xsh = bsh + 16*40;             // 16*136 (output tile)
        int pblk  = blockIdx.x - NCH;
        int rbase = pblk * 16;
        int w = t >> 6, l = t & 63;
        int m = l & 15, q = l >> 4;
        int col = w*16 + m;
        for (int i = t; i < 16*40; i += 256) bsh[i] = 0;
#pragma unroll
        for (int j = 0; j < 2; j++){
            int cid = t*2 + j;
            int row = cid >> 5, c4 = cid & 31;
            int orow = rbase + row;
            float4 v = make_float4(0.f, 0.f, 0.f, 0.f);
            if (orow < n) v = *(const float4*)(x + (size_t)orow * 128 + c4*4);
            *(unsigned int*)(&ash[row*136 + c4*4])     = pack2bf(v.x, v.y);
            *(unsigned int*)(&ash[row*136 + c4*4 + 2]) = pack2bf(v.z, v.w);
        }
        __syncthreads();
        {
            int row = t >> 4, k = t & 15;
            int orow = rbase + row;
            bsh[row*40 + k] = (orow < n) ? f2bf(s[(size_t)orow*16 + k]) : (unsigned short)0;
        }
        __syncthreads();
        {
            v8s ap[4];
#pragma unroll
            for (int ko = 0; ko < 4; ko++)
                ap[ko] = *(const v8s*)(&ash[m*136 + ko*32 + q*8]);
            v4f accp = {0.f, 0.f, 0.f, 0.f};
#pragma unroll
            for (int ko = 0; ko < 4; ko++){
                v8s b = *(const v8s*)(preWF + (size_t)((w*4 + ko)*64 + l) * 8);
                accp = __builtin_amdgcn_mfma_f32_16x16x32_bf16(ap[ko], b, accp, 0, 0, 0);
            }
            v8s ae = *(const v8s*)(&bsh[m*40 + q*8]);
            v8s be = *(const v8s*)(embWF + (size_t)(w*64 + l) * 8);
            v4f acce = {0.f, 0.f, 0.f, 0.f};
            acce = __builtin_amdgcn_mfma_f32_16x16x32_bf16(ae, be, acce, 0, 0, 0);
            float bvp = preb[col];
            float bve = embb[col];
#pragma unroll
            for (int r = 0; r < 4; r++){
                xsh[(q*4 + r)*136 + col]      = f2bf(accp[r] + bvp);
                xsh[(q*4 + r)*136 + 64 + col] = f2bf(acce[r] + bve);
            }
        }
        __syncthreads();
        {
            int row = t >> 4, ch = t & 15;
            int orow = rbase + row;
            if (orow < n)
                *(uint4*)(xcb + (size_t)orow * 128 + ch*8) =
                    *(const uint4*)(&xsh[row*136 + ch*8]);
        }
    }
}

__global__ __launch_bounds__(256) void scatter_all(
        const unsigned int* __restrict__ ebuf, const int* __restrict__ ghist,
        int* __restrict__ off, float* __restrict__ dinv,
        int* __restrict__ csr, int n){
    __shared__ int lcnt[512];
    __shared__ int lex[512];
    __shared__ int sc[256];
    int t = threadIdx.x, b = blockIdx.x;
    int n0 = b << CBSH;
    int nn = n - n0; if (nn > 512) nn = 512;
    int lo = ghist[b];
    int hi = (b + 1 < CB) ? ghist[b + 1] : NE;
    lcnt[t] = 0; lcnt[t + 256] = 0;
    __syncthreads();
    for (int j = lo + t; j < hi; j += 256)
        atomicAdd(&lcnt[(int)(ebuf[j] >> 16) - n0], 1);
    __syncthreads();
    int c0 = lcnt[2*t], c1 = lcnt[2*t+1];
    sc[t] = c0 + c1;
    __syncthreads();
    for (int d = 1; d < 256; d <<= 1){
        int u = (t >= d) ? sc[t-d] : 0;
        __syncthreads();
        sc[t] += u;
        __syncthreads();
    }
    int bse = sc[t] - (c0 + c1);
    lex[2*t]   = bse;
    lex[2*t+1] = bse + c0;
    __syncthreads();
    for (int i = t; i < nn; i += 256){
        off[n0 + i]  = lo + lex[i];
        dinv[n0 + i] = rsqrtf((float)lcnt[i] + 1.0f);
    }
    if (b == 0 && t == 0) off[n] = NE;
    __syncthreads();
    for (int j = lo + t; j < hi; j += 256){
        unsigned int u = ebuf[j];
        int d = (int)(u >> 16) - n0;
        int p = atomicAdd(&lex[d], 1);
        csr[lo + p] = (int)(u & 0xffffu);
    }
}

// ---------------- fused per-layer: merged agg + GIN MLP + GCN linear -------
// Block = 16 nodes, 4 waves. Phase 1 (agg): wave w runs the proven 8-edge
// unrolled gather body for nodes rbase+4w..+3, writing pack2bf results
// directly into the ash/bsh LDS tiles (bit-identical to the old hpreb/ub
// global round trip, which this eliminates along with 3 launches/layer).
// Phase 2: quadrant-split MFMA MLP (R12 ginmlp3 body). NN % 16 == 0.
__global__ __launch_bounds__(256) void agg_mlp(
        const unsigned int* __restrict__ xcb_cur,
        const float* __restrict__ dinv,
        const int* __restrict__ off, const int* __restrict__ csr,
        const unsigned short* __restrict__ W1F,     // frag order, K=128
        const float* __restrict__ b1,
        const unsigned short* __restrict__ W2F,     // frag order, K=64
        const float* __restrict__ b2,
        const unsigned short* __restrict__ gcnWF,   // frag order, K=64
        const float* __restrict__ gcnb,
        unsigned short* __restrict__ xcb_nxt,
        const unsigned short* __restrict__ whpWF,   // frag order, K=128
        const float* __restrict__ whpb,
        const int* __restrict__ batch,
        float* __restrict__ gbuf,
        int do_whp, int n)
{
    __shared__ unsigned short ash[16 * 136];   // hpre tile (agg output)
    __shared__ unsigned short bsh[16 * 72];    // ub tile (agg output)
    __shared__ unsigned short hsh[16 * 72];    // GEMM1 output
    __shared__ unsigned short xsh[16 * 136];   // [x_new|s_new] tile
    __shared__ float gacc[8 * 64];
    int tid = threadIdx.x;
    int w = tid >> 6, l = tid & 63;
    int m = l & 15, q = l >> 4;
    int rbase = blockIdx.x * 16;
    int col   = w*16 + m;

    // ---- phase 1: aggregation (4 nodes per wave) ----
    for (int vi = 0; vi < 4; vi++){
        int lrow = w*4 + vi;
        int node = __builtin_amdgcn_readfirstlane(rbase + lrow);
        int beg = off[node], end = off[node+1];
        unsigned int ps = xcb_cur[(size_t)node*64 + l];
        float s0f = bf_lo(ps), s1f = bf_hi(ps);
        float a0 = s0f, a1 = s1f;
        float g0 = 0.f, g1 = 0.f;
        int e = beg;
        for (; e + 8 <= end; e += 8){
            int s0 = csr[e],   s1 = csr[e+1], s2 = csr[e+2], s3 = csr[e+3];
            int s4 = csr[e+4], s5 = csr[e+5], s6 = csr[e+6], s7 = csr[e+7];
            unsigned int p0 = xcb_cur[(size_t)s0*64 + l];
            unsigned int p1 = xcb_cur[(size_t)s1*64 + l];
            unsigned int p2 = xcb_cur[(size_t)s2*64 + l];
            unsigned int p3 = xcb_cur[(size_t)s3*64 + l];
            unsigned int p4 = xcb_cur[(size_t)s4*64 + l];
            unsigned int p5 = xcb_cur[(size_t)s5*64 + l];
            unsigned int p6 = xcb_cur[(size_t)s6*64 + l];
            unsigned int p7 = xcb_cur[(size_t)s7*64 + l];
            float d0 = dinv[s0], d1 = dinv[s1], d2 = dinv[s2], d3 = dinv[s3];
            float d4 = dinv[s4], d5 = dinv[s5], d6 = dinv[s6], d7 = dinv[s7];
            float v0 = bf_lo(p0), v1 = bf_lo(p1), v2 = bf_lo(p2), v3 = bf_lo(p3);
            float v4 = bf_lo(p4), v5 = bf_lo(p5), v6 = bf_lo(p6), v7 = bf_lo(p7);
            float w0 = bf_hi(p0), w1 = bf_hi(p1), w2 = bf_hi(p2), w3 = bf_hi(p3);
            float w4 = bf_hi(p4), w5 = bf_hi(p5), w6 = bf_hi(p6), w7 = bf_hi(p7);
            a0 += ((v0 + v1) + (v2 + v3)) + ((v4 + v5) + (v6 + v7));
            a1 += ((w0 + w1) + (w2 + w3)) + ((w4 + w5) + (w6 + w7));
            float ga = fmaf(d0, v0, fmaf(d1, v1, fmaf(d2, v2, d3*v3)));
            float gb = fmaf(d4, v4, fmaf(d5, v5, fmaf(d6, v6, d7*v7)));
            g0 += ga + gb;
            float gc = fmaf(d0, w0, fmaf(d1, w1, fmaf(d2, w2, d3*w3)));
            float gd = fmaf(d4, w4, fmaf(d5, w5, fmaf(d6, w6, d7*w7)));
            g1 += gc + gd;
        }
        for (; e + 4 <= end; e += 4){
            int s0 = csr[e], s1 = csr[e+1], s2 = csr[e+2], s3 = csr[e+3];
            unsigned int p0 = xcb_cur[(size_t)s0*64 + l];
            unsigned int p1 = xcb_cur[(size_t)s1*64 + l];
            unsigned int p2 = xcb_cur[(size_t)s2*64 + l];
            unsigned int p3 = xcb_cur[(size_t)s3*64 + l];
            float d0 = dinv[s0], d1 = dinv[s1], d2 = dinv[s2], d3 = dinv[s3];
            float v0 = bf_lo(p0), v1 = bf_lo(p1), v2 = bf_lo(p2), v3 = bf_lo(p3);
            float w0 = bf_hi(p0), w1 = bf_hi(p1), w2 = bf_hi(p2), w3 = bf_hi(p3);
            a0 += (v0 + v1) + (v2 + v3);
            a1 += (w0 + w1) + (w2 + w3);
            g0 = fmaf(d0, v0, fmaf(d1, v1, fmaf(d2, v2, fmaf(d3, v3, g0))));
            g1 = fmaf(d0, w0, fmaf(d1, w1, fmaf(d2, w2, fmaf(d3, w3, g1))));
        }
        for (; e < end; e++){
            int s0 = csr[e];
            unsigned int p0 = xcb_cur[(size_t)s0*64 + l];
            float d0 = dinv[s0];
            float v0 = bf_lo(p0), w0 = bf_hi(p0);
            a0 += v0; a1 += w0;
            g0 = fmaf(d0, v0, g0);
            g1 = fmaf(d0, w0, g1);
        }
        *(unsigned int*)(&ash[lrow*136 + 2*l]) = pack2bf(a0, a1);
        if (l >= 32){   // lanes 32..63 hold s_prev cols (64..127)
            float di = dinv[node];
            float u0 = fmaf(di, g0, di*di*s0f);
            float u1 = fmaf(di, g1, di*di*s1f);
            *(unsigned int*)(&bsh[lrow*72 + 2*(l - 32)]) = pack2bf(u0, u1);
        }
    }
    int bmin = 0, span = 0;
    bool useLds = false;
    if (do_whp){
        int rmax = rbase + 15; if (rmax > n - 1) rmax = n - 1;
        bmin = batch[rbase];
        span = batch[rmax] - bmin + 1;
        useLds = (span <= 8);
        if (useLds)
            for (int i = tid; i < span * 64; i += 256) gacc[i] = 0.f;
    }
    __syncthreads();

    // ---- phase 2: MFMA MLP (quadrant w) ----
    // GEMM3: s_new = tanh(ub @ gcnW + b) -> xsh cols 64+
    {
        v8s a3[2];
#pragma unroll
        for (int ko = 0; ko < 2; ko++)
            a3[ko] = *(const v8s*)(&bsh[m*72 + ko*32 + q*8]);
        v4f acc = {0.f, 0.f, 0.f, 0.f};
#pragma unroll
        for (int ko = 0; ko < 2; ko++){
            v8s b = *(const v8s*)(gcnWF + (size_t)((w*2 + ko)*64 + l) * 8);
            acc = __builtin_amdgcn_mfma_f32_16x16x32_bf16(a3[ko], b, acc, 0, 0, 0);
        }
        float bv = gcnb[col];
#pragma unroll
        for (int r = 0; r < 4; r++)
            xsh[(q*4 + r)*136 + 64 + col] = f2bf(fast_tanh(acc[r] + bv));
    }
    // GEMM1: h = relu(hpre @ W1 + b1) -> hsh
    {
        v8s a[4];
#pragma unroll
        for (int ko = 0; ko < 4; ko++)
            a[ko] = *(const v8s*)(&ash[m*136 + ko*32 + q*8]);
        v4f acc = {0.f, 0.f, 0.f, 0.f};
#pragma unroll
        for (int ko = 0; ko < 4; ko++){
            v8s b = *(const v8s*)(W1F + (size_t)((w*4 + ko)*64 + l) * 8);
            acc = __builtin_amdgcn_mfma_f32_16x16x32_bf16(a[ko], b, acc, 0, 0, 0);
        }
        float bv = b1[col];
#pragma unroll
        for (int r = 0; r < 4; r++)
            hsh[(q*4 + r)*72 + col] = f2bf(fmaxf(acc[r] + bv, 0.f));
    }
    __syncthreads();
    // GEMM2: x_new = relu(h @ W2 + b2) -> xsh cols 0..63
    {
        v8s a2[2];
#pragma unroll
        for (int ko = 0; ko < 2; ko++)
            a2[ko] = *(const v8s*)(&hsh[m*72 + ko*32 + q*8]);
        v4f acc = {0.f, 0.f, 0.f, 0.f};
#pragma unroll
        for (int ko = 0; ko < 2; ko++){
            v8s b = *(const v8s*)(W2F + (size_t)((w*2 + ko)*64 + l) * 8);
            acc = __builtin_amdgcn_mfma_f32_16x16x32_bf16(a2[ko], b, acc, 0, 0, 0);
        }
        float bv = b2[col];
#pragma unroll
        for (int r = 0; r < 4; r++)
            xsh[(q*4 + r)*136 + col] = f2bf(fmaxf(acc[r] + bv, 0.f));
    }
    __syncthreads();   // xsh complete

    if (!do_whp){
        int row = tid >> 4, ch = tid & 15;
        int orow = rbase + row;
        if (orow < n)
            *(uint4*)(xcb_nxt + (size_t)orow * 128 + ch*8) =
                *(const uint4*)(&xsh[row*136 + ch*8]);
    } else {
        // GEMM4: xw = [x_new|s_new] @ whpW + b, pooled by graph
        v8s a4[4];
#pragma unroll
        for (int ko = 0; ko < 4; ko++)
            a4[ko] = *(const v8s*)(&xsh[m*136 + ko*32 + q*8]);
        int bb[4];
#pragma unroll
        for (int r = 0; r < 4; r++){
            int orow = rbase + q*4 + r;
            bb[r] = (orow < n) ? batch[orow] : -1;
        }
        v4f acc = {0.f, 0.f, 0.f, 0.f};
#pragma unroll
        for (int ko = 0; ko < 4; ko++){
            v8s b = *(const v8s*)(whpWF + (size_t)((w*4 + ko)*64 + l) * 8);
            acc = __builtin_amdgcn_mfma_f32_16x16x32_bf16(a4[ko], b, acc, 0, 0, 0);
        }
        float bv = whpb[col];
#pragma unroll
        for (int r = 0; r < 4; r++){
            if (bb[r] >= 0){
                float val = acc[r] + bv;
                if (useLds) atomicAdd(&gacc[(bb[r] - bmin) * 64 + col], val);
                else        atomicAdd(&gbuf[(size_t)bb[r] * 64 + col], val);
            }
        }
        __syncthreads();
        if (useLds){
            for (int i = tid; i < span * 64; i += 256)
                atomicAdd(&gbuf[(size_t)(bmin + (i >> 6)) * 64 + (i & 63)], gacc[i]);
        }
    }
}

// ---------------- head ----------------------------------------------------
__global__ __launch_bounds__(256) void head_kernel(
        const float* __restrict__ g, const float* __restrict__ postW,
        const float* __restrict__ postb, const float* __restrict__ roW,
        const float* __restrict__ rob, float* __restrict__ out, int ngraph)
{
    int gr = __builtin_amdgcn_readfirstlane(blockIdx.x * 4 + (threadIdx.x >> 6));
    int lane = threadIdx.x & 63;
    if (gr >= ngraph) return;
    float gv = g[(size_t)gr*64 + lane];
    float t = postb[lane];
    for (int k = 0; k < 64; k++){
        float a = __shfl(gv, k);
        t = fmaf(a, postW[k*64 + lane], t);
    }
    t = fmaxf(t, 0.f);
    float lg = (lane < NCLS) ? rob[lane] : 0.f;
    for (int k = 0; k < 64; k++){
        float a = __shfl(t, k);
        float w = (lane < NCLS) ? roW[k*NCLS + lane] : 0.f;
        lg = fmaf(a, w, lg);
    }
    float m = (lane < NCLS) ? lg : -INFINITY;
#pragma unroll
    for (int d = 1; d < 16; d <<= 1) m = fmaxf(m, __shfl_xor(m, d, 16));
    float ex = (lane < NCLS) ? expf(lg - m) : 0.f;
    float ssum = ex;
#pragma unroll
    for (int d = 1; d < 16; d <<= 1) ssum += __shfl_xor(ssum, d, 16);
    if (lane < NCLS) out[(size_t)gr*NCLS + lane] = lg - m - logf(ssum);
}

// ---------------- launch --------------------------------------------------
extern "C" void kernel_launch(void* const* d_in, const int* in_sizes, int n_in,
                              void* d_out, int out_size, void* d_ws, size_t ws_size,
                              hipStream_t stream) {
    const float* x      = (const float*)d_in[0];
    const float* s      = (const float*)d_in[1];
    const int*   ei     = (const int*)d_in[2];    // int32
    const int*   batch  = (const int*)d_in[3];    // int32
    const float* pre_W  = (const float*)d_in[4];
    const float* pre_b  = (const float*)d_in[5];
    const float* emb_W  = (const float*)d_in[6];
    const float* emb_b  = (const float*)d_in[7];
    const float* gin_W1 = (const float*)d_in[8];
    const float* gin_b1 = (const float*)d_in[9];
    const float* gin_W2 = (const float*)d_in[10];
    const float* gin_b2 = (const float*)d_in[11];
    const float* gcn_W  = (const float*)d_in[12];
    const float* gcn_b  = (const float*)d_in[13];
    const float* whp_W  = (const float*)d_in[14];
    const float* whp_b  = (const float*)d_in[15];
    const float* post_W = (const float*)d_in[16];
    const float* post_b = (const float*)d_in[17];
    const float* ro_W   = (const float*)d_in[18];
    const float* ro_b   = (const float*)d_in[19];
    float* out = (float*)d_out;

    char* w = (char*)d_ws;
    auto alloc = [&](size_t bytes) -> void* {
        void* p = (void*)w;
        w += (bytes + 255) & ~(size_t)255;
        return p;
    };
    int*   off   = (int*)  alloc((size_t)(NN+1) * 4);
    int*   csr   = (int*)  alloc((size_t)NE * 4);
    int*   ghist = (int*)  alloc((size_t)NCH * CB * 4);
    unsigned int* ebuf = (unsigned int*)alloc((size_t)NE * 4);
    float* dinv = (float*)alloc((size_t)NN * 4);
    unsigned short* xcb0 = (unsigned short*)alloc((size_t)NN * 128 * 2);
    unsigned short* xcb1 = (unsigned short*)alloc((size_t)NN * 128 * 2);
    float* gbuf = (float*)alloc((size_t)NG * 64 * 4);
    unsigned short* gcnWF = (unsigned short*)alloc((size_t)3 * 4096 * 2);
    unsigned short* W1F   = (unsigned short*)alloc((size_t)3 * 8192 * 2);
    unsigned short* W2F   = (unsigned short*)alloc((size_t)3 * 4096 * 2);
    unsigned short* whpWF = (unsigned short*)alloc((size_t)8192 * 2);
    unsigned short* preWF = (unsigned short*)alloc((size_t)8192 * 2);
    unsigned short* embWF = (unsigned short*)alloc((size_t)2048 * 2);

    const int B   = 256;
    const int GT  = (NN + 15) / 16;        // 3125 (16-row tiles)
    const int GZB = (NG*64 + 255) / 256;   // 126

    // fused prep (wprep-frag + coarse_hist + gbuf zero), then scan, then
    // fused bin+pre_emb-MFMA (dynamic LDS = 38912B), then scatter.
    k_prep<<<264 + NCH + GZB, B, 0, stream>>>(gcn_W, gin_W1, gin_W2, whp_W,
                                              pre_W, emb_W,
                                              gcnWF, W1F, W2F, whpWF,
                                              preWF, embWF,
                                              ei + NE, ghist, gbuf);
    coarse_scan<<<1, B, 0, stream>>>(ghist);
    bin_pre<<<NCH + GT, B, 38912, stream>>>(ei, ei + NE, ghist, ebuf,
                                            x, preWF, pre_b, s, embWF, emb_b,
                                            xcb0, NN);
    scatter_all<<<CB, B, 0, stream>>>(ebuf, ghist, off, dinv, csr, NN);

    for (int i = 0; i < NLAY; i++){
        unsigned short* cur = (i & 1) ? xcb1 : xcb0;
        unsigned short* nxt = (i & 1) ? xcb0 : xcb1;
        agg_mlp<<<GT, B, 0, stream>>>((const unsigned int*)cur, dinv, off, csr,
                                      W1F + (size_t)i*8192, gin_b1 + i*64,
                                      W2F + (size_t)i*4096, gin_b2 + i*64,
                                      gcnWF + (size_t)i*4096, gcn_b + i*64,
                                      nxt,
                                      whpWF, whp_b, batch, gbuf,
                                      (i == NLAY - 1) ? 1 : 0, NN);
    }

    // pool fused into last agg_mlp; head reads gbuf
    head_kernel<<<(NG + 3)/4, B, 0, stream>>>(gbuf, post_W, post_b, ro_W, ro_b, out, NG);
}